// Round 10
// baseline (315.792 us; speedup 1.0000x reference)
//
#include <hip/hip_runtime.h>
#include <math.h>

#define NN 50000
#define EE 800000
#define RAWD 128
#define HIDD 256
#define OUTD 64
#define KK 4
#define PHID 16

typedef __attribute__((ext_vector_type(8))) short short8;
typedef __attribute__((ext_vector_type(4))) float f32x4;

__device__ inline float b2f(unsigned short u) {
    union { unsigned i; float f; } v; v.i = ((unsigned)u) << 16; return v.f;
}
__device__ inline unsigned short f2b(float f) {
    unsigned u = __float_as_uint(f);
    unsigned r = (u + 0x7FFFu + ((u >> 16) & 1u)) >> 16;   // RNE
    return (unsigned short)r;
}
__device__ inline unsigned char f2fp8(float v) {
    return (unsigned char)(__builtin_amdgcn_cvt_pk_fp8_f32(v, v, 0, false) & 0xFF);
}
__device__ inline unsigned cvt_pk_bf16(float lo, float hi) {
    unsigned r;
    asm("v_cvt_pk_bf16_f32 %0, %1, %2" : "=v"(r) : "v"(lo), "v"(hi));
    return r;
}

// ---------------------------------------------------------------------------
// weight prep: W_t (perm: row cp=ch*4+k), W1, W2, Wphi_t (+pad), zero l_focus
// ---------------------------------------------------------------------------
__global__ void wprep_k(const float* __restrict__ W, const float* __restrict__ W1,
                        const float* __restrict__ W2, const float* __restrict__ W_phi,
                        unsigned short* __restrict__ W_t, unsigned short* __restrict__ W1_bf,
                        unsigned short* __restrict__ W2_bf, unsigned short* __restrict__ Wphi_t,
                        float* __restrict__ lfocus_zero) {
    int i = blockIdx.x * 256 + threadIdx.x;
    if (i == 0) *lfocus_zero = 0.f;
    if (i < 65536) {
        int cp = i >> 8, r = i & 255;
        int ch = cp >> 2, k = cp & 3;
        W_t[i] = f2b(W[(size_t)r * 256 + (k << 6) + ch]);
    } else if (i < 65536 + 32768) {
        int j = i - 65536;
        W1_bf[j] = f2b(W1[j]);
    } else if (i < 65536 + 32768 + 16384) {
        int j = i - 98304;
        W2_bf[j] = f2b(W2[j]);
    } else if (i < 65536 + 32768 + 16384 + 2048) {
        int j = i - 114688;
        int cp = j >> 7, r = j & 127;
        Wphi_t[j] = (cp < 15) ? f2b(W_phi[(size_t)r * 15 + cp]) : (unsigned short)0;
    }
}

// ---------------------------------------------------------------------------
// tilde_norm + l_sep
// ---------------------------------------------------------------------------
__global__ void tnorm_lsep_k(const float* __restrict__ tilde_phi,
                             float* __restrict__ tnorm,
                             float* __restrict__ lsep_out) {
    __shared__ float tn[KK][PHID];
    int t = threadIdx.x;
    if (t < KK * PHID) {
        float v = tilde_phi[t];
        float sq = v * v;
        #pragma unroll
        for (int s = 8; s; s >>= 1) sq += __shfl_xor(sq, s, 16);
        float tnv = v / sqrtf(sq);
        tn[t >> 4][t & 15] = tnv;
        tnorm[t] = tnv;
    }
    __syncthreads();
    if (t == 0) {
        float tot = 0.f;
        for (int i = 0; i < KK; ++i)
            for (int j = 0; j < KK; ++j) {
                float s2 = 0.f;
                for (int p = 0; p < PHID; ++p) {
                    float df = tn[i][p] - tn[j][p];
                    s2 += df * df;
                }
                tot += s2;
            }
        lsep_out[0] = tot / (float)KK;
    }
}

// ---------------------------------------------------------------------------
// Direct-from-global MFMA GEMM: NO LDS, NO barriers.
// 256 thr = 4 waves; wave grid (4/WN_WAVES) x WN_WAVES; frag grid AM x AN.
// A: [*, KD] f32 (AF32, packed to bf16 in-reg) or bf16. Bt: [N][KD] bf16 (L2-hot).
// OMODE: 0=f32, 1=bf16, 2=fp8. Optional LFOCUS (sum v^2) and TNADJ (+tn_vec).
// ---------------------------------------------------------------------------
template <int KD, int WN_WAVES, int AM, int AN, bool RELU, bool AF32, int OMODE,
          bool LFOCUS, bool TNADJ>
__global__ __launch_bounds__(256) void dgemm_k(const void* __restrict__ A,
                                               const unsigned short* __restrict__ Bt,
                                               const float* __restrict__ bias_vec,
                                               void* __restrict__ Cout, int ldc,
                                               float* __restrict__ lfocus_acc,
                                               const float* __restrict__ tn_vec) {
    const int tid = threadIdx.x;
    const int w = tid >> 6, l = tid & 63;
    const int l15 = l & 15, l4 = l >> 4;
    const int RPB = (4 / WN_WAVES) * AM * 16;     // rows per block
    const int wr = w / WN_WAVES, wc = w % WN_WAVES;
    const int row0 = blockIdx.x * RPB + wr * AM * 16;
    const int col0 = wc * AN * 16;

    int arow[AM];
    #pragma unroll
    for (int m = 0; m < AM; ++m) {
        int r = row0 + m * 16 + l15;
        arow[m] = (r < NN) ? r : NN - 1;
    }

    f32x4 acc[AM][AN];
    #pragma unroll
    for (int m = 0; m < AM; ++m)
        #pragma unroll
        for (int n = 0; n < AN; ++n)
            acc[m][n] = (f32x4){0.f, 0.f, 0.f, 0.f};

    #pragma unroll 2
    for (int k0 = 0; k0 < KD; k0 += 32) {
        short8 af[AM], bfr[AN];
        #pragma unroll
        for (int m = 0; m < AM; ++m) {
            if (AF32) {
                const float* Af = (const float*)A + (size_t)arow[m] * KD + k0 + l4 * 8;
                float4 f0 = *(const float4*)Af;
                float4 f1 = *(const float4*)(Af + 4);
                union { unsigned u[4]; short8 s; } cv;
                cv.u[0] = cvt_pk_bf16(f0.x, f0.y);
                cv.u[1] = cvt_pk_bf16(f0.z, f0.w);
                cv.u[2] = cvt_pk_bf16(f1.x, f1.y);
                cv.u[3] = cvt_pk_bf16(f1.z, f1.w);
                af[m] = cv.s;
            } else {
                af[m] = *(const short8*)&((const unsigned short*)A)[(size_t)arow[m] * KD + k0 + l4 * 8];
            }
        }
        #pragma unroll
        for (int n = 0; n < AN; ++n)
            bfr[n] = *(const short8*)&Bt[(size_t)(col0 + n * 16 + l15) * KD + k0 + l4 * 8];
        #pragma unroll
        for (int m = 0; m < AM; ++m)
            #pragma unroll
            for (int n = 0; n < AN; ++n)
                acc[m][n] = __builtin_amdgcn_mfma_f32_16x16x32_bf16(af[m], bfr[n], acc[m][n], 0, 0, 0);
    }

    float lf = 0.f;
    // C/D layout: col=lane&15, row=(lane>>4)*4+reg
    #pragma unroll
    for (int m = 0; m < AM; ++m) {
        #pragma unroll
        for (int n = 0; n < AN; ++n) {
            int gc = col0 + n * 16 + l15;
            float bv = bias_vec ? bias_vec[gc] : 0.f;
            float tv = TNADJ ? tn_vec[gc] : 0.f;
            #pragma unroll
            for (int r = 0; r < 4; ++r) {
                int gr = row0 + m * 16 + l4 * 4 + r;
                if (gr >= NN) continue;
                float v = acc[m][n][r] + bv;
                if (RELU) v = fmaxf(v, 0.f);
                if (LFOCUS) lf += v * v;
                if (TNADJ) v += tv;
                if (OMODE == 0)
                    ((float*)Cout)[(size_t)gr * ldc + gc] = v;
                else if (OMODE == 1)
                    ((unsigned short*)Cout)[(size_t)gr * ldc + gc] = f2b(v);
                else
                    ((unsigned char*)Cout)[(size_t)gr * ldc + gc] = f2fp8(v);
            }
        }
    }
    if (LFOCUS) {
        #pragma unroll
        for (int s = 32; s; s >>= 1) lf += __shfl_xor(lf, s);
        if ((tid & 63) == 0)
            atomicAdd(lfocus_acc, lf * (1.f / ((float)NN * KK)));
    }
}

// ---------------------------------------------------------------------------
__global__ void degree_k(const int* __restrict__ dst, int* __restrict__ deg) {
    int e = blockIdx.x * 256 + threadIdx.x;
    if (e < EE) atomicAdd(&deg[dst[e]], 1);
}

#define SCAN_NB ((NN + 255) / 256)   // 196

__global__ __launch_bounds__(256) void scan_partial_k(const int* __restrict__ deg,
                                                      int* __restrict__ bsum) {
    __shared__ int ws_[4];
    int i = blockIdx.x * 256 + threadIdx.x;
    int v = (i < NN) ? deg[i] : 0;
    int x = v;
    #pragma unroll
    for (int s = 32; s; s >>= 1) x += __shfl_xor(x, s);
    if ((threadIdx.x & 63) == 0) ws_[threadIdx.x >> 6] = x;
    __syncthreads();
    if (threadIdx.x == 0) bsum[blockIdx.x] = ws_[0] + ws_[1] + ws_[2] + ws_[3];
}

__global__ __launch_bounds__(256) void scan_bsum_k(int* __restrict__ bsum) {
    __shared__ int sd[256];
    int t = threadIdx.x;
    int v = (t < SCAN_NB) ? bsum[t] : 0;
    sd[t] = v;
    __syncthreads();
    for (int s = 1; s < 256; s <<= 1) {
        int u = (t >= s) ? sd[t - s] : 0;
        __syncthreads();
        sd[t] += u;
        __syncthreads();
    }
    if (t < SCAN_NB) bsum[t] = sd[t] - v;   // exclusive
}

__global__ __launch_bounds__(256) void scan_scatter_k(const int* __restrict__ deg,
                                                      const int* __restrict__ bsum,
                                                      int* __restrict__ offs,
                                                      int* __restrict__ cursor) {
    __shared__ int wexc[4];
    int i = blockIdx.x * 256 + threadIdx.x;
    int lane = threadIdx.x & 63, wid = threadIdx.x >> 6;
    int v = (i < NN) ? deg[i] : 0;
    int x = v;
    #pragma unroll
    for (int d = 1; d < 64; d <<= 1) { int u = __shfl_up(x, d); if (lane >= d) x += u; }
    if (lane == 63) wexc[wid] = x;
    __syncthreads();
    if (threadIdx.x == 0) {
        int a = wexc[0], b = wexc[1], c = wexc[2];
        wexc[0] = 0; wexc[1] = a; wexc[2] = a + b; wexc[3] = a + b + c;
    }
    __syncthreads();
    int excl = (x - v) + wexc[wid] + bsum[blockIdx.x];
    if (i < NN) {
        cursor[i] = excl;
        offs[i + 1] = excl + v;
        if (i == 0) offs[0] = 0;
    }
}

__global__ void scatter_src_k(const int* __restrict__ src, const int* __restrict__ dst,
                              int* __restrict__ cursor, int* __restrict__ csr_src,
                              int* __restrict__ csr_dst) {
    int e = blockIdx.x * 256 + threadIdx.x;
    if (e >= EE) return;
    int d = dst[e];
    int pos = atomicAdd(&cursor[d], 1);
    csr_src[pos] = src[e];
    csr_dst[pos] = d;
}

// ---------------------------------------------------------------------------
// edge weights, thread per CSR slot. delta' already includes tnorm.
// ---------------------------------------------------------------------------
__global__ __launch_bounds__(256) void edge_w_k(const int* __restrict__ csr_src,
                                                const int* __restrict__ csr_dst,
                                                const float* __restrict__ phi,
                                                const float* __restrict__ deltap,
                                                float4* __restrict__ csr_w) {
    int e = blockIdx.x * 256 + threadIdx.x;
    if (e >= EE) return;
    int s = csr_src[e], d = csr_dst[e];
    const float4* ps4 = (const float4*)(phi + (size_t)s * 16);
    const float4* pd4 = (const float4*)(phi + (size_t)d * 16);
    float dv[16];
    float nrm2 = 0.f;
    #pragma unroll
    for (int q = 0; q < 4; ++q) {
        float4 a = ps4[q], b = pd4[q];
        dv[q * 4 + 0] = a.x - b.x;
        dv[q * 4 + 1] = a.y - b.y;
        dv[q * 4 + 2] = a.z - b.z;
        dv[q * 4 + 3] = a.w - b.w;
    }
    #pragma unroll
    for (int p = 0; p < 15; ++p) nrm2 += dv[p] * dv[p];
    float z = (nrm2 == 0.f) ? 1.f : 0.f;
    dv[15] = z;
    nrm2 += z;
    float inv = 1.f / fmaxf(sqrtf(nrm2), 1e-8f);
    const float* dl = deltap + (size_t)d * 64;
    float res[4];
    #pragma unroll
    for (int k = 0; k < 4; ++k) {
        const float4* dk = (const float4*)(dl + k * 16);
        float sacc = 0.f;
        #pragma unroll
        for (int q = 0; q < 4; ++q) {
            float4 tv = dk[q];
            sacc += dv[q * 4 + 0] * tv.x;
            sacc += dv[q * 4 + 1] * tv.y;
            sacc += dv[q * 4 + 2] * tv.z;
            sacc += dv[q * 4 + 3] * tv.w;
        }
        res[k] = sacc * inv;
    }
    csr_w[e] = make_float4(__expf(res[0]), __expf(res[1]),
                           __expf(res[2]), __expf(res[3]));
}

// ---------------------------------------------------------------------------
// per-dst single-pass aggregation. Wave per node, lane = channel.
// h is fp8 [node][ch][k]: one uint (4 fp8) gather per lane per edge.
// ---------------------------------------------------------------------------
__global__ __launch_bounds__(256) void aggregate_k(const int* __restrict__ offs,
                                                   const int* __restrict__ csr_src,
                                                   const float4* __restrict__ csr_w,
                                                   const unsigned int* __restrict__ h8,
                                                   const float* __restrict__ bias,
                                                   float* __restrict__ out) {
    int wave = threadIdx.x >> 6;
    int lane = threadIdx.x & 63;
    int n = blockIdx.x * 4 + wave;
    if (n >= NN) return;
    int beg = offs[n], end = offs[n + 1];

    float a0 = 0.f, a1 = 0.f, a2 = 0.f, a3 = 0.f;
    float d0 = 0.f, d1 = 0.f, d2 = 0.f, d3 = 0.f;
    int p = beg;
    for (; p + 3 < end; p += 4) {
        float4 w0 = csr_w[p], w1 = csr_w[p + 1], w2 = csr_w[p + 2], w3 = csr_w[p + 3];
        int s0 = csr_src[p], s1 = csr_src[p + 1], s2 = csr_src[p + 2], s3 = csr_src[p + 3];
        unsigned hv0 = h8[(size_t)s0 * 64 + lane];
        unsigned hv1 = h8[(size_t)s1 * 64 + lane];
        unsigned hv2 = h8[(size_t)s2 * 64 + lane];
        unsigned hv3 = h8[(size_t)s3 * 64 + lane];
        d0 += (w0.x + w1.x) + (w2.x + w3.x);
        d1 += (w0.y + w1.y) + (w2.y + w3.y);
        d2 += (w0.z + w1.z) + (w2.z + w3.z);
        d3 += (w0.w + w1.w) + (w2.w + w3.w);
        a0 += w0.x * __builtin_amdgcn_cvt_f32_fp8(hv0, 0) + w1.x * __builtin_amdgcn_cvt_f32_fp8(hv1, 0)
            + w2.x * __builtin_amdgcn_cvt_f32_fp8(hv2, 0) + w3.x * __builtin_amdgcn_cvt_f32_fp8(hv3, 0);
        a1 += w0.y * __builtin_amdgcn_cvt_f32_fp8(hv0, 1) + w1.y * __builtin_amdgcn_cvt_f32_fp8(hv1, 1)
            + w2.y * __builtin_amdgcn_cvt_f32_fp8(hv2, 1) + w3.y * __builtin_amdgcn_cvt_f32_fp8(hv3, 1);
        a2 += w0.z * __builtin_amdgcn_cvt_f32_fp8(hv0, 2) + w1.z * __builtin_amdgcn_cvt_f32_fp8(hv1, 2)
            + w2.z * __builtin_amdgcn_cvt_f32_fp8(hv2, 2) + w3.z * __builtin_amdgcn_cvt_f32_fp8(hv3, 2);
        a3 += w0.w * __builtin_amdgcn_cvt_f32_fp8(hv0, 3) + w1.w * __builtin_amdgcn_cvt_f32_fp8(hv1, 3)
            + w2.w * __builtin_amdgcn_cvt_f32_fp8(hv2, 3) + w3.w * __builtin_amdgcn_cvt_f32_fp8(hv3, 3);
    }
    for (; p < end; ++p) {
        float4 wA = csr_w[p];
        int sA = csr_src[p];
        unsigned hv = h8[(size_t)sA * 64 + lane];
        d0 += wA.x; d1 += wA.y; d2 += wA.z; d3 += wA.w;
        a0 += wA.x * __builtin_amdgcn_cvt_f32_fp8(hv, 0);
        a1 += wA.y * __builtin_amdgcn_cvt_f32_fp8(hv, 1);
        a2 += wA.z * __builtin_amdgcn_cvt_f32_fp8(hv, 2);
        a3 += wA.w * __builtin_amdgcn_cvt_f32_fp8(hv, 3);
    }
    float v = (d0 > 0.f ? a0 / d0 : 0.f) + (d1 > 0.f ? a1 / d1 : 0.f) +
              (d2 > 0.f ? a2 / d2 : 0.f) + (d3 > 0.f ? a3 / d3 : 0.f) + bias[lane];
    float nr = v * v;
    #pragma unroll
    for (int s = 32; s; s >>= 1) nr += __shfl_xor(nr, s);
    float invn = 1.f / fmaxf(sqrtf(nr), 1e-8f);
    out[(size_t)n * 64 + lane] = v * invn;
}

// ---------------------------------------------------------------------------
extern "C" void kernel_launch(void* const* d_in, const int* in_sizes, int n_in,
                              void* d_out, int out_size, void* d_ws, size_t ws_size,
                              hipStream_t stream) {
    const float* h_l       = (const float*)d_in[0];
    const float* e_l       = (const float*)d_in[1];
    const int*   src       = (const int*)d_in[2];
    const int*   dst       = (const int*)d_in[3];
    const float* W_phi     = (const float*)d_in[4];
    const float* W1        = (const float*)d_in[5];
    const float* b1        = (const float*)d_in[6];
    const float* W2        = (const float*)d_in[7];
    const float* b2        = (const float*)d_in[8];
    const float* tilde_phi = (const float*)d_in[9];
    const float* W         = (const float*)d_in[10];
    const float* bias      = (const float*)d_in[11];
    float* out = (float*)d_out;
    float* lsep_ptr   = out + (size_t)NN * OUTD;
    float* lfocus_ptr = out + (size_t)NN * OUTD + 1;

    char* ws = (char*)d_ws;
    size_t off = 0;
    auto alloc = [&](size_t bytes) -> char* {
        char* p = ws + off;
        off += (bytes + 255) & ~(size_t)255;
        return p;
    };
    float*          phi     = (float*)alloc((size_t)NN * 16 * 4);
    float*          deltap  = (float*)alloc((size_t)NN * 64 * 4);
    unsigned char*  h8      = (unsigned char*)alloc((size_t)NN * 256);
    unsigned short* hid_bf  = (unsigned short*)alloc((size_t)NN * 256 * 2);
    int*            csr_src = (int*)alloc((size_t)EE * 4);
    int*            csr_dst = (int*)alloc((size_t)EE * 4);
    float*          csr_w   = (float*)alloc((size_t)EE * 4 * 4);
    int*            deg     = (int*)alloc((size_t)NN * 4);
    int*            offs    = (int*)alloc((size_t)(NN + 1) * 4);
    int*            cursor  = (int*)alloc((size_t)NN * 4);
    int*            bsum    = (int*)alloc((size_t)SCAN_NB * 4);
    unsigned short* W_t     = (unsigned short*)alloc(256 * 256 * 2);
    unsigned short* W1_bf   = (unsigned short*)alloc(256 * 128 * 2);
    unsigned short* W2_bf   = (unsigned short*)alloc(64 * 256 * 2);
    unsigned short* Wphi_t  = (unsigned short*)alloc(16 * 128 * 2);
    float*          tnorm   = (float*)alloc(64 * 4);

    hipMemsetAsync(deg, 0, (size_t)NN * 4, stream);

    tnorm_lsep_k<<<1, 64, 0, stream>>>(tilde_phi, tnorm, lsep_ptr);
    wprep_k<<<(116736 + 255) / 256, 256, 0, stream>>>(W, W1, W2, W_phi, W_t, W1_bf,
                                                      W2_bf, Wphi_t, lfocus_ptr);

    const int G64  = (NN + 63) / 64;      // 782 (64 rows/block)
    const int G256 = (NN + 255) / 256;    // 196 (256 rows/block)

    // hid = relu(e_l @ W1^T + b1) -> bf16     [64 rows x 256 cols per block]
    dgemm_k<128, 4, 4, 4, true, true, 1, false, false>
        <<<G64, 256, 0, stream>>>(e_l, W1_bf, b1, hid_bf, 256, nullptr, nullptr);
    // phi = e_l @ W_phi (16 cols, padded)     [256 rows x 16 cols per block]
    dgemm_k<128, 1, 4, 1, false, true, 0, false, false>
        <<<G256, 256, 0, stream>>>(e_l, Wphi_t, nullptr, phi, 16, nullptr, nullptr);
    // delta' = hid @ W2^T + b2 (+tnorm), l_focus  [256 rows x 64 cols]
    dgemm_k<256, 1, 4, 4, false, false, 0, true, true>
        <<<G256, 256, 0, stream>>>(hid_bf, W2_bf, b2, deltap, 64, lfocus_ptr, tnorm);
    // h = h_l @ W -> fp8, [ch][k]-interleaved [64 rows x 256 cols per block]
    dgemm_k<256, 4, 4, 4, false, true, 2, false, false>
        <<<G64, 256, 0, stream>>>(h_l, W_t, nullptr, h8, 256, nullptr, nullptr);

    // CSR build
    degree_k<<<3125, 256, 0, stream>>>(dst, deg);
    scan_partial_k<<<SCAN_NB, 256, 0, stream>>>(deg, bsum);
    scan_bsum_k<<<1, 256, 0, stream>>>(bsum);
    scan_scatter_k<<<SCAN_NB, 256, 0, stream>>>(deg, bsum, offs, cursor);
    scatter_src_k<<<3125, 256, 0, stream>>>(src, dst, cursor, csr_src, csr_dst);

    // edge weights (thread-per-slot, CSR-ordered)
    edge_w_k<<<3125, 256, 0, stream>>>(csr_src, csr_dst, phi, deltap, (float4*)csr_w);

    // per-dst single-pass softmax + aggregation + normalize
    aggregate_k<<<12500, 256, 0, stream>>>(offs, csr_src, (const float4*)csr_w,
                                           (const unsigned int*)h8, bias, out);
}

// Round 11
// 311.218 us; speedup vs baseline: 1.0147x; 1.0147x over previous
//
#include <hip/hip_runtime.h>
#include <math.h>

#define NN 50000
#define EE 800000

typedef __attribute__((ext_vector_type(8))) short short8;
typedef __attribute__((ext_vector_type(4))) float f32x4;

__device__ inline float b2f(unsigned short u) {
    union { unsigned i; float f; } v; v.i = ((unsigned)u) << 16; return v.f;
}
__device__ inline unsigned short f2b(float f) {
    unsigned u = __float_as_uint(f);
    unsigned r = (u + 0x7FFFu + ((u >> 16) & 1u)) >> 16;   // RNE
    return (unsigned short)r;
}
__device__ inline unsigned char f2fp8(float v) {
    return (unsigned char)(__builtin_amdgcn_cvt_pk_fp8_f32(v, v, 0, false) & 0xFF);
}
__device__ inline unsigned cvt_pk_bf16(float lo, float hi) {
    unsigned r;
    asm("v_cvt_pk_bf16_f32 %0, %1, %2" : "=v"(r) : "v"(lo), "v"(hi));
    return r;
}
// async global->LDS, 16B per lane; lds ptr must be wave-uniform base
__device__ inline void gload16(const unsigned short* g, unsigned short* l) {
    __builtin_amdgcn_global_load_lds(
        (const __attribute__((address_space(1))) void*)g,
        (__attribute__((address_space(3))) void*)l, 16, 0, 0);
}

// ---------------------------------------------------------------------------
// fused prep: tnorm+l_sep (block 0), weight preps, e_l/h_l -> bf16 casts,
// zero l_focus.
// index ranges: [0,65536) W_t perm | [.. +32768) W1 | [.. +16384) W2 |
// [.. +2048) Wphi pad | [.. +800000) e_l cast x8 | [.. +1600000) h_l cast x8
// ---------------------------------------------------------------------------
#define PREP_THREADS (65536 + 32768 + 16384 + 2048 + 800000 + 1600000)

__global__ __launch_bounds__(256) void prep_k(const float* __restrict__ W,
                                              const float* __restrict__ W1,
                                              const float* __restrict__ W2,
                                              const float* __restrict__ W_phi,
                                              const float* __restrict__ e_l,
                                              const float* __restrict__ h_l,
                                              const float* __restrict__ tilde_phi,
                                              unsigned short* __restrict__ W_t,
                                              unsigned short* __restrict__ W1_bf,
                                              unsigned short* __restrict__ W2_bf,
                                              unsigned short* __restrict__ Wphi_t,
                                              unsigned short* __restrict__ e_bf,
                                              unsigned short* __restrict__ hl_bf,
                                              float* __restrict__ tnorm,
                                              float* __restrict__ lsep_out,
                                              float* __restrict__ lfocus_zero) {
    if (blockIdx.x == 0) {
        __shared__ float tn[64];
        int t = threadIdx.x;
        if (t < 64) {
            float v = tilde_phi[t];
            float sq = v * v;
            #pragma unroll
            for (int s = 8; s; s >>= 1) sq += __shfl_xor(sq, s, 16);
            float tnv = v / sqrtf(sq);
            tn[t] = tnv;
            tnorm[t] = tnv;
        }
        __syncthreads();
        if (t == 0) {
            float tot = 0.f;
            for (int a = 0; a < 4; ++a)
                for (int b = 0; b < 4; ++b) {
                    float s2 = 0.f;
                    for (int p = 0; p < 16; ++p) {
                        float df = tn[a * 16 + p] - tn[b * 16 + p];
                        s2 += df * df;
                    }
                    tot += s2;
                }
            lsep_out[0] = tot * 0.25f;
            lfocus_zero[0] = 0.f;
        }
    }
    int i = blockIdx.x * 256 + threadIdx.x;
    if (i < 65536) {
        int cp = i >> 8, r = i & 255;
        int ch = cp >> 2, k = cp & 3;
        W_t[i] = f2b(W[(size_t)r * 256 + (k << 6) + ch]);
    } else if (i < 98304) {
        int j = i - 65536;
        W1_bf[j] = f2b(W1[j]);
    } else if (i < 114688) {
        int j = i - 98304;
        W2_bf[j] = f2b(W2[j]);
    } else if (i < 116736) {
        int j = i - 114688;
        int cp = j >> 7, r = j & 127;
        Wphi_t[j] = (cp < 15) ? f2b(W_phi[(size_t)r * 15 + cp]) : (unsigned short)0;
    } else if (i < 116736 + 800000) {
        int j = i - 116736;                        // 8 floats of e_l
        const float4* p = (const float4*)e_l + (size_t)j * 2;
        float4 f0 = p[0], f1 = p[1];
        ((uint4*)e_bf)[j] = make_uint4(cvt_pk_bf16(f0.x, f0.y), cvt_pk_bf16(f0.z, f0.w),
                                       cvt_pk_bf16(f1.x, f1.y), cvt_pk_bf16(f1.z, f1.w));
    } else if (i < 116736 + 800000 + 1600000) {
        int j = i - 916736;                        // 8 floats of h_l
        const float4* p = (const float4*)h_l + (size_t)j * 2;
        float4 f0 = p[0], f1 = p[1];
        ((uint4*)hl_bf)[j] = make_uint4(cvt_pk_bf16(f0.x, f0.y), cvt_pk_bf16(f0.z, f0.w),
                                        cvt_pk_bf16(f1.x, f1.y), cvt_pk_bf16(f1.z, f1.w));
    }
}

// ---------------------------------------------------------------------------
// m97-style GEMM: global_load_lds staging, [k-slice][row] LDS layout
// (conflict-free ds_read_b128), double-buffered, one barrier per K-step.
// A [*, KD] bf16; Bt [Ncols][KD] bf16. OMODE: 0=f32, 1=bf16, 2=fp8.
// ---------------------------------------------------------------------------
template <int KD, int BM, int BN, int WR, int WC, bool RELU, int OMODE,
          bool LFOCUS, bool TNADJ>
__global__ __launch_bounds__(256) void ggemm_k(const unsigned short* __restrict__ A,
                                               const unsigned short* __restrict__ Bt,
                                               const float* __restrict__ bias_vec,
                                               void* __restrict__ Cout, int ldc,
                                               float* __restrict__ lfocus_acc,
                                               const float* __restrict__ tn_vec) {
    const int AM = BM / (WR * 16), AN = BN / (WC * 16);
    __shared__ __align__(16) unsigned short As[2][BM * 32];
    __shared__ __align__(16) unsigned short Bs[2][BN * 32];
    const int tid = threadIdx.x;
    const int l = tid & 63;
    const int l15 = l & 15, l4 = l >> 4;
    const int w = tid >> 6;
    const int wr = w / WC, wc = w % WC;
    const int row0 = blockIdx.x * BM;
    const int col0 = blockIdx.y * BN;
    const int wrow = wr * AM * 16, wcol = wc * AN * 16;
    const int wbase = (tid & 192) * 8;          // wave-uniform ushort offset

    auto stageA = [&](int buf, int k0) {
        #pragma unroll
        for (int j = 0; j < BM / 64; ++j) {
            int o = j * 256 + tid;              // 16B-unit index
            int s = o / BM, r = o % BM;
            int gr = row0 + r; if (gr >= NN) gr = NN - 1;
            gload16(&A[(size_t)gr * KD + k0 + s * 8], &As[buf][j * 2048 + wbase]);
        }
    };
    auto stageB = [&](int buf, int k0) {
        if (BN >= 64) {
            #pragma unroll
            for (int j = 0; j < BN / 64; ++j) {
                int o = j * 256 + tid;
                int s = o / BN, r = o % BN;
                gload16(&Bt[(size_t)(col0 + r) * KD + k0 + s * 8],
                        &Bs[buf][j * 2048 + wbase]);
            }
        } else {                                 // BN==16: one wave covers 1 KB
            if (tid < 64) {
                int s = tid >> 4, r = tid & 15;
                gload16(&Bt[(size_t)r * KD + k0 + s * 8], &Bs[buf][0]);
            }
        }
    };

    f32x4 acc[AM][AN];
    #pragma unroll
    for (int m = 0; m < AM; ++m)
        #pragma unroll
        for (int n = 0; n < AN; ++n)
            acc[m][n] = (f32x4){0.f, 0.f, 0.f, 0.f};

    stageA(0, 0); stageB(0, 0);
    __syncthreads();
    int cur = 0;
    const int NT = KD / 32;
    for (int t = 0; t < NT; ++t) {
        if (t + 1 < NT) { stageA(cur ^ 1, (t + 1) * 32); stageB(cur ^ 1, (t + 1) * 32); }
        short8 af[AM], bfr[AN];
        #pragma unroll
        for (int m = 0; m < AM; ++m)
            af[m] = *(const short8*)&As[cur][(l4 * BM + wrow + m * 16 + l15) * 8];
        #pragma unroll
        for (int n = 0; n < AN; ++n)
            bfr[n] = *(const short8*)&Bs[cur][(l4 * BN + wcol + n * 16 + l15) * 8];
        #pragma unroll
        for (int m = 0; m < AM; ++m)
            #pragma unroll
            for (int n = 0; n < AN; ++n)
                acc[m][n] = __builtin_amdgcn_mfma_f32_16x16x32_bf16(af[m], bfr[n], acc[m][n], 0, 0, 0);
        if (t + 1 < NT) __syncthreads();
        cur ^= 1;
    }

    float lf = 0.f;
    // C/D layout: col=lane&15, row=(lane>>4)*4+reg
    #pragma unroll
    for (int m = 0; m < AM; ++m) {
        #pragma unroll
        for (int n = 0; n < AN; ++n) {
            int gc = col0 + wcol + n * 16 + l15;
            float bv = bias_vec ? bias_vec[gc] : 0.f;
            float tv = TNADJ ? tn_vec[gc] : 0.f;
            #pragma unroll
            for (int r = 0; r < 4; ++r) {
                int gr = row0 + wrow + m * 16 + l4 * 4 + r;
                if (gr >= NN) continue;
                float v = acc[m][n][r] + bv;
                if (RELU) v = fmaxf(v, 0.f);
                if (LFOCUS) lf += v * v;
                if (TNADJ) v += tv;
                if (OMODE == 0)
                    ((float*)Cout)[(size_t)gr * ldc + gc] = v;
                else if (OMODE == 1)
                    ((unsigned short*)Cout)[(size_t)gr * ldc + gc] = f2b(v);
                else
                    ((unsigned char*)Cout)[(size_t)gr * ldc + gc] = f2fp8(v);
            }
        }
    }
    if (LFOCUS) {
        #pragma unroll
        for (int s = 32; s; s >>= 1) lf += __shfl_xor(lf, s);
        if ((tid & 63) == 0)
            atomicAdd(lfocus_acc, lf * (1.f / ((float)NN * 4)));
    }
}

// ---------------------------------------------------------------------------
__global__ void degree_k(const int* __restrict__ dst, int* __restrict__ deg) {
    int e = blockIdx.x * 256 + threadIdx.x;
    if (e < EE) atomicAdd(&deg[dst[e]], 1);
}

#define SCAN_NB ((NN + 255) / 256)   // 196

__global__ __launch_bounds__(256) void scan_partial_k(const int* __restrict__ deg,
                                                      int* __restrict__ bsum) {
    __shared__ int ws_[4];
    int i = blockIdx.x * 256 + threadIdx.x;
    int v = (i < NN) ? deg[i] : 0;
    int x = v;
    #pragma unroll
    for (int s = 32; s; s >>= 1) x += __shfl_xor(x, s);
    if ((threadIdx.x & 63) == 0) ws_[threadIdx.x >> 6] = x;
    __syncthreads();
    if (threadIdx.x == 0) bsum[blockIdx.x] = ws_[0] + ws_[1] + ws_[2] + ws_[3];
}

__global__ __launch_bounds__(256) void scan_bsum_k(int* __restrict__ bsum) {
    __shared__ int sd[256];
    int t = threadIdx.x;
    int v = (t < SCAN_NB) ? bsum[t] : 0;
    sd[t] = v;
    __syncthreads();
    for (int s = 1; s < 256; s <<= 1) {
        int u = (t >= s) ? sd[t - s] : 0;
        __syncthreads();
        sd[t] += u;
        __syncthreads();
    }
    if (t < SCAN_NB) bsum[t] = sd[t] - v;   // exclusive
}

__global__ __launch_bounds__(256) void scan_scatter_k(const int* __restrict__ deg,
                                                      const int* __restrict__ bsum,
                                                      int* __restrict__ offs,
                                                      int* __restrict__ cursor) {
    __shared__ int wexc[4];
    int i = blockIdx.x * 256 + threadIdx.x;
    int lane = threadIdx.x & 63, wid = threadIdx.x >> 6;
    int v = (i < NN) ? deg[i] : 0;
    int x = v;
    #pragma unroll
    for (int d = 1; d < 64; d <<= 1) { int u = __shfl_up(x, d); if (lane >= d) x += u; }
    if (lane == 63) wexc[wid] = x;
    __syncthreads();
    if (threadIdx.x == 0) {
        int a = wexc[0], b = wexc[1], c = wexc[2];
        wexc[0] = 0; wexc[1] = a; wexc[2] = a + b; wexc[3] = a + b + c;
    }
    __syncthreads();
    int excl = (x - v) + wexc[wid] + bsum[blockIdx.x];
    if (i < NN) {
        cursor[i] = excl;
        offs[i + 1] = excl + v;
        if (i == 0) offs[0] = 0;
    }
}

__global__ void scatter_src_k(const int* __restrict__ src, const int* __restrict__ dst,
                              int* __restrict__ cursor, int* __restrict__ csr_src,
                              int* __restrict__ csr_dst) {
    int e = blockIdx.x * 256 + threadIdx.x;
    if (e >= EE) return;
    int d = dst[e];
    int pos = atomicAdd(&cursor[d], 1);
    csr_src[pos] = src[e];
    csr_dst[pos] = d;
}

// ---------------------------------------------------------------------------
// edge weights, thread per CSR slot. delta' already includes tnorm.
// ---------------------------------------------------------------------------
__global__ __launch_bounds__(256) void edge_w_k(const int* __restrict__ csr_src,
                                                const int* __restrict__ csr_dst,
                                                const float* __restrict__ phi,
                                                const float* __restrict__ deltap,
                                                float4* __restrict__ csr_w) {
    int e = blockIdx.x * 256 + threadIdx.x;
    if (e >= EE) return;
    int s = csr_src[e], d = csr_dst[e];
    const float4* ps4 = (const float4*)(phi + (size_t)s * 16);
    const float4* pd4 = (const float4*)(phi + (size_t)d * 16);
    float dv[16];
    float nrm2 = 0.f;
    #pragma unroll
    for (int q = 0; q < 4; ++q) {
        float4 a = ps4[q], b = pd4[q];
        dv[q * 4 + 0] = a.x - b.x;
        dv[q * 4 + 1] = a.y - b.y;
        dv[q * 4 + 2] = a.z - b.z;
        dv[q * 4 + 3] = a.w - b.w;
    }
    #pragma unroll
    for (int p = 0; p < 15; ++p) nrm2 += dv[p] * dv[p];
    float z = (nrm2 == 0.f) ? 1.f : 0.f;
    dv[15] = z;
    nrm2 += z;
    float inv = 1.f / fmaxf(sqrtf(nrm2), 1e-8f);
    const float* dl = deltap + (size_t)d * 64;
    float res[4];
    #pragma unroll
    for (int k = 0; k < 4; ++k) {
        const float4* dk = (const float4*)(dl + k * 16);
        float sacc = 0.f;
        #pragma unroll
        for (int q = 0; q < 4; ++q) {
            float4 tv = dk[q];
            sacc += dv[q * 4 + 0] * tv.x;
            sacc += dv[q * 4 + 1] * tv.y;
            sacc += dv[q * 4 + 2] * tv.z;
            sacc += dv[q * 4 + 3] * tv.w;
        }
        res[k] = sacc * inv;
    }
    csr_w[e] = make_float4(__expf(res[0]), __expf(res[1]),
                           __expf(res[2]), __expf(res[3]));
}

// ---------------------------------------------------------------------------
// per-dst single-pass aggregation. Wave per node, lane = channel.
// h is fp8 [node][ch][k]: one uint (4 fp8) gather per lane per edge.
// ---------------------------------------------------------------------------
__global__ __launch_bounds__(256) void aggregate_k(const int* __restrict__ offs,
                                                   const int* __restrict__ csr_src,
                                                   const float4* __restrict__ csr_w,
                                                   const unsigned int* __restrict__ h8,
                                                   const float* __restrict__ bias,
                                                   float* __restrict__ out) {
    int wave = threadIdx.x >> 6;
    int lane = threadIdx.x & 63;
    int n = blockIdx.x * 4 + wave;
    if (n >= NN) return;
    int beg = offs[n], end = offs[n + 1];

    float a0 = 0.f, a1 = 0.f, a2 = 0.f, a3 = 0.f;
    float d0 = 0.f, d1 = 0.f, d2 = 0.f, d3 = 0.f;
    int p = beg;
    for (; p + 3 < end; p += 4) {
        float4 w0 = csr_w[p], w1 = csr_w[p + 1], w2 = csr_w[p + 2], w3 = csr_w[p + 3];
        int s0 = csr_src[p], s1 = csr_src[p + 1], s2 = csr_src[p + 2], s3 = csr_src[p + 3];
        unsigned hv0 = h8[(size_t)s0 * 64 + lane];
        unsigned hv1 = h8[(size_t)s1 * 64 + lane];
        unsigned hv2 = h8[(size_t)s2 * 64 + lane];
        unsigned hv3 = h8[(size_t)s3 * 64 + lane];
        d0 += (w0.x + w1.x) + (w2.x + w3.x);
        d1 += (w0.y + w1.y) + (w2.y + w3.y);
        d2 += (w0.z + w1.z) + (w2.z + w3.z);
        d3 += (w0.w + w1.w) + (w2.w + w3.w);
        a0 += w0.x * __builtin_amdgcn_cvt_f32_fp8(hv0, 0) + w1.x * __builtin_amdgcn_cvt_f32_fp8(hv1, 0)
            + w2.x * __builtin_amdgcn_cvt_f32_fp8(hv2, 0) + w3.x * __builtin_amdgcn_cvt_f32_fp8(hv3, 0);
        a1 += w0.y * __builtin_amdgcn_cvt_f32_fp8(hv0, 1) + w1.y * __builtin_amdgcn_cvt_f32_fp8(hv1, 1)
            + w2.y * __builtin_amdgcn_cvt_f32_fp8(hv2, 1) + w3.y * __builtin_amdgcn_cvt_f32_fp8(hv3, 1);
        a2 += w0.z * __builtin_amdgcn_cvt_f32_fp8(hv0, 2) + w1.z * __builtin_amdgcn_cvt_f32_fp8(hv1, 2)
            + w2.z * __builtin_amdgcn_cvt_f32_fp8(hv2, 2) + w3.z * __builtin_amdgcn_cvt_f32_fp8(hv3, 2);
        a3 += w0.w * __builtin_amdgcn_cvt_f32_fp8(hv0, 3) + w1.w * __builtin_amdgcn_cvt_f32_fp8(hv1, 3)
            + w2.w * __builtin_amdgcn_cvt_f32_fp8(hv2, 3) + w3.w * __builtin_amdgcn_cvt_f32_fp8(hv3, 3);
    }
    for (; p < end; ++p) {
        float4 wA = csr_w[p];
        int sA = csr_src[p];
        unsigned hv = h8[(size_t)sA * 64 + lane];
        d0 += wA.x; d1 += wA.y; d2 += wA.z; d3 += wA.w;
        a0 += wA.x * __builtin_amdgcn_cvt_f32_fp8(hv, 0);
        a1 += wA.y * __builtin_amdgcn_cvt_f32_fp8(hv, 1);
        a2 += wA.z * __builtin_amdgcn_cvt_f32_fp8(hv, 2);
        a3 += wA.w * __builtin_amdgcn_cvt_f32_fp8(hv, 3);
    }
    float v = (d0 > 0.f ? a0 / d0 : 0.f) + (d1 > 0.f ? a1 / d1 : 0.f) +
              (d2 > 0.f ? a2 / d2 : 0.f) + (d3 > 0.f ? a3 / d3 : 0.f) + bias[lane];
    float nr = v * v;
    #pragma unroll
    for (int s = 32; s; s >>= 1) nr += __shfl_xor(nr, s);
    float invn = 1.f / fmaxf(sqrtf(nr), 1e-8f);
    out[(size_t)n * 64 + lane] = v * invn;
}

// ---------------------------------------------------------------------------
extern "C" void kernel_launch(void* const* d_in, const int* in_sizes, int n_in,
                              void* d_out, int out_size, void* d_ws, size_t ws_size,
                              hipStream_t stream) {
    const float* h_l       = (const float*)d_in[0];
    const float* e_l       = (const float*)d_in[1];
    const int*   src       = (const int*)d_in[2];
    const int*   dst       = (const int*)d_in[3];
    const float* W_phi     = (const float*)d_in[4];
    const float* W1        = (const float*)d_in[5];
    const float* b1        = (const float*)d_in[6];
    const float* W2        = (const float*)d_in[7];
    const float* b2        = (const float*)d_in[8];
    const float* tilde_phi = (const float*)d_in[9];
    const float* W         = (const float*)d_in[10];
    const float* bias      = (const float*)d_in[11];
    float* out = (float*)d_out;
    float* lsep_ptr   = out + (size_t)NN * 64;
    float* lfocus_ptr = out + (size_t)NN * 64 + 1;

    char* ws = (char*)d_ws;
    size_t off = 0;
    auto alloc = [&](size_t bytes) -> char* {
        char* p = ws + off;
        off += (bytes + 255) & ~(size_t)255;
        return p;
    };
    float*          phi     = (float*)alloc((size_t)NN * 16 * 4);
    float*          deltap  = (float*)alloc((size_t)NN * 64 * 4);
    unsigned char*  h8      = (unsigned char*)alloc((size_t)NN * 256);
    unsigned short* hid_bf  = (unsigned short*)alloc((size_t)NN * 256 * 2);
    unsigned short* e_bf    = (unsigned short*)alloc((size_t)NN * 128 * 2);
    unsigned short* hl_bf   = (unsigned short*)alloc((size_t)NN * 256 * 2);
    int*            csr_src = (int*)alloc((size_t)EE * 4);
    int*            csr_dst = (int*)alloc((size_t)EE * 4);
    float*          csr_w   = (float*)alloc((size_t)EE * 4 * 4);
    int*            deg     = (int*)alloc((size_t)NN * 4);
    int*            offs    = (int*)alloc((size_t)(NN + 1) * 4);
    int*            cursor  = (int*)alloc((size_t)NN * 4);
    int*            bsum    = (int*)alloc((size_t)SCAN_NB * 4);
    unsigned short* W_t     = (unsigned short*)alloc(256 * 256 * 2);
    unsigned short* W1_bf   = (unsigned short*)alloc(256 * 128 * 2);
    unsigned short* W2_bf   = (unsigned short*)alloc(64 * 256 * 2);
    unsigned short* Wphi_t  = (unsigned short*)alloc(16 * 128 * 2);
    float*          tnorm   = (float*)alloc(64 * 4);

    hipMemsetAsync(deg, 0, (size_t)NN * 4, stream);

    // fused prep: tnorm/lsep + weight preps + bf16 casts + lfocus zero
    prep_k<<<(PREP_THREADS + 255) / 256, 256, 0, stream>>>(
        W, W1, W2, W_phi, e_l, h_l, tilde_phi,
        W_t, W1_bf, W2_bf, Wphi_t, e_bf, hl_bf, tnorm, lsep_ptr, lfocus_ptr);

    // hid = relu(e_l @ W1^T + b1) -> bf16      [128x128 tiles, grid 391x2]
    ggemm_k<128, 128, 128, 2, 2, true, 1, false, false>
        <<<dim3(391, 2), 256, 0, stream>>>(e_bf, W1_bf, b1, hid_bf, 256, nullptr, nullptr);
    // phi = e_l @ W_phi (16 cols, padded) -> f32  [128x16, grid 391]
    ggemm_k<128, 128, 16, 4, 1, false, 0, false, false>
        <<<dim3(391, 1), 256, 0, stream>>>(e_bf, Wphi_t, nullptr, phi, 16, nullptr, nullptr);
    // delta' = hid @ W2^T + b2 (+tnorm), l_focus -> f32  [64x64, grid 782]
    ggemm_k<256, 64, 64, 2, 2, false, 0, true, true>
        <<<dim3(782, 1), 256, 0, stream>>>(hid_bf, W2_bf, b2, deltap, 64, lfocus_ptr, tnorm);
    // h = h_l @ W -> fp8, [ch][k]-interleaved  [128x128, grid 391x2]
    ggemm_k<256, 128, 128, 2, 2, false, 2, false, false>
        <<<dim3(391, 2), 256, 0, stream>>>(hl_bf, W_t, nullptr, h8, 256, nullptr, nullptr);

    // CSR build
    degree_k<<<3125, 256, 0, stream>>>(dst, deg);
    scan_partial_k<<<SCAN_NB, 256, 0, stream>>>(deg, bsum);
    scan_bsum_k<<<1, 256, 0, stream>>>(bsum);
    scan_scatter_k<<<SCAN_NB, 256, 0, stream>>>(deg, bsum, offs, cursor);
    scatter_src_k<<<3125, 256, 0, stream>>>(src, dst, cursor, csr_src, csr_dst);

    // edge weights (thread-per-slot, CSR-ordered)
    edge_w_k<<<3125, 256, 0, stream>>>(csr_src, csr_dst, phi, deltap, (float4*)csr_w);

    // per-dst single-pass softmax + aggregation + normalize
    aggregate_k<<<12500, 256, 0, stream>>>(offs, csr_src, (const float4*)csr_w,
                                           (const unsigned int*)h8, bias, out);
}

// Round 12
// 309.078 us; speedup vs baseline: 1.0217x; 1.0069x over previous
//
#include <hip/hip_runtime.h>
#include <math.h>

#define NN 50000
#define EE 800000

typedef __attribute__((ext_vector_type(8))) short short8;
typedef __attribute__((ext_vector_type(4))) float f32x4;
typedef __attribute__((ext_vector_type(2))) float f32x2;

__device__ inline float b2f(unsigned short u) {
    union { unsigned i; float f; } v; v.i = ((unsigned)u) << 16; return v.f;
}
__device__ inline unsigned short f2b(float f) {
    unsigned u = __float_as_uint(f);
    unsigned r = (u + 0x7FFFu + ((u >> 16) & 1u)) >> 16;   // RNE
    return (unsigned short)r;
}
__device__ inline unsigned char f2fp8(float v) {
    return (unsigned char)(__builtin_amdgcn_cvt_pk_fp8_f32(v, v, 0, false) & 0xFF);
}
__device__ inline unsigned cvt_pk_bf16(float lo, float hi) {
    unsigned r;
    asm("v_cvt_pk_bf16_f32 %0, %1, %2" : "=v"(r) : "v"(lo), "v"(hi));
    return r;
}
// async global->LDS, 16B per lane; lds ptr must be wave-uniform base
__device__ inline void gload16(const unsigned short* g, unsigned short* l) {
    __builtin_amdgcn_global_load_lds(
        (const __attribute__((address_space(1))) void*)g,
        (__attribute__((address_space(3))) void*)l, 16, 0, 0);
}

// ---------------------------------------------------------------------------
// fused prep: tnorm+l_sep (block 0), weight preps, e_l/h_l -> bf16 casts,
// zero l_focus.
// ---------------------------------------------------------------------------
#define PREP_THREADS (65536 + 32768 + 16384 + 2048 + 800000 + 1600000)

__global__ __launch_bounds__(256) void prep_k(const float* __restrict__ W,
                                              const float* __restrict__ W1,
                                              const float* __restrict__ W2,
                                              const float* __restrict__ W_phi,
                                              const float* __restrict__ e_l,
                                              const float* __restrict__ h_l,
                                              const float* __restrict__ tilde_phi,
                                              unsigned short* __restrict__ W_t,
                                              unsigned short* __restrict__ W1_bf,
                                              unsigned short* __restrict__ W2_bf,
                                              unsigned short* __restrict__ Wphi_t,
                                              unsigned short* __restrict__ e_bf,
                                              unsigned short* __restrict__ hl_bf,
                                              float* __restrict__ tnorm,
                                              float* __restrict__ lsep_out,
                                              float* __restrict__ lfocus_zero) {
    if (blockIdx.x == 0) {
        __shared__ float tn[64];
        int t = threadIdx.x;
        if (t < 64) {
            float v = tilde_phi[t];
            float sq = v * v;
            #pragma unroll
            for (int s = 8; s; s >>= 1) sq += __shfl_xor(sq, s, 16);
            float tnv = v / sqrtf(sq);
            tn[t] = tnv;
            tnorm[t] = tnv;
        }
        __syncthreads();
        if (t == 0) {
            float tot = 0.f;
            for (int a = 0; a < 4; ++a)
                for (int b = 0; b < 4; ++b) {
                    float s2 = 0.f;
                    for (int p = 0; p < 16; ++p) {
                        float df = tn[a * 16 + p] - tn[b * 16 + p];
                        s2 += df * df;
                    }
                    tot += s2;
                }
            lsep_out[0] = tot * 0.25f;
            lfocus_zero[0] = 0.f;
        }
    }
    int i = blockIdx.x * 256 + threadIdx.x;
    if (i < 65536) {
        int cp = i >> 8, r = i & 255;
        int ch = cp >> 2, k = cp & 3;
        W_t[i] = f2b(W[(size_t)r * 256 + (k << 6) + ch]);
    } else if (i < 98304) {
        int j = i - 65536;
        W1_bf[j] = f2b(W1[j]);
    } else if (i < 114688) {
        int j = i - 98304;
        W2_bf[j] = f2b(W2[j]);
    } else if (i < 116736) {
        int j = i - 114688;
        int cp = j >> 7, r = j & 127;
        Wphi_t[j] = (cp < 15) ? f2b(W_phi[(size_t)r * 15 + cp]) : (unsigned short)0;
    } else if (i < 116736 + 800000) {
        int j = i - 116736;
        const float4* p = (const float4*)e_l + (size_t)j * 2;
        float4 f0 = p[0], f1 = p[1];
        ((uint4*)e_bf)[j] = make_uint4(cvt_pk_bf16(f0.x, f0.y), cvt_pk_bf16(f0.z, f0.w),
                                       cvt_pk_bf16(f1.x, f1.y), cvt_pk_bf16(f1.z, f1.w));
    } else if (i < 116736 + 800000 + 1600000) {
        int j = i - 916736;
        const float4* p = (const float4*)h_l + (size_t)j * 2;
        float4 f0 = p[0], f1 = p[1];
        ((uint4*)hl_bf)[j] = make_uint4(cvt_pk_bf16(f0.x, f0.y), cvt_pk_bf16(f0.z, f0.w),
                                        cvt_pk_bf16(f1.x, f1.y), cvt_pk_bf16(f1.z, f1.w));
    }
}

// ---------------------------------------------------------------------------
// m97-style GEMM: global_load_lds staging, [k-slice][row] LDS layout
// (conflict-free ds_read_b128), double-buffered, one barrier per K-step.
// ---------------------------------------------------------------------------
template <int KD, int BM, int BN, int WR, int WC, bool RELU, int OMODE,
          bool LFOCUS, bool TNADJ>
__global__ __launch_bounds__(256) void ggemm_k(const unsigned short* __restrict__ A,
                                               const unsigned short* __restrict__ Bt,
                                               const float* __restrict__ bias_vec,
                                               void* __restrict__ Cout, int ldc,
                                               float* __restrict__ lfocus_acc,
                                               const float* __restrict__ tn_vec) {
    const int AM = BM / (WR * 16), AN = BN / (WC * 16);
    __shared__ __align__(16) unsigned short As[2][BM * 32];
    __shared__ __align__(16) unsigned short Bs[2][BN * 32];
    const int tid = threadIdx.x;
    const int l = tid & 63;
    const int l15 = l & 15, l4 = l >> 4;
    const int w = tid >> 6;
    const int wr = w / WC, wc = w % WC;
    const int row0 = blockIdx.x * BM;
    const int col0 = blockIdx.y * BN;
    const int wrow = wr * AM * 16, wcol = wc * AN * 16;
    const int wbase = (tid & 192) * 8;

    auto stageA = [&](int buf, int k0) {
        #pragma unroll
        for (int j = 0; j < BM / 64; ++j) {
            int o = j * 256 + tid;
            int s = o / BM, r = o % BM;
            int gr = row0 + r; if (gr >= NN) gr = NN - 1;
            gload16(&A[(size_t)gr * KD + k0 + s * 8], &As[buf][j * 2048 + wbase]);
        }
    };
    auto stageB = [&](int buf, int k0) {
        if (BN >= 64) {
            #pragma unroll
            for (int j = 0; j < BN / 64; ++j) {
                int o = j * 256 + tid;
                int s = o / BN, r = o % BN;
                gload16(&Bt[(size_t)(col0 + r) * KD + k0 + s * 8],
                        &Bs[buf][j * 2048 + wbase]);
            }
        } else {
            if (tid < 64) {
                int s = tid >> 4, r = tid & 15;
                gload16(&Bt[(size_t)r * KD + k0 + s * 8], &Bs[buf][0]);
            }
        }
    };

    f32x4 acc[AM][AN];
    #pragma unroll
    for (int m = 0; m < AM; ++m)
        #pragma unroll
        for (int n = 0; n < AN; ++n)
            acc[m][n] = (f32x4){0.f, 0.f, 0.f, 0.f};

    stageA(0, 0); stageB(0, 0);
    __syncthreads();
    int cur = 0;
    const int NT = KD / 32;
    for (int t = 0; t < NT; ++t) {
        if (t + 1 < NT) { stageA(cur ^ 1, (t + 1) * 32); stageB(cur ^ 1, (t + 1) * 32); }
        short8 af[AM], bfr[AN];
        #pragma unroll
        for (int m = 0; m < AM; ++m)
            af[m] = *(const short8*)&As[cur][(l4 * BM + wrow + m * 16 + l15) * 8];
        #pragma unroll
        for (int n = 0; n < AN; ++n)
            bfr[n] = *(const short8*)&Bs[cur][(l4 * BN + wcol + n * 16 + l15) * 8];
        #pragma unroll
        for (int m = 0; m < AM; ++m)
            #pragma unroll
            for (int n = 0; n < AN; ++n)
                acc[m][n] = __builtin_amdgcn_mfma_f32_16x16x32_bf16(af[m], bfr[n], acc[m][n], 0, 0, 0);
        if (t + 1 < NT) __syncthreads();
        cur ^= 1;
    }

    float lf = 0.f;
    #pragma unroll
    for (int m = 0; m < AM; ++m) {
        #pragma unroll
        for (int n = 0; n < AN; ++n) {
            int gc = col0 + wcol + n * 16 + l15;
            float bv = bias_vec ? bias_vec[gc] : 0.f;
            float tv = TNADJ ? tn_vec[gc] : 0.f;
            #pragma unroll
            for (int r = 0; r < 4; ++r) {
                int gr = row0 + wrow + m * 16 + l4 * 4 + r;
                if (gr >= NN) continue;
                float v = acc[m][n][r] + bv;
                if (RELU) v = fmaxf(v, 0.f);
                if (LFOCUS) lf += v * v;
                if (TNADJ) v += tv;
                if (OMODE == 0)
                    ((float*)Cout)[(size_t)gr * ldc + gc] = v;
                else if (OMODE == 1)
                    ((unsigned short*)Cout)[(size_t)gr * ldc + gc] = f2b(v);
                else
                    ((unsigned char*)Cout)[(size_t)gr * ldc + gc] = f2fp8(v);
            }
        }
    }
    if (LFOCUS) {
        #pragma unroll
        for (int s = 32; s; s >>= 1) lf += __shfl_xor(lf, s);
        if ((tid & 63) == 0)
            atomicAdd(lfocus_acc, lf * (1.f / ((float)NN * 4)));
    }
}

// ---------------------------------------------------------------------------
__global__ void degree_k(const int* __restrict__ dst, int* __restrict__ deg) {
    int e = blockIdx.x * 256 + threadIdx.x;
    if (e < EE) atomicAdd(&deg[dst[e]], 1);
}

#define SCAN_NB ((NN + 255) / 256)   // 196

__global__ __launch_bounds__(256) void scan_partial_k(const int* __restrict__ deg,
                                                      int* __restrict__ bsum) {
    __shared__ int ws_[4];
    int i = blockIdx.x * 256 + threadIdx.x;
    int v = (i < NN) ? deg[i] : 0;
    int x = v;
    #pragma unroll
    for (int s = 32; s; s >>= 1) x += __shfl_xor(x, s);
    if ((threadIdx.x & 63) == 0) ws_[threadIdx.x >> 6] = x;
    __syncthreads();
    if (threadIdx.x == 0) bsum[blockIdx.x] = ws_[0] + ws_[1] + ws_[2] + ws_[3];
}

__global__ __launch_bounds__(256) void scan_bsum_k(int* __restrict__ bsum) {
    __shared__ int sd[256];
    int t = threadIdx.x;
    int v = (t < SCAN_NB) ? bsum[t] : 0;
    sd[t] = v;
    __syncthreads();
    for (int s = 1; s < 256; s <<= 1) {
        int u = (t >= s) ? sd[t - s] : 0;
        __syncthreads();
        sd[t] += u;
        __syncthreads();
    }
    if (t < SCAN_NB) bsum[t] = sd[t] - v;   // exclusive
}

__global__ __launch_bounds__(256) void scan_scatter_k(const int* __restrict__ deg,
                                                      const int* __restrict__ bsum,
                                                      int* __restrict__ offs,
                                                      int* __restrict__ cursor) {
    __shared__ int wexc[4];
    int i = blockIdx.x * 256 + threadIdx.x;
    int lane = threadIdx.x & 63, wid = threadIdx.x >> 6;
    int v = (i < NN) ? deg[i] : 0;
    int x = v;
    #pragma unroll
    for (int d = 1; d < 64; d <<= 1) { int u = __shfl_up(x, d); if (lane >= d) x += u; }
    if (lane == 63) wexc[wid] = x;
    __syncthreads();
    if (threadIdx.x == 0) {
        int a = wexc[0], b = wexc[1], c = wexc[2];
        wexc[0] = 0; wexc[1] = a; wexc[2] = a + b; wexc[3] = a + b + c;
    }
    __syncthreads();
    int excl = (x - v) + wexc[wid] + bsum[blockIdx.x];
    if (i < NN) {
        cursor[i] = excl;
        offs[i + 1] = excl + v;
        if (i == 0) offs[0] = 0;
    }
}

__global__ void scatter_src_k(const int* __restrict__ src, const int* __restrict__ dst,
                              int* __restrict__ cursor, int* __restrict__ csr_src,
                              int* __restrict__ csr_dst) {
    int e = blockIdx.x * 256 + threadIdx.x;
    if (e >= EE) return;
    int d = dst[e];
    int pos = atomicAdd(&cursor[d], 1);
    csr_src[pos] = src[e];
    csr_dst[pos] = d;
}

// ---------------------------------------------------------------------------
// edge weights, thread per CSR slot. delta' already includes tnorm.
// ---------------------------------------------------------------------------
__global__ __launch_bounds__(256) void edge_w_k(const int* __restrict__ csr_src,
                                                const int* __restrict__ csr_dst,
                                                const float* __restrict__ phi,
                                                const float* __restrict__ deltap,
                                                float4* __restrict__ csr_w) {
    int e = blockIdx.x * 256 + threadIdx.x;
    if (e >= EE) return;
    int s = csr_src[e], d = csr_dst[e];
    const float4* ps4 = (const float4*)(phi + (size_t)s * 16);
    const float4* pd4 = (const float4*)(phi + (size_t)d * 16);
    float dv[16];
    float nrm2 = 0.f;
    #pragma unroll
    for (int q = 0; q < 4; ++q) {
        float4 a = ps4[q], b = pd4[q];
        dv[q * 4 + 0] = a.x - b.x;
        dv[q * 4 + 1] = a.y - b.y;
        dv[q * 4 + 2] = a.z - b.z;
        dv[q * 4 + 3] = a.w - b.w;
    }
    #pragma unroll
    for (int p = 0; p < 15; ++p) nrm2 += dv[p] * dv[p];
    float z = (nrm2 == 0.f) ? 1.f : 0.f;
    dv[15] = z;
    nrm2 += z;
    float inv = 1.f / fmaxf(sqrtf(nrm2), 1e-8f);
    const float* dl = deltap + (size_t)d * 64;
    float res[4];
    #pragma unroll
    for (int k = 0; k < 4; ++k) {
        const float4* dk = (const float4*)(dl + k * 16);
        float sacc = 0.f;
        #pragma unroll
        for (int q = 0; q < 4; ++q) {
            float4 tv = dk[q];
            sacc += dv[q * 4 + 0] * tv.x;
            sacc += dv[q * 4 + 1] * tv.y;
            sacc += dv[q * 4 + 2] * tv.z;
            sacc += dv[q * 4 + 3] * tv.w;
        }
        res[k] = sacc * inv;
    }
    csr_w[e] = make_float4(__expf(res[0]), __expf(res[1]),
                           __expf(res[2]), __expf(res[3]));
}

// ---------------------------------------------------------------------------
// per-dst aggregation, wave per node, lane = channel.
// Phase 1: softmax denominators via coalesced flat read + k-class shfl reduce.
// Phase 2: accumulate w*h with packed fp8 decode; scale by inv-den at end.
// ---------------------------------------------------------------------------
__global__ __launch_bounds__(256) void aggregate_k(const int* __restrict__ offs,
                                                   const int* __restrict__ csr_src,
                                                   const float* __restrict__ csr_wf,
                                                   const unsigned int* __restrict__ h8,
                                                   const float* __restrict__ bias,
                                                   float* __restrict__ out) {
    int wave = threadIdx.x >> 6;
    int lane = threadIdx.x & 63;
    int n = blockIdx.x * 4 + wave;
    if (n >= NN) return;
    int beg = offs[n], end = offs[n + 1];

    // phase 1: den_k. lane covers flat positions q = beg*4+lane, +64, ...
    // q % 4 == lane % 4 always -> lane's partial belongs to k-class lane&3.
    float part = 0.f;
    for (int q = beg * 4 + lane; q < end * 4; q += 64) part += csr_wf[q];
    #pragma unroll
    for (int s = 4; s < 64; s <<= 1) part += __shfl_xor(part, s);
    float inv = (part > 0.f) ? 1.f / part : 0.f;
    float i0 = __shfl(inv, 0), i1 = __shfl(inv, 1);
    float i2 = __shfl(inv, 2), i3 = __shfl(inv, 3);

    // phase 2: weighted accumulation
    const float4* csr_w = (const float4*)csr_wf;
    float a0 = 0.f, a1 = 0.f, a2 = 0.f, a3 = 0.f;
    int p = beg;
    for (; p + 3 < end; p += 4) {
        float4 w0 = csr_w[p], w1 = csr_w[p + 1], w2 = csr_w[p + 2], w3 = csr_w[p + 3];
        int s0 = csr_src[p], s1 = csr_src[p + 1], s2 = csr_src[p + 2], s3 = csr_src[p + 3];
        unsigned hv0 = h8[(size_t)s0 * 64 + lane];
        unsigned hv1 = h8[(size_t)s1 * 64 + lane];
        unsigned hv2 = h8[(size_t)s2 * 64 + lane];
        unsigned hv3 = h8[(size_t)s3 * 64 + lane];
        f32x2 lo, hi;
        lo = __builtin_amdgcn_cvt_pk_f32_fp8(hv0, false);
        hi = __builtin_amdgcn_cvt_pk_f32_fp8(hv0, true);
        a0 += w0.x * lo.x; a1 += w0.y * lo.y; a2 += w0.z * hi.x; a3 += w0.w * hi.y;
        lo = __builtin_amdgcn_cvt_pk_f32_fp8(hv1, false);
        hi = __builtin_amdgcn_cvt_pk_f32_fp8(hv1, true);
        a0 += w1.x * lo.x; a1 += w1.y * lo.y; a2 += w1.z * hi.x; a3 += w1.w * hi.y;
        lo = __builtin_amdgcn_cvt_pk_f32_fp8(hv2, false);
        hi = __builtin_amdgcn_cvt_pk_f32_fp8(hv2, true);
        a0 += w2.x * lo.x; a1 += w2.y * lo.y; a2 += w2.z * hi.x; a3 += w2.w * hi.y;
        lo = __builtin_amdgcn_cvt_pk_f32_fp8(hv3, false);
        hi = __builtin_amdgcn_cvt_pk_f32_fp8(hv3, true);
        a0 += w3.x * lo.x; a1 += w3.y * lo.y; a2 += w3.z * hi.x; a3 += w3.w * hi.y;
    }
    for (; p < end; ++p) {
        float4 wA = csr_w[p];
        int sA = csr_src[p];
        unsigned hv = h8[(size_t)sA * 64 + lane];
        f32x2 lo = __builtin_amdgcn_cvt_pk_f32_fp8(hv, false);
        f32x2 hi = __builtin_amdgcn_cvt_pk_f32_fp8(hv, true);
        a0 += wA.x * lo.x; a1 += wA.y * lo.y; a2 += wA.z * hi.x; a3 += wA.w * hi.y;
    }
    float v = a0 * i0 + a1 * i1 + a2 * i2 + a3 * i3 + bias[lane];
    float nr = v * v;
    #pragma unroll
    for (int s = 32; s; s >>= 1) nr += __shfl_xor(nr, s);
    float invn = 1.f / fmaxf(sqrtf(nr), 1e-8f);
    out[(size_t)n * 64 + lane] = v * invn;
}

// ---------------------------------------------------------------------------
extern "C" void kernel_launch(void* const* d_in, const int* in_sizes, int n_in,
                              void* d_out, int out_size, void* d_ws, size_t ws_size,
                              hipStream_t stream) {
    const float* h_l       = (const float*)d_in[0];
    const float* e_l       = (const float*)d_in[1];
    const int*   src       = (const int*)d_in[2];
    const int*   dst       = (const int*)d_in[3];
    const float* W_phi     = (const float*)d_in[4];
    const float* W1        = (const float*)d_in[5];
    const float* b1        = (const float*)d_in[6];
    const float* W2        = (const float*)d_in[7];
    const float* b2        = (const float*)d_in[8];
    const float* tilde_phi = (const float*)d_in[9];
    const float* W         = (const float*)d_in[10];
    const float* bias      = (const float*)d_in[11];
    float* out = (float*)d_out;
    float* lsep_ptr   = out + (size_t)NN * 64;
    float* lfocus_ptr = out + (size_t)NN * 64 + 1;

    char* ws = (char*)d_ws;
    size_t off = 0;
    auto alloc = [&](size_t bytes) -> char* {
        char* p = ws + off;
        off += (bytes + 255) & ~(size_t)255;
        return p;
    };
    float*          phi     = (float*)alloc((size_t)NN * 16 * 4);
    float*          deltap  = (float*)alloc((size_t)NN * 64 * 4);
    unsigned char*  h8      = (unsigned char*)alloc((size_t)NN * 256);
    unsigned short* hid_bf  = (unsigned short*)alloc((size_t)NN * 256 * 2);
    unsigned short* e_bf    = (unsigned short*)alloc((size_t)NN * 128 * 2);
    unsigned short* hl_bf   = (unsigned short*)alloc((size_t)NN * 256 * 2);
    int*            csr_src = (int*)alloc((size_t)EE * 4);
    int*            csr_dst = (int*)alloc((size_t)EE * 4);
    float*          csr_w   = (float*)alloc((size_t)EE * 4 * 4);
    int*            deg     = (int*)alloc((size_t)NN * 4);
    int*            offs    = (int*)alloc((size_t)(NN + 1) * 4);
    int*            cursor  = (int*)alloc((size_t)NN * 4);
    int*            bsum    = (int*)alloc((size_t)SCAN_NB * 4);
    unsigned short* W_t     = (unsigned short*)alloc(256 * 256 * 2);
    unsigned short* W1_bf   = (unsigned short*)alloc(256 * 128 * 2);
    unsigned short* W2_bf   = (unsigned short*)alloc(64 * 256 * 2);
    unsigned short* Wphi_t  = (unsigned short*)alloc(16 * 128 * 2);
    float*          tnorm   = (float*)alloc(64 * 4);

    hipMemsetAsync(deg, 0, (size_t)NN * 4, stream);

    prep_k<<<(PREP_THREADS + 255) / 256, 256, 0, stream>>>(
        W, W1, W2, W_phi, e_l, h_l, tilde_phi,
        W_t, W1_bf, W2_bf, Wphi_t, e_bf, hl_bf, tnorm, lsep_ptr, lfocus_ptr);

    // hid = relu(e_l @ W1^T + b1) -> bf16
    ggemm_k<128, 128, 128, 2, 2, true, 1, false, false>
        <<<dim3(391, 2), 256, 0, stream>>>(e_bf, W1_bf, b1, hid_bf, 256, nullptr, nullptr);
    // phi = e_l @ W_phi -> f32
    ggemm_k<128, 128, 16, 4, 1, false, 0, false, false>
        <<<dim3(391, 1), 256, 0, stream>>>(e_bf, Wphi_t, nullptr, phi, 16, nullptr, nullptr);
    // delta' = hid @ W2^T + b2 (+tnorm), l_focus -> f32
    ggemm_k<256, 64, 64, 2, 2, false, 0, true, true>
        <<<dim3(782, 1), 256, 0, stream>>>(hid_bf, W2_bf, b2, deltap, 64, lfocus_ptr, tnorm);
    // h = h_l @ W -> fp8, [ch][k]-interleaved
    ggemm_k<256, 128, 128, 2, 2, false, 2, false, false>
        <<<dim3(391, 2), 256, 0, stream>>>(hl_bf, W_t, nullptr, h8, 256, nullptr, nullptr);

    // CSR build
    degree_k<<<3125, 256, 0, stream>>>(dst, deg);
    scan_partial_k<<<SCAN_NB, 256, 0, stream>>>(deg, bsum);
    scan_bsum_k<<<1, 256, 0, stream>>>(bsum);
    scan_scatter_k<<<SCAN_NB, 256, 0, stream>>>(deg, bsum, offs, cursor);
    scatter_src_k<<<3125, 256, 0, stream>>>(src, dst, cursor, csr_src, csr_dst);

    // edge weights (thread-per-slot, CSR-ordered)
    edge_w_k<<<3125, 256, 0, stream>>>(csr_src, csr_dst, phi, deltap, (float4*)csr_w);

    // per-dst softmax + aggregation + normalize
    aggregate_k<<<12500, 256, 0, stream>>>(offs, csr_src, csr_w,
                                           (const unsigned int*)h8, bias, out);
}

// Round 13
// 263.665 us; speedup vs baseline: 1.1977x; 1.1722x over previous
//
#include <hip/hip_runtime.h>
#include <math.h>

#define NN 50000
#define EE 800000

typedef __attribute__((ext_vector_type(8))) short short8;
typedef __attribute__((ext_vector_type(4))) float f32x4;
typedef __attribute__((ext_vector_type(2))) float f32x2;

__device__ inline unsigned short f2b(float f) {
    unsigned u = __float_as_uint(f);
    unsigned r = (u + 0x7FFFu + ((u >> 16) & 1u)) >> 16;   // RNE
    return (unsigned short)r;
}
__device__ inline unsigned char f2fp8(float v) {
    return (unsigned char)(__builtin_amdgcn_cvt_pk_fp8_f32(v, v, 0, false) & 0xFF);
}
__device__ inline unsigned cvt_pk_bf16(float lo, float hi) {
    unsigned r;
    asm("v_cvt_pk_bf16_f32 %0, %1, %2" : "=v"(r) : "v"(lo), "v"(hi));
    return r;
}
__device__ inline void gload16(const unsigned short* g, unsigned short* l) {
    __builtin_amdgcn_global_load_lds(
        (const __attribute__((address_space(1))) void*)g,
        (__attribute__((address_space(3))) void*)l, 16, 0, 0);
}

// ---------------------------------------------------------------------------
// fused prep: tnorm+l_sep, weight preps, e_l/h_l -> bf16 casts, degree count
// ---------------------------------------------------------------------------
#define PREP_THREADS (65536 + 32768 + 16384 + 2048 + 800000 + 1600000 + 800000)

__global__ __launch_bounds__(256) void prep_k(const float* __restrict__ W,
                                              const float* __restrict__ W1,
                                              const float* __restrict__ W2,
                                              const float* __restrict__ W_phi,
                                              const float* __restrict__ e_l,
                                              const float* __restrict__ h_l,
                                              const float* __restrict__ tilde_phi,
                                              const int* __restrict__ dst,
                                              unsigned short* __restrict__ W_t,
                                              unsigned short* __restrict__ W1_bf,
                                              unsigned short* __restrict__ W2_bf,
                                              unsigned short* __restrict__ Wphi_t,
                                              unsigned short* __restrict__ e_bf,
                                              unsigned short* __restrict__ hl_bf,
                                              int* __restrict__ deg,
                                              float* __restrict__ tnorm,
                                              float* __restrict__ lsep_out,
                                              float* __restrict__ lfocus_zero) {
    if (blockIdx.x == 0) {
        __shared__ float tn[64];
        int t = threadIdx.x;
        if (t < 64) {
            float v = tilde_phi[t];
            float sq = v * v;
            #pragma unroll
            for (int s = 8; s; s >>= 1) sq += __shfl_xor(sq, s, 16);
            float tnv = v / sqrtf(sq);
            tn[t] = tnv;
            tnorm[t] = tnv;
        }
        __syncthreads();
        if (t == 0) {
            float tot = 0.f;
            for (int a = 0; a < 4; ++a)
                for (int b = 0; b < 4; ++b) {
                    float s2 = 0.f;
                    for (int p = 0; p < 16; ++p) {
                        float df = tn[a * 16 + p] - tn[b * 16 + p];
                        s2 += df * df;
                    }
                    tot += s2;
                }
            lsep_out[0] = tot * 0.25f;
            lfocus_zero[0] = 0.f;
        }
    }
    int i = blockIdx.x * 256 + threadIdx.x;
    if (i < 65536) {
        int cp = i >> 8, r = i & 255;
        int ch = cp >> 2, k = cp & 3;
        W_t[i] = f2b(W[(size_t)r * 256 + (k << 6) + ch]);
    } else if (i < 98304) {
        int j = i - 65536;
        W1_bf[j] = f2b(W1[j]);
    } else if (i < 114688) {
        int j = i - 98304;
        W2_bf[j] = f2b(W2[j]);
    } else if (i < 116736) {
        int j = i - 114688;
        int cp = j >> 7, r = j & 127;
        Wphi_t[j] = (cp < 15) ? f2b(W_phi[(size_t)r * 15 + cp]) : (unsigned short)0;
    } else if (i < 916736) {
        int j = i - 116736;
        const float4* p = (const float4*)e_l + (size_t)j * 2;
        float4 f0 = p[0], f1 = p[1];
        ((uint4*)e_bf)[j] = make_uint4(cvt_pk_bf16(f0.x, f0.y), cvt_pk_bf16(f0.z, f0.w),
                                       cvt_pk_bf16(f1.x, f1.y), cvt_pk_bf16(f1.z, f1.w));
    } else if (i < 2516736) {
        int j = i - 916736;
        const float4* p = (const float4*)h_l + (size_t)j * 2;
        float4 f0 = p[0], f1 = p[1];
        ((uint4*)hl_bf)[j] = make_uint4(cvt_pk_bf16(f0.x, f0.y), cvt_pk_bf16(f0.z, f0.w),
                                        cvt_pk_bf16(f1.x, f1.y), cvt_pk_bf16(f1.z, f1.w));
    } else if (i < 3316736) {
        int j = i - 2516736;
        atomicAdd(&deg[dst[j]], 1);
    }
}

// ---------------------------------------------------------------------------
// GEMM body: global_load_lds staging, [k-slice][row] LDS layout, dbuf.
// lds must hold 2*BM*32 + 2*BN*32 ushorts.
// ---------------------------------------------------------------------------
template <int KD, int BM, int BN, int WR, int WC, bool RELU, int OMODE,
          bool LFOCUS, bool TNADJ>
__device__ __forceinline__ void ggemm_body(unsigned short* lds,
                                           const unsigned short* __restrict__ A,
                                           const unsigned short* __restrict__ Bt,
                                           const float* __restrict__ bias_vec,
                                           void* __restrict__ Cout, int ldc,
                                           float* __restrict__ lfocus_acc,
                                           const float* __restrict__ tn_vec,
                                           int bxm, int bxn) {
    const int AM = BM / (WR * 16), AN = BN / (WC * 16);
    unsigned short* As = lds;                  // [2][BM*32]
    unsigned short* Bs = lds + 2 * BM * 32;    // [2][BN*32]
    const int tid = threadIdx.x;
    const int l = tid & 63, l15 = l & 15, l4 = l >> 4;
    const int w = tid >> 6;
    const int wr = w / WC, wc = w % WC;
    const int row0 = bxm * BM;
    const int col0 = bxn * BN;
    const int wrow = wr * AM * 16, wcol = wc * AN * 16;

    auto stageA = [&](int buf, int k0) {
        #pragma unroll
        for (int o = tid; o < BM * 4; o += 256) {
            int s = o / BM, r = o % BM;
            int gr = row0 + r; if (gr >= NN) gr = NN - 1;
            gload16(&A[(size_t)gr * KD + k0 + s * 8], &As[buf * (BM * 32) + (o - l) * 8]);
        }
    };
    auto stageB = [&](int buf, int k0) {
        #pragma unroll
        for (int o = tid; o < BN * 4; o += 256) {
            int s = o / BN, r = o % BN;
            gload16(&Bt[(size_t)(col0 + r) * KD + k0 + s * 8],
                    &Bs[buf * (BN * 32) + (o - l) * 8]);
        }
    };

    f32x4 acc[AM][AN];
    #pragma unroll
    for (int m = 0; m < AM; ++m)
        #pragma unroll
        for (int n = 0; n < AN; ++n)
            acc[m][n] = (f32x4){0.f, 0.f, 0.f, 0.f};

    stageA(0, 0); stageB(0, 0);
    __syncthreads();
    int cur = 0;
    const int NT = KD / 32;
    for (int t = 0; t < NT; ++t) {
        if (t + 1 < NT) { stageA(cur ^ 1, (t + 1) * 32); stageB(cur ^ 1, (t + 1) * 32); }
        short8 af[AM], bfr[AN];
        #pragma unroll
        for (int m = 0; m < AM; ++m)
            af[m] = *(const short8*)&As[cur * (BM * 32) + (l4 * BM + wrow + m * 16 + l15) * 8];
        #pragma unroll
        for (int n = 0; n < AN; ++n)
            bfr[n] = *(const short8*)&Bs[cur * (BN * 32) + (l4 * BN + wcol + n * 16 + l15) * 8];
        #pragma unroll
        for (int m = 0; m < AM; ++m)
            #pragma unroll
            for (int n = 0; n < AN; ++n)
                acc[m][n] = __builtin_amdgcn_mfma_f32_16x16x32_bf16(af[m], bfr[n], acc[m][n], 0, 0, 0);
        if (t + 1 < NT) __syncthreads();
        cur ^= 1;
    }

    float lf = 0.f;
    // C/D layout: col=lane&15, row=(lane>>4)*4+reg
    #pragma unroll
    for (int m = 0; m < AM; ++m) {
        #pragma unroll
        for (int n = 0; n < AN; ++n) {
            int gc = col0 + wcol + n * 16 + l15;
            float bv = bias_vec ? bias_vec[gc] : 0.f;
            float tv = TNADJ ? tn_vec[gc] : 0.f;
            #pragma unroll
            for (int r = 0; r < 4; ++r) {
                int gr = row0 + wrow + m * 16 + l4 * 4 + r;
                if (gr >= NN) continue;
                float v = acc[m][n][r] + bv;
                if (RELU) v = fmaxf(v, 0.f);
                if (LFOCUS) lf += v * v;
                if (TNADJ) v += tv;
                if (OMODE == 0)
                    ((float*)Cout)[(size_t)gr * ldc + gc] = v;
                else if (OMODE == 1)
                    ((unsigned short*)Cout)[(size_t)gr * ldc + gc] = f2b(v);
                else
                    ((unsigned char*)Cout)[(size_t)gr * ldc + gc] = f2fp8(v);
            }
        }
    }
    if (LFOCUS) {
        #pragma unroll
        for (int s = 32; s; s >>= 1) lf += __shfl_xor(lf, s);
        __syncthreads();                     // safe to reuse lds as scratch
        float* red = (float*)lds;
        if (l == 0) red[w] = lf;
        __syncthreads();
        if (tid == 0)
            atomicAdd(lfocus_acc, (red[0] + red[1] + red[2] + red[3]) *
                                  (1.f / ((float)NN * 4)));
    }
}

// ---------------------------------------------------------------------------
// merged dispatch: hid-GEMM [0,782) + phi-GEMM [782,1173) + h-GEMM [1173,1955)
// + CSR scatter [1955,5080). Independent work overlaps on the machine.
// ---------------------------------------------------------------------------
__global__ __launch_bounds__(256) void fused3_k(const unsigned short* __restrict__ e_bf,
                                                const unsigned short* __restrict__ hl_bf,
                                                const unsigned short* __restrict__ W1_bf,
                                                const unsigned short* __restrict__ Wphi_t,
                                                const unsigned short* __restrict__ W_t,
                                                const float* __restrict__ b1,
                                                unsigned short* __restrict__ hid_bf,
                                                float* __restrict__ phi,
                                                unsigned char* __restrict__ h8,
                                                const int* __restrict__ src,
                                                const int* __restrict__ dst,
                                                int* __restrict__ cursor,
                                                int2* __restrict__ csr_sd) {
    __shared__ __align__(16) unsigned short lds[2 * 128 * 32 + 2 * 128 * 32];
    int bx = blockIdx.x;
    if (bx < 782) {
        ggemm_body<128, 128, 128, 2, 2, true, 1, false, false>(
            lds, e_bf, W1_bf, b1, hid_bf, 256, nullptr, nullptr, bx >> 1, bx & 1);
    } else if (bx < 1173) {
        ggemm_body<128, 128, 16, 4, 1, false, 0, false, false>(
            lds, e_bf, Wphi_t, nullptr, phi, 16, nullptr, nullptr, bx - 782, 0);
    } else if (bx < 1955) {
        int b = bx - 1173;
        ggemm_body<256, 128, 128, 2, 2, false, 2, false, false>(
            lds, hl_bf, W_t, nullptr, h8, 256, nullptr, nullptr, b >> 1, b & 1);
    } else {
        int e = (bx - 1955) * 256 + threadIdx.x;
        if (e < EE) {
            int d = dst[e];
            int pos = atomicAdd(&cursor[d], 1);
            csr_sd[pos] = make_int2(src[e], d);
        }
    }
}

// ---------------------------------------------------------------------------
// delta' = hid @ W2^T + b2 (+tnorm), l_focus.  BM=32 -> 1563 blocks for TLP.
// ---------------------------------------------------------------------------
__global__ __launch_bounds__(256) void delta_k(const unsigned short* __restrict__ hid_bf,
                                               const unsigned short* __restrict__ W2_bf,
                                               const float* __restrict__ b2,
                                               float* __restrict__ deltap,
                                               float* __restrict__ lfocus_acc,
                                               const float* __restrict__ tnorm) {
    __shared__ __align__(16) unsigned short lds[2 * 32 * 32 + 2 * 64 * 32];
    ggemm_body<256, 32, 64, 1, 4, false, 0, true, true>(
        lds, hid_bf, W2_bf, b2, deltap, 64, lfocus_acc, tnorm, blockIdx.x, 0);
}

// ---------------------------------------------------------------------------
#define SCAN_NB ((NN + 255) / 256)   // 196

__global__ __launch_bounds__(256) void scan_partial_k(const int* __restrict__ deg,
                                                      int* __restrict__ bsum) {
    __shared__ int ws_[4];
    int i = blockIdx.x * 256 + threadIdx.x;
    int v = (i < NN) ? deg[i] : 0;
    int x = v;
    #pragma unroll
    for (int s = 32; s; s >>= 1) x += __shfl_xor(x, s);
    if ((threadIdx.x & 63) == 0) ws_[threadIdx.x >> 6] = x;
    __syncthreads();
    if (threadIdx.x == 0) bsum[blockIdx.x] = ws_[0] + ws_[1] + ws_[2] + ws_[3];
}

__global__ __launch_bounds__(256) void scan_bsum_k(int* __restrict__ bsum) {
    __shared__ int sd[256];
    int t = threadIdx.x;
    int v = (t < SCAN_NB) ? bsum[t] : 0;
    sd[t] = v;
    __syncthreads();
    for (int s = 1; s < 256; s <<= 1) {
        int u = (t >= s) ? sd[t - s] : 0;
        __syncthreads();
        sd[t] += u;
        __syncthreads();
    }
    if (t < SCAN_NB) bsum[t] = sd[t] - v;   // exclusive
}

__global__ __launch_bounds__(256) void scan_scatter_k(const int* __restrict__ deg,
                                                      const int* __restrict__ bsum,
                                                      int* __restrict__ offs,
                                                      int* __restrict__ cursor) {
    __shared__ int wexc[4];
    int i = blockIdx.x * 256 + threadIdx.x;
    int lane = threadIdx.x & 63, wid = threadIdx.x >> 6;
    int v = (i < NN) ? deg[i] : 0;
    int x = v;
    #pragma unroll
    for (int d = 1; d < 64; d <<= 1) { int u = __shfl_up(x, d); if (lane >= d) x += u; }
    if (lane == 63) wexc[wid] = x;
    __syncthreads();
    if (threadIdx.x == 0) {
        int a = wexc[0], b = wexc[1], c = wexc[2];
        wexc[0] = 0; wexc[1] = a; wexc[2] = a + b; wexc[3] = a + b + c;
    }
    __syncthreads();
    int excl = (x - v) + wexc[wid] + bsum[blockIdx.x];
    if (i < NN) {
        cursor[i] = excl;
        offs[i + 1] = excl + v;
        if (i == 0) offs[0] = 0;
    }
}

// ---------------------------------------------------------------------------
// edge weights, thread per CSR slot (packed int2). delta' includes tnorm.
// ---------------------------------------------------------------------------
__global__ __launch_bounds__(256) void edge_w_k(const int2* __restrict__ csr_sd,
                                                const float* __restrict__ phi,
                                                const float* __restrict__ deltap,
                                                float4* __restrict__ csr_w) {
    int e = blockIdx.x * 256 + threadIdx.x;
    if (e >= EE) return;
    int2 sd = csr_sd[e];
    int s = sd.x, d = sd.y;
    const float4* ps4 = (const float4*)(phi + (size_t)s * 16);
    const float4* pd4 = (const float4*)(phi + (size_t)d * 16);
    float dv[16];
    float nrm2 = 0.f;
    #pragma unroll
    for (int q = 0; q < 4; ++q) {
        float4 a = ps4[q], b = pd4[q];
        dv[q * 4 + 0] = a.x - b.x;
        dv[q * 4 + 1] = a.y - b.y;
        dv[q * 4 + 2] = a.z - b.z;
        dv[q * 4 + 3] = a.w - b.w;
    }
    #pragma unroll
    for (int p = 0; p < 15; ++p) nrm2 += dv[p] * dv[p];
    float z = (nrm2 == 0.f) ? 1.f : 0.f;
    dv[15] = z;
    nrm2 += z;
    float inv = 1.f / fmaxf(sqrtf(nrm2), 1e-8f);
    const float* dl = deltap + (size_t)d * 64;
    float res[4];
    #pragma unroll
    for (int k = 0; k < 4; ++k) {
        const float4* dk = (const float4*)(dl + k * 16);
        float sacc = 0.f;
        #pragma unroll
        for (int q = 0; q < 4; ++q) {
            float4 tv = dk[q];
            sacc += dv[q * 4 + 0] * tv.x;
            sacc += dv[q * 4 + 1] * tv.y;
            sacc += dv[q * 4 + 2] * tv.z;
            sacc += dv[q * 4 + 3] * tv.w;
        }
        res[k] = sacc * inv;
    }
    csr_w[e] = make_float4(__expf(res[0]), __expf(res[1]),
                           __expf(res[2]), __expf(res[3]));
}

// ---------------------------------------------------------------------------
// per-dst aggregation, wave per node, lane = channel.
// ---------------------------------------------------------------------------
__global__ __launch_bounds__(256) void aggregate_k(const int* __restrict__ offs,
                                                   const int2* __restrict__ csr_sd,
                                                   const float* __restrict__ csr_wf,
                                                   const unsigned int* __restrict__ h8,
                                                   const float* __restrict__ bias,
                                                   float* __restrict__ out) {
    int wave = threadIdx.x >> 6;
    int lane = threadIdx.x & 63;
    int n = blockIdx.x * 4 + wave;
    if (n >= NN) return;
    int beg = offs[n], end = offs[n + 1];

    // phase 1: denominators (flat coalesced read; k-class = lane&3)
    float part = 0.f;
    for (int q = beg * 4 + lane; q < end * 4; q += 64) part += csr_wf[q];
    #pragma unroll
    for (int s = 4; s < 64; s <<= 1) part += __shfl_xor(part, s);
    float inv = (part > 0.f) ? 1.f / part : 0.f;
    float i0 = __shfl(inv, 0), i1 = __shfl(inv, 1);
    float i2 = __shfl(inv, 2), i3 = __shfl(inv, 3);

    // phase 2: weighted accumulation (packed fp8 decode)
    const float4* csr_w = (const float4*)csr_wf;
    float a0 = 0.f, a1 = 0.f, a2 = 0.f, a3 = 0.f;
    int p = beg;
    for (; p + 3 < end; p += 4) {
        float4 w0 = csr_w[p], w1 = csr_w[p + 1], w2 = csr_w[p + 2], w3 = csr_w[p + 3];
        int s0 = csr_sd[p].x, s1 = csr_sd[p + 1].x, s2 = csr_sd[p + 2].x, s3 = csr_sd[p + 3].x;
        unsigned hv0 = h8[(size_t)s0 * 64 + lane];
        unsigned hv1 = h8[(size_t)s1 * 64 + lane];
        unsigned hv2 = h8[(size_t)s2 * 64 + lane];
        unsigned hv3 = h8[(size_t)s3 * 64 + lane];
        f32x2 lo, hi;
        lo = __builtin_amdgcn_cvt_pk_f32_fp8(hv0, false);
        hi = __builtin_amdgcn_cvt_pk_f32_fp8(hv0, true);
        a0 += w0.x * lo.x; a1 += w0.y * lo.y; a2 += w0.z * hi.x; a3 += w0.w * hi.y;
        lo = __builtin_amdgcn_cvt_pk_f32_fp8(hv1, false);
        hi = __builtin_amdgcn_cvt_pk_f32_fp8(hv1, true);
        a0 += w1.x * lo.x; a1 += w1.y * lo.y; a2 += w1.z * hi.x; a3 += w1.w * hi.y;
        lo = __builtin_amdgcn_cvt_pk_f32_fp8(hv2, false);
        hi = __builtin_amdgcn_cvt_pk_f32_fp8(hv2, true);
        a0 += w2.x * lo.x; a1 += w2.y * lo.y; a2 += w2.z * hi.x; a3 += w2.w * hi.y;
        lo = __builtin_amdgcn_cvt_pk_f32_fp8(hv3, false);
        hi = __builtin_amdgcn_cvt_pk_f32_fp8(hv3, true);
        a0 += w3.x * lo.x; a1 += w3.y * lo.y; a2 += w3.z * hi.x; a3 += w3.w * hi.y;
    }
    for (; p < end; ++p) {
        float4 wA = csr_w[p];
        int sA = csr_sd[p].x;
        unsigned hv = h8[(size_t)sA * 64 + lane];
        f32x2 lo = __builtin_amdgcn_cvt_pk_f32_fp8(hv, false);
        f32x2 hi = __builtin_amdgcn_cvt_pk_f32_fp8(hv, true);
        a0 += wA.x * lo.x; a1 += wA.y * lo.y; a2 += wA.z * hi.x; a3 += wA.w * hi.y;
    }
    float v = a0 * i0 + a1 * i1 + a2 * i2 + a3 * i3 + bias[lane];
    float nr = v * v;
    #pragma unroll
    for (int s = 32; s; s >>= 1) nr += __shfl_xor(nr, s);
    float invn = 1.f / fmaxf(sqrtf(nr), 1e-8f);
    out[(size_t)n * 64 + lane] = v * invn;
}

// ---------------------------------------------------------------------------
extern "C" void kernel_launch(void* const* d_in, const int* in_sizes, int n_in,
                              void* d_out, int out_size, void* d_ws, size_t ws_size,
                              hipStream_t stream) {
    const float* h_l       = (const float*)d_in[0];
    const float* e_l       = (const float*)d_in[1];
    const int*   src       = (const int*)d_in[2];
    const int*   dst       = (const int*)d_in[3];
    const float* W_phi     = (const float*)d_in[4];
    const float* W1        = (const float*)d_in[5];
    const float* b1        = (const float*)d_in[6];
    const float* W2        = (const float*)d_in[7];
    const float* b2        = (const float*)d_in[8];
    const float* tilde_phi = (const float*)d_in[9];
    const float* W         = (const float*)d_in[10];
    const float* bias      = (const float*)d_in[11];
    float* out = (float*)d_out;
    float* lsep_ptr   = out + (size_t)NN * 64;
    float* lfocus_ptr = out + (size_t)NN * 64 + 1;

    char* ws = (char*)d_ws;
    size_t off = 0;
    auto alloc = [&](size_t bytes) -> char* {
        char* p = ws + off;
        off += (bytes + 255) & ~(size_t)255;
        return p;
    };
    float*          phi     = (float*)alloc((size_t)NN * 16 * 4);
    float*          deltap  = (float*)alloc((size_t)NN * 64 * 4);
    unsigned char*  h8      = (unsigned char*)alloc((size_t)NN * 256);
    unsigned short* hid_bf  = (unsigned short*)alloc((size_t)NN * 256 * 2);
    unsigned short* e_bf    = (unsigned short*)alloc((size_t)NN * 128 * 2);
    unsigned short* hl_bf   = (unsigned short*)alloc((size_t)NN * 256 * 2);
    int2*           csr_sd  = (int2*)alloc((size_t)EE * 8);
    float*          csr_w   = (float*)alloc((size_t)EE * 4 * 4);
    int*            deg     = (int*)alloc((size_t)NN * 4);
    int*            offs    = (int*)alloc((size_t)(NN + 1) * 4);
    int*            cursor  = (int*)alloc((size_t)NN * 4);
    int*            bsum    = (int*)alloc((size_t)SCAN_NB * 4);
    unsigned short* W_t     = (unsigned short*)alloc(256 * 256 * 2);
    unsigned short* W1_bf   = (unsigned short*)alloc(256 * 128 * 2);
    unsigned short* W2_bf   = (unsigned short*)alloc(64 * 256 * 2);
    unsigned short* Wphi_t  = (unsigned short*)alloc(16 * 128 * 2);
    float*          tnorm   = (float*)alloc(64 * 4);

    hipMemsetAsync(deg, 0, (size_t)NN * 4, stream);

    // prep: tnorm/lsep + weight prep + bf16 casts + degree count
    prep_k<<<(PREP_THREADS + 255) / 256, 256, 0, stream>>>(
        W, W1, W2, W_phi, e_l, h_l, tilde_phi, dst,
        W_t, W1_bf, W2_bf, Wphi_t, e_bf, hl_bf, deg, tnorm, lsep_ptr, lfocus_ptr);

    // CSR offsets
    scan_partial_k<<<SCAN_NB, 256, 0, stream>>>(deg, bsum);
    scan_bsum_k<<<1, 256, 0, stream>>>(bsum);
    scan_scatter_k<<<SCAN_NB, 256, 0, stream>>>(deg, bsum, offs, cursor);

    // merged: hid-GEMM + phi-GEMM + h-GEMM + CSR scatter
    fused3_k<<<5080, 256, 0, stream>>>(e_bf, hl_bf, W1_bf, Wphi_t, W_t, b1,
                                       hid_bf, phi, h8, src, dst, cursor, csr_sd);

    // delta' (depends on hid)
    delta_k<<<1563, 256, 0, stream>>>(hid_bf, W2_bf, b2, deltap, lfocus_ptr, tnorm);

    // edge weights (thread-per-slot, CSR-ordered)
    edge_w_k<<<3125, 256, 0, stream>>>(csr_sd, phi, deltap, (float4*)csr_w);

    // per-dst softmax + aggregation + normalize
    aggregate_k<<<12500, 256, 0, stream>>>(offs, csr_sd, csr_w,
                                           (const unsigned int*)h8, bias, out);
}

// Round 14
// 248.702 us; speedup vs baseline: 1.2698x; 1.0602x over previous
//
#include <hip/hip_runtime.h>
#include <math.h>

#define NN 50000
#define EE 800000

typedef __attribute__((ext_vector_type(8))) short short8;
typedef __attribute__((ext_vector_type(4))) float f32x4;
typedef __attribute__((ext_vector_type(2))) float f32x2;

__device__ inline unsigned short f2b(float f) {
    unsigned u = __float_as_uint(f);
    unsigned r = (u + 0x7FFFu + ((u >> 16) & 1u)) >> 16;   // RNE
    return (unsigned short)r;
}
__device__ inline unsigned char f2fp8(float v) {
    return (unsigned char)(__builtin_amdgcn_cvt_pk_fp8_f32(v, v, 0, false) & 0xFF);
}
__device__ inline unsigned cvt_pk_bf16(float lo, float hi) {
    unsigned r;
    asm("v_cvt_pk_bf16_f32 %0, %1, %2" : "=v"(r) : "v"(lo), "v"(hi));
    return r;
}
__device__ inline void gload16(const unsigned short* g, unsigned short* l) {
    __builtin_amdgcn_global_load_lds(
        (const __attribute__((address_space(1))) void*)g,
        (__attribute__((address_space(3))) void*)l, 16, 0, 0);
}

// ---------------------------------------------------------------------------
// fused prep: tnorm+l_sep, weight preps, e_l/h_l -> bf16 casts, degree count
// ---------------------------------------------------------------------------
#define PREP_THREADS (65536 + 32768 + 16384 + 2048 + 800000 + 1600000 + 800000)

__global__ __launch_bounds__(256) void prep_k(const float* __restrict__ W,
                                              const float* __restrict__ W1,
                                              const float* __restrict__ W2,
                                              const float* __restrict__ W_phi,
                                              const float* __restrict__ e_l,
                                              const float* __restrict__ h_l,
                                              const float* __restrict__ tilde_phi,
                                              const int* __restrict__ dst,
                                              unsigned short* __restrict__ W_t,
                                              unsigned short* __restrict__ W1_bf,
                                              unsigned short* __restrict__ W2_bf,
                                              unsigned short* __restrict__ Wphi_t,
                                              unsigned short* __restrict__ e_bf,
                                              unsigned short* __restrict__ hl_bf,
                                              int* __restrict__ deg,
                                              float* __restrict__ tnorm,
                                              float* __restrict__ lsep_out,
                                              float* __restrict__ lfocus_zero) {
    if (blockIdx.x == 0) {
        __shared__ float tn[64];
        int t = threadIdx.x;
        if (t < 64) {
            float v = tilde_phi[t];
            float sq = v * v;
            #pragma unroll
            for (int s = 8; s; s >>= 1) sq += __shfl_xor(sq, s, 16);
            float tnv = v / sqrtf(sq);
            tn[t] = tnv;
            tnorm[t] = tnv;
        }
        __syncthreads();
        if (t == 0) {
            float tot = 0.f;
            for (int a = 0; a < 4; ++a)
                for (int b = 0; b < 4; ++b) {
                    float s2 = 0.f;
                    for (int p = 0; p < 16; ++p) {
                        float df = tn[a * 16 + p] - tn[b * 16 + p];
                        s2 += df * df;
                    }
                    tot += s2;
                }
            lsep_out[0] = tot * 0.25f;
            lfocus_zero[0] = 0.f;
        }
    }
    int i = blockIdx.x * 256 + threadIdx.x;
    if (i < 65536) {
        int cp = i >> 8, r = i & 255;
        int ch = cp >> 2, k = cp & 3;
        W_t[i] = f2b(W[(size_t)r * 256 + (k << 6) + ch]);
    } else if (i < 98304) {
        int j = i - 65536;
        W1_bf[j] = f2b(W1[j]);
    } else if (i < 114688) {
        int j = i - 98304;
        W2_bf[j] = f2b(W2[j]);
    } else if (i < 116736) {
        int j = i - 114688;
        int cp = j >> 7, r = j & 127;
        Wphi_t[j] = (cp < 15) ? f2b(W_phi[(size_t)r * 15 + cp]) : (unsigned short)0;
    } else if (i < 916736) {
        int j = i - 116736;
        const float4* p = (const float4*)e_l + (size_t)j * 2;
        float4 f0 = p[0], f1 = p[1];
        ((uint4*)e_bf)[j] = make_uint4(cvt_pk_bf16(f0.x, f0.y), cvt_pk_bf16(f0.z, f0.w),
                                       cvt_pk_bf16(f1.x, f1.y), cvt_pk_bf16(f1.z, f1.w));
    } else if (i < 2516736) {
        int j = i - 916736;
        const float4* p = (const float4*)h_l + (size_t)j * 2;
        float4 f0 = p[0], f1 = p[1];
        ((uint4*)hl_bf)[j] = make_uint4(cvt_pk_bf16(f0.x, f0.y), cvt_pk_bf16(f0.z, f0.w),
                                        cvt_pk_bf16(f1.x, f1.y), cvt_pk_bf16(f1.z, f1.w));
    } else if (i < 3316736) {
        int j = i - 2516736;
        atomicAdd(&deg[dst[j]], 1);
    }
}

// ---------------------------------------------------------------------------
// GEMM body v2: COALESCED global_load_lds staging (row-major [BM][32] LDS,
// 4 consecutive lanes cover one 64B line), double-buffered.
// 8-way ds_read bank conflict accepted (m97 parity: hidden under MFMA).
// lds must hold 2*BM*32 + 2*BN*32 ushorts.
// ---------------------------------------------------------------------------
template <int KD, int BM, int BN, int WR, int WC, bool RELU, int OMODE,
          bool LFOCUS, bool TNADJ>
__device__ __forceinline__ void ggemm_body(unsigned short* lds,
                                           const unsigned short* __restrict__ A,
                                           const unsigned short* __restrict__ Bt,
                                           const float* __restrict__ bias_vec,
                                           void* __restrict__ Cout, int ldc,
                                           float* __restrict__ lfocus_acc,
                                           const float* __restrict__ tn_vec,
                                           int bxm, int bxn) {
    const int AM = BM / (WR * 16), AN = BN / (WC * 16);
    unsigned short* As = lds;                  // [2][BM][32] row-major
    unsigned short* Bs = lds + 2 * BM * 32;    // [2][BN][32] row-major
    const int tid = threadIdx.x;
    const int l = tid & 63, l15 = l & 15, l4 = l >> 4;
    const int w = tid >> 6;
    const int wr = w / WC, wc = w % WC;
    const int row0 = bxm * BM;
    const int col0 = bxn * BN;
    const int wrow = wr * AM * 16, wcol = wc * AN * 16;

    // slot o = r*4 + s  (16B units): lanes o..o+3 read one 64B line of row r
    auto stageA = [&](int buf, int k0) {
        #pragma unroll
        for (int o = tid; o < BM * 4; o += 256) {
            int r = o >> 2, s = o & 3;
            int gr = row0 + r; if (gr >= NN) gr = NN - 1;
            gload16(&A[(size_t)gr * KD + k0 + s * 8], &As[buf * (BM * 32) + (o - l) * 8]);
        }
    };
    auto stageB = [&](int buf, int k0) {
        #pragma unroll
        for (int o = tid; o < BN * 4; o += 256) {
            int r = o >> 2, s = o & 3;
            gload16(&Bt[(size_t)(col0 + r) * KD + k0 + s * 8],
                    &Bs[buf * (BN * 32) + (o - l) * 8]);
        }
    };

    f32x4 acc[AM][AN];
    #pragma unroll
    for (int m = 0; m < AM; ++m)
        #pragma unroll
        for (int n = 0; n < AN; ++n)
            acc[m][n] = (f32x4){0.f, 0.f, 0.f, 0.f};

    stageA(0, 0); stageB(0, 0);
    __syncthreads();
    int cur = 0;
    const int NT = KD / 32;
    for (int t = 0; t < NT; ++t) {
        if (t + 1 < NT) { stageA(cur ^ 1, (t + 1) * 32); stageB(cur ^ 1, (t + 1) * 32); }
        short8 af[AM], bfr[AN];
        #pragma unroll
        for (int m = 0; m < AM; ++m)
            af[m] = *(const short8*)&As[cur * (BM * 32) + ((wrow + m * 16 + l15) * 4 + l4) * 8];
        #pragma unroll
        for (int n = 0; n < AN; ++n)
            bfr[n] = *(const short8*)&Bs[cur * (BN * 32) + ((wcol + n * 16 + l15) * 4 + l4) * 8];
        #pragma unroll
        for (int m = 0; m < AM; ++m)
            #pragma unroll
            for (int n = 0; n < AN; ++n)
                acc[m][n] = __builtin_amdgcn_mfma_f32_16x16x32_bf16(af[m], bfr[n], acc[m][n], 0, 0, 0);
        if (t + 1 < NT) __syncthreads();
        cur ^= 1;
    }

    float lf = 0.f;
    // C/D layout: col=lane&15, row=(lane>>4)*4+reg
    #pragma unroll
    for (int m = 0; m < AM; ++m) {
        #pragma unroll
        for (int n = 0; n < AN; ++n) {
            int gc = col0 + wcol + n * 16 + l15;
            float bv = bias_vec ? bias_vec[gc] : 0.f;
            float tv = TNADJ ? tn_vec[gc] : 0.f;
            #pragma unroll
            for (int r = 0; r < 4; ++r) {
                int gr = row0 + wrow + m * 16 + l4 * 4 + r;
                if (gr >= NN) continue;
                float v = acc[m][n][r] + bv;
                if (RELU) v = fmaxf(v, 0.f);
                if (LFOCUS) lf += v * v;
                if (TNADJ) v += tv;
                if (OMODE == 0)
                    ((float*)Cout)[(size_t)gr * ldc + gc] = v;
                else if (OMODE == 1)
                    ((unsigned short*)Cout)[(size_t)gr * ldc + gc] = f2b(v);
                else
                    ((unsigned char*)Cout)[(size_t)gr * ldc + gc] = f2fp8(v);
            }
        }
    }
    if (LFOCUS) {
        #pragma unroll
        for (int s = 32; s; s >>= 1) lf += __shfl_xor(lf, s);
        __syncthreads();
        float* red = (float*)lds;
        if (l == 0) red[w] = lf;
        __syncthreads();
        if (tid == 0)
            atomicAdd(lfocus_acc, (red[0] + red[1] + red[2] + red[3]) *
                                  (1.f / ((float)NN * 4)));
    }
}

// ---------------------------------------------------------------------------
// merged dispatch. Block ranges (longest pole first):
//   [0,3125)        CSR scatter (4B csr_src only)
//   [3125,3907)     hid-GEMM   (782)
//   [3907,4298)     phi-GEMM   (391)
//   [4298,5080)     h-GEMM     (782)
//   [5080,17580)    csr_dst contiguous fill (wave per node)
// ---------------------------------------------------------------------------
__global__ __launch_bounds__(256) void fused3_k(const unsigned short* __restrict__ e_bf,
                                                const unsigned short* __restrict__ hl_bf,
                                                const unsigned short* __restrict__ W1_bf,
                                                const unsigned short* __restrict__ Wphi_t,
                                                const unsigned short* __restrict__ W_t,
                                                const float* __restrict__ b1,
                                                unsigned short* __restrict__ hid_bf,
                                                float* __restrict__ phi,
                                                unsigned char* __restrict__ h8,
                                                const int* __restrict__ src,
                                                const int* __restrict__ dst,
                                                int* __restrict__ cursor,
                                                int* __restrict__ csr_src,
                                                int* __restrict__ csr_dst,
                                                const int* __restrict__ offs) {
    __shared__ __align__(16) unsigned short lds[2 * 128 * 32 + 2 * 128 * 32];
    int bx = blockIdx.x;
    if (bx < 3125) {
        int e = bx * 256 + threadIdx.x;
        if (e < EE) {
            int d = dst[e];
            int pos = atomicAdd(&cursor[d], 1);
            csr_src[pos] = src[e];
        }
    } else if (bx < 3907) {
        int b = bx - 3125;
        ggemm_body<128, 128, 128, 2, 2, true, 1, false, false>(
            lds, e_bf, W1_bf, b1, hid_bf, 256, nullptr, nullptr, b >> 1, b & 1);
    } else if (bx < 4298) {
        ggemm_body<128, 128, 16, 4, 1, false, 0, false, false>(
            lds, e_bf, Wphi_t, nullptr, phi, 16, nullptr, nullptr, bx - 3907, 0);
    } else if (bx < 5080) {
        int b = bx - 4298;
        ggemm_body<256, 128, 128, 2, 2, false, 2, false, false>(
            lds, hl_bf, W_t, nullptr, h8, 256, nullptr, nullptr, b >> 1, b & 1);
    } else {
        int n = (bx - 5080) * 4 + (threadIdx.x >> 6);
        if (n < NN) {
            int lane = threadIdx.x & 63;
            int beg = offs[n], end = offs[n + 1];
            for (int q = beg + lane; q < end; q += 64) csr_dst[q] = n;
        }
    }
}

// ---------------------------------------------------------------------------
// delta' = hid @ W2^T + b2 (+tnorm), l_focus.  BM=32 -> 1563 blocks for TLP.
// ---------------------------------------------------------------------------
__global__ __launch_bounds__(256) void delta_k(const unsigned short* __restrict__ hid_bf,
                                               const unsigned short* __restrict__ W2_bf,
                                               const float* __restrict__ b2,
                                               float* __restrict__ deltap,
                                               float* __restrict__ lfocus_acc,
                                               const float* __restrict__ tnorm) {
    __shared__ __align__(16) unsigned short lds[2 * 32 * 32 + 2 * 64 * 32];
    ggemm_body<256, 32, 64, 1, 4, false, 0, true, true>(
        lds, hid_bf, W2_bf, b2, deltap, 64, lfocus_acc, tnorm, blockIdx.x, 0);
}

// ---------------------------------------------------------------------------
#define SCAN_NB ((NN + 255) / 256)   // 196

__global__ __launch_bounds__(256) void scan_partial_k(const int* __restrict__ deg,
                                                      int* __restrict__ bsum) {
    __shared__ int ws_[4];
    int i = blockIdx.x * 256 + threadIdx.x;
    int v = (i < NN) ? deg[i] : 0;
    int x = v;
    #pragma unroll
    for (int s = 32; s; s >>= 1) x += __shfl_xor(x, s);
    if ((threadIdx.x & 63) == 0) ws_[threadIdx.x >> 6] = x;
    __syncthreads();
    if (threadIdx.x == 0) bsum[blockIdx.x] = ws_[0] + ws_[1] + ws_[2] + ws_[3];
}

__global__ __launch_bounds__(256) void scan_bsum_k(int* __restrict__ bsum) {
    __shared__ int sd[256];
    int t = threadIdx.x;
    int v = (t < SCAN_NB) ? bsum[t] : 0;
    sd[t] = v;
    __syncthreads();
    for (int s = 1; s < 256; s <<= 1) {
        int u = (t >= s) ? sd[t - s] : 0;
        __syncthreads();
        sd[t] += u;
        __syncthreads();
    }
    if (t < SCAN_NB) bsum[t] = sd[t] - v;   // exclusive
}

__global__ __launch_bounds__(256) void scan_scatter_k(const int* __restrict__ deg,
                                                      const int* __restrict__ bsum,
                                                      int* __restrict__ offs,
                                                      int* __restrict__ cursor) {
    __shared__ int wexc[4];
    int i = blockIdx.x * 256 + threadIdx.x;
    int lane = threadIdx.x & 63, wid = threadIdx.x >> 6;
    int v = (i < NN) ? deg[i] : 0;
    int x = v;
    #pragma unroll
    for (int d = 1; d < 64; d <<= 1) { int u = __shfl_up(x, d); if (lane >= d) x += u; }
    if (lane == 63) wexc[wid] = x;
    __syncthreads();
    if (threadIdx.x == 0) {
        int a = wexc[0], b = wexc[1], c = wexc[2];
        wexc[0] = 0; wexc[1] = a; wexc[2] = a + b; wexc[3] = a + b + c;
    }
    __syncthreads();
    int excl = (x - v) + wexc[wid] + bsum[blockIdx.x];
    if (i < NN) {
        cursor[i] = excl;
        offs[i + 1] = excl + v;
        if (i == 0) offs[0] = 0;
    }
}

// ---------------------------------------------------------------------------
// edge weights, thread per CSR slot. delta' already includes tnorm.
// ---------------------------------------------------------------------------
__global__ __launch_bounds__(256) void edge_w_k(const int* __restrict__ csr_src,
                                                const int* __restrict__ csr_dst,
                                                const float* __restrict__ phi,
                                                const float* __restrict__ deltap,
                                                float4* __restrict__ csr_w) {
    int e = blockIdx.x * 256 + threadIdx.x;
    if (e >= EE) return;
    int s = csr_src[e], d = csr_dst[e];
    const float4* ps4 = (const float4*)(phi + (size_t)s * 16);
    const float4* pd4 = (const float4*)(phi + (size_t)d * 16);
    float dv[16];
    float nrm2 = 0.f;
    #pragma unroll
    for (int q = 0; q < 4; ++q) {
        float4 a = ps4[q], b = pd4[q];
        dv[q * 4 + 0] = a.x - b.x;
        dv[q * 4 + 1] = a.y - b.y;
        dv[q * 4 + 2] = a.z - b.z;
        dv[q * 4 + 3] = a.w - b.w;
    }
    #pragma unroll
    for (int p = 0; p < 15; ++p) nrm2 += dv[p] * dv[p];
    float z = (nrm2 == 0.f) ? 1.f : 0.f;
    dv[15] = z;
    nrm2 += z;
    float inv = 1.f / fmaxf(sqrtf(nrm2), 1e-8f);
    const float* dl = deltap + (size_t)d * 64;
    float res[4];
    #pragma unroll
    for (int k = 0; k < 4; ++k) {
        const float4* dk = (const float4*)(dl + k * 16);
        float sacc = 0.f;
        #pragma unroll
        for (int q = 0; q < 4; ++q) {
            float4 tv = dk[q];
            sacc += dv[q * 4 + 0] * tv.x;
            sacc += dv[q * 4 + 1] * tv.y;
            sacc += dv[q * 4 + 2] * tv.z;
            sacc += dv[q * 4 + 3] * tv.w;
        }
        res[k] = sacc * inv;
    }
    csr_w[e] = make_float4(__expf(res[0]), __expf(res[1]),
                           __expf(res[2]), __expf(res[3]));
}

// ---------------------------------------------------------------------------
// per-dst aggregation, wave per node, lane = channel.
// ---------------------------------------------------------------------------
__global__ __launch_bounds__(256) void aggregate_k(const int* __restrict__ offs,
                                                   const int* __restrict__ csr_src,
                                                   const float* __restrict__ csr_wf,
                                                   const unsigned int* __restrict__ h8,
                                                   const float* __restrict__ bias,
                                                   float* __restrict__ out) {
    int wave = threadIdx.x >> 6;
    int lane = threadIdx.x & 63;
    int n = blockIdx.x * 4 + wave;
    if (n >= NN) return;
    int beg = offs[n], end = offs[n + 1];

    // phase 1: denominators (flat coalesced read; k-class = lane&3)
    float part = 0.f;
    for (int q = beg * 4 + lane; q < end * 4; q += 64) part += csr_wf[q];
    #pragma unroll
    for (int s = 4; s < 64; s <<= 1) part += __shfl_xor(part, s);
    float inv = (part > 0.f) ? 1.f / part : 0.f;
    float i0 = __shfl(inv, 0), i1 = __shfl(inv, 1);
    float i2 = __shfl(inv, 2), i3 = __shfl(inv, 3);

    // phase 2: weighted accumulation (packed fp8 decode)
    const float4* csr_w = (const float4*)csr_wf;
    float a0 = 0.f, a1 = 0.f, a2 = 0.f, a3 = 0.f;
    int p = beg;
    for (; p + 3 < end; p += 4) {
        float4 w0 = csr_w[p], w1 = csr_w[p + 1], w2 = csr_w[p + 2], w3 = csr_w[p + 3];
        int s0 = csr_src[p], s1 = csr_src[p + 1], s2 = csr_src[p + 2], s3 = csr_src[p + 3];
        unsigned hv0 = h8[(size_t)s0 * 64 + lane];
        unsigned hv1 = h8[(size_t)s1 * 64 + lane];
        unsigned hv2 = h8[(size_t)s2 * 64 + lane];
        unsigned hv3 = h8[(size_t)s3 * 64 + lane];
        f32x2 lo, hi;
        lo = __builtin_amdgcn_cvt_pk_f32_fp8(hv0, false);
        hi = __builtin_amdgcn_cvt_pk_f32_fp8(hv0, true);
        a0 += w0.x * lo.x; a1 += w0.y * lo.y; a2 += w0.z * hi.x; a3 += w0.w * hi.y;
        lo = __builtin_amdgcn_cvt_pk_f32_fp8(hv1, false);
        hi = __builtin_amdgcn_cvt_pk_f32_fp8(hv1, true);
        a0 += w1.x * lo.x; a1 += w1.y * lo.y; a2 += w1.z * hi.x; a3 += w1.w * hi.y;
        lo = __builtin_amdgcn_cvt_pk_f32_fp8(hv2, false);
        hi = __builtin_amdgcn_cvt_pk_f32_fp8(hv2, true);
        a0 += w2.x * lo.x; a1 += w2.y * lo.y; a2 += w2.z * hi.x; a3 += w2.w * hi.y;
        lo = __builtin_amdgcn_cvt_pk_f32_fp8(hv3, false);
        hi = __builtin_amdgcn_cvt_pk_f32_fp8(hv3, true);
        a0 += w3.x * lo.x; a1 += w3.y * lo.y; a2 += w3.z * hi.x; a3 += w3.w * hi.y;
    }
    for (; p < end; ++p) {
        float4 wA = csr_w[p];
        int sA = csr_src[p];
        unsigned hv = h8[(size_t)sA * 64 + lane];
        f32x2 lo = __builtin_amdgcn_cvt_pk_f32_fp8(hv, false);
        f32x2 hi = __builtin_amdgcn_cvt_pk_f32_fp8(hv, true);
        a0 += wA.x * lo.x; a1 += wA.y * lo.y; a2 += wA.z * hi.x; a3 += wA.w * hi.y;
    }
    float v = a0 * i0 + a1 * i1 + a2 * i2 + a3 * i3 + bias[lane];
    float nr = v * v;
    #pragma unroll
    for (int s = 32; s; s >>= 1) nr += __shfl_xor(nr, s);
    float invn = 1.f / fmaxf(sqrtf(nr), 1e-8f);
    out[(size_t)n * 64 + lane] = v * invn;
}

// ---------------------------------------------------------------------------
extern "C" void kernel_launch(void* const* d_in, const int* in_sizes, int n_in,
                              void* d_out, int out_size, void* d_ws, size_t ws_size,
                              hipStream_t stream) {
    const float* h_l       = (const float*)d_in[0];
    const float* e_l       = (const float*)d_in[1];
    const int*   src       = (const int*)d_in[2];
    const int*   dst       = (const int*)d_in[3];
    const float* W_phi     = (const float*)d_in[4];
    const float* W1        = (const float*)d_in[5];
    const float* b1        = (const float*)d_in[6];
    const float* W2        = (const float*)d_in[7];
    const float* b2        = (const float*)d_in[8];
    const float* tilde_phi = (const float*)d_in[9];
    const float* W         = (const float*)d_in[10];
    const float* bias      = (const float*)d_in[11];
    float* out = (float*)d_out;
    float* lsep_ptr   = out + (size_t)NN * 64;
    float* lfocus_ptr = out + (size_t)NN * 64 + 1;

    char* ws = (char*)d_ws;
    size_t off = 0;
    auto alloc = [&](size_t bytes) -> char* {
        char* p = ws + off;
        off += (bytes + 255) & ~(size_t)255;
        return p;
    };
    float*          phi     = (float*)alloc((size_t)NN * 16 * 4);
    float*          deltap  = (float*)alloc((size_t)NN * 64 * 4);
    unsigned char*  h8      = (unsigned char*)alloc((size_t)NN * 256);
    unsigned short* hid_bf  = (unsigned short*)alloc((size_t)NN * 256 * 2);
    unsigned short* e_bf    = (unsigned short*)alloc((size_t)NN * 128 * 2);
    unsigned short* hl_bf   = (unsigned short*)alloc((size_t)NN * 256 * 2);
    int*            csr_src = (int*)alloc((size_t)EE * 4);
    int*            csr_dst = (int*)alloc((size_t)EE * 4);
    float*          csr_w   = (float*)alloc((size_t)EE * 4 * 4);
    int*            deg     = (int*)alloc((size_t)NN * 4);
    int*            offs    = (int*)alloc((size_t)(NN + 1) * 4);
    int*            cursor  = (int*)alloc((size_t)NN * 4);
    int*            bsum    = (int*)alloc((size_t)SCAN_NB * 4);
    unsigned short* W_t     = (unsigned short*)alloc(256 * 256 * 2);
    unsigned short* W1_bf   = (unsigned short*)alloc(256 * 128 * 2);
    unsigned short* W2_bf   = (unsigned short*)alloc(64 * 256 * 2);
    unsigned short* Wphi_t  = (unsigned short*)alloc(16 * 128 * 2);
    float*          tnorm   = (float*)alloc(64 * 4);

    hipMemsetAsync(deg, 0, (size_t)NN * 4, stream);

    // prep: tnorm/lsep + weight prep + bf16 casts + degree count
    prep_k<<<(PREP_THREADS + 255) / 256, 256, 0, stream>>>(
        W, W1, W2, W_phi, e_l, h_l, tilde_phi, dst,
        W_t, W1_bf, W2_bf, Wphi_t, e_bf, hl_bf, deg, tnorm, lsep_ptr, lfocus_ptr);

    // CSR offsets
    scan_partial_k<<<SCAN_NB, 256, 0, stream>>>(deg, bsum);
    scan_bsum_k<<<1, 256, 0, stream>>>(bsum);
    scan_scatter_k<<<SCAN_NB, 256, 0, stream>>>(deg, bsum, offs, cursor);

    // merged: CSR scatter + hid-GEMM + phi-GEMM + h-GEMM + csr_dst fill
    fused3_k<<<17580, 256, 0, stream>>>(e_bf, hl_bf, W1_bf, Wphi_t, W_t, b1,
                                        hid_bf, phi, h8, src, dst, cursor,
                                        csr_src, csr_dst, offs);

    // delta' (depends on hid)
    delta_k<<<1563, 256, 0, stream>>>(hid_bf, W2_bf, b2, deltap, lfocus_ptr, tnorm);

    // edge weights (thread-per-slot, CSR-ordered)
    edge_w_k<<<3125, 256, 0, stream>>>(csr_src, csr_dst, phi, deltap, (float4*)csr_w);

    // per-dst softmax + aggregation + normalize
    aggregate_k<<<12500, 256, 0, stream>>>(offs, csr_src, csr_w,
                                           (const unsigned int*)h8, bias, out);
}

// Round 15
// 215.738 us; speedup vs baseline: 1.4638x; 1.1528x over previous
//
#include <hip/hip_runtime.h>
#include <math.h>

#define NN 50000
#define EE 800000

typedef __attribute__((ext_vector_type(8))) short short8;
typedef __attribute__((ext_vector_type(4))) float f32x4;
typedef __attribute__((ext_vector_type(2))) float f32x2;

__device__ inline unsigned short f2b(float f) {
    unsigned u = __float_as_uint(f);
    unsigned r = (u + 0x7FFFu + ((u >> 16) & 1u)) >> 16;   // RNE
    return (unsigned short)r;
}
__device__ inline unsigned char f2fp8(float v) {
    return (unsigned char)(__builtin_amdgcn_cvt_pk_fp8_f32(v, v, 0, false) & 0xFF);
}
__device__ inline unsigned cvt_pk_bf16(float lo, float hi) {
    unsigned r;
    asm("v_cvt_pk_bf16_f32 %0, %1, %2" : "=v"(r) : "v"(lo), "v"(hi));
    return r;
}
__device__ inline void gload16(const unsigned short* g, unsigned short* l) {
    __builtin_amdgcn_global_load_lds(
        (const __attribute__((address_space(1))) void*)g,
        (__attribute__((address_space(3))) void*)l, 16, 0, 0);
}

// ---------------------------------------------------------------------------
// fused prep: tnorm+l_sep, weight preps, e_l/h_l -> bf16 casts, degree count
// ---------------------------------------------------------------------------
#define PREP_THREADS (65536 + 32768 + 16384 + 2048 + 800000 + 1600000 + 800000)

__global__ __launch_bounds__(256) void prep_k(const float* __restrict__ W,
                                              const float* __restrict__ W1,
                                              const float* __restrict__ W2,
                                              const float* __restrict__ W_phi,
                                              const float* __restrict__ e_l,
                                              const float* __restrict__ h_l,
                                              const float* __restrict__ tilde_phi,
                                              const int* __restrict__ dst,
                                              unsigned short* __restrict__ W_t,
                                              unsigned short* __restrict__ W1_bf,
                                              unsigned short* __restrict__ W2_bf,
                                              unsigned short* __restrict__ Wphi_t,
                                              unsigned short* __restrict__ e_bf,
                                              unsigned short* __restrict__ hl_bf,
                                              int* __restrict__ deg,
                                              float* __restrict__ tnorm,
                                              float* __restrict__ lsep_out) {
    if (blockIdx.x == 0) {
        __shared__ float tn[64];
        int t = threadIdx.x;
        if (t < 64) {
            float v = tilde_phi[t];
            float sq = v * v;
            #pragma unroll
            for (int s = 8; s; s >>= 1) sq += __shfl_xor(sq, s, 16);
            float tnv = v / sqrtf(sq);
            tn[t] = tnv;
            tnorm[t] = tnv;
        }
        __syncthreads();
        if (t == 0) {
            float tot = 0.f;
            for (int a = 0; a < 4; ++a)
                for (int b = 0; b < 4; ++b) {
                    float s2 = 0.f;
                    for (int p = 0; p < 16; ++p) {
                        float df = tn[a * 16 + p] - tn[b * 16 + p];
                        s2 += df * df;
                    }
                    tot += s2;
                }
            lsep_out[0] = tot * 0.25f;
        }
    }
    int i = blockIdx.x * 256 + threadIdx.x;
    if (i < 65536) {
        int cp = i >> 8, r = i & 255;
        int ch = cp >> 2, k = cp & 3;
        W_t[i] = f2b(W[(size_t)r * 256 + (k << 6) + ch]);
    } else if (i < 98304) {
        int j = i - 65536;
        W1_bf[j] = f2b(W1[j]);
    } else if (i < 114688) {
        int j = i - 98304;
        W2_bf[j] = f2b(W2[j]);
    } else if (i < 116736) {
        int j = i - 114688;
        int cp = j >> 7, r = j & 127;
        Wphi_t[j] = (cp < 15) ? f2b(W_phi[(size_t)r * 15 + cp]) : (unsigned short)0;
    } else if (i < 916736) {
        int j = i - 116736;
        const float4* p = (const float4*)e_l + (size_t)j * 2;
        float4 f0 = p[0], f1 = p[1];
        ((uint4*)e_bf)[j] = make_uint4(cvt_pk_bf16(f0.x, f0.y), cvt_pk_bf16(f0.z, f0.w),
                                       cvt_pk_bf16(f1.x, f1.y), cvt_pk_bf16(f1.z, f1.w));
    } else if (i < 2516736) {
        int j = i - 916736;
        const float4* p = (const float4*)h_l + (size_t)j * 2;
        float4 f0 = p[0], f1 = p[1];
        ((uint4*)hl_bf)[j] = make_uint4(cvt_pk_bf16(f0.x, f0.y), cvt_pk_bf16(f0.z, f0.w),
                                        cvt_pk_bf16(f1.x, f1.y), cvt_pk_bf16(f1.z, f1.w));
    } else if (i < 3316736) {
        int j = i - 2516736;
        atomicAdd(&deg[dst[j]], 1);
    }
}

// ---------------------------------------------------------------------------
// GEMM body: coalesced global_load_lds staging (row-major [BM][32] LDS),
// double-buffered. LFOCUS partials go to an array (no same-address atomics).
// ---------------------------------------------------------------------------
template <int KD, int BM, int BN, int WR, int WC, bool RELU, int OMODE,
          bool LFOCUS, bool TNADJ>
__device__ __forceinline__ void ggemm_body(unsigned short* lds,
                                           const unsigned short* __restrict__ A,
                                           const unsigned short* __restrict__ Bt,
                                           const float* __restrict__ bias_vec,
                                           void* __restrict__ Cout, int ldc,
                                           float* __restrict__ lfocus_part,
                                           const float* __restrict__ tn_vec,
                                           int bxm, int bxn) {
    const int AM = BM / (WR * 16), AN = BN / (WC * 16);
    unsigned short* As = lds;                  // [2][BM][32]
    unsigned short* Bs = lds + 2 * BM * 32;    // [2][BN][32]
    const int tid = threadIdx.x;
    const int l = tid & 63, l15 = l & 15, l4 = l >> 4;
    const int w = tid >> 6;
    const int wr = w / WC, wc = w % WC;
    const int row0 = bxm * BM;
    const int col0 = bxn * BN;
    const int wrow = wr * AM * 16, wcol = wc * AN * 16;

    auto stageA = [&](int buf, int k0) {
        #pragma unroll
        for (int o = tid; o < BM * 4; o += 256) {
            int r = o >> 2, s = o & 3;
            int gr = row0 + r; if (gr >= NN) gr = NN - 1;
            gload16(&A[(size_t)gr * KD + k0 + s * 8], &As[buf * (BM * 32) + (o - l) * 8]);
        }
    };
    auto stageB = [&](int buf, int k0) {
        #pragma unroll
        for (int o = tid; o < BN * 4; o += 256) {
            int r = o >> 2, s = o & 3;
            gload16(&Bt[(size_t)(col0 + r) * KD + k0 + s * 8],
                    &Bs[buf * (BN * 32) + (o - l) * 8]);
        }
    };

    f32x4 acc[AM][AN];
    #pragma unroll
    for (int m = 0; m < AM; ++m)
        #pragma unroll
        for (int n = 0; n < AN; ++n)
            acc[m][n] = (f32x4){0.f, 0.f, 0.f, 0.f};

    stageA(0, 0); stageB(0, 0);
    __syncthreads();
    int cur = 0;
    const int NT = KD / 32;
    for (int t = 0; t < NT; ++t) {
        if (t + 1 < NT) { stageA(cur ^ 1, (t + 1) * 32); stageB(cur ^ 1, (t + 1) * 32); }
        short8 af[AM], bfr[AN];
        #pragma unroll
        for (int m = 0; m < AM; ++m)
            af[m] = *(const short8*)&As[cur * (BM * 32) + ((wrow + m * 16 + l15) * 4 + l4) * 8];
        #pragma unroll
        for (int n = 0; n < AN; ++n)
            bfr[n] = *(const short8*)&Bs[cur * (BN * 32) + ((wcol + n * 16 + l15) * 4 + l4) * 8];
        #pragma unroll
        for (int m = 0; m < AM; ++m)
            #pragma unroll
            for (int n = 0; n < AN; ++n)
                acc[m][n] = __builtin_amdgcn_mfma_f32_16x16x32_bf16(af[m], bfr[n], acc[m][n], 0, 0, 0);
        if (t + 1 < NT) __syncthreads();
        cur ^= 1;
    }

    float lf = 0.f;
    // C/D layout: col=lane&15, row=(lane>>4)*4+reg
    #pragma unroll
    for (int m = 0; m < AM; ++m) {
        #pragma unroll
        for (int n = 0; n < AN; ++n) {
            int gc = col0 + wcol + n * 16 + l15;
            float bv = bias_vec ? bias_vec[gc] : 0.f;
            float tv = TNADJ ? tn_vec[gc] : 0.f;
            #pragma unroll
            for (int r = 0; r < 4; ++r) {
                int gr = row0 + wrow + m * 16 + l4 * 4 + r;
                if (gr >= NN) continue;
                float v = acc[m][n][r] + bv;
                if (RELU) v = fmaxf(v, 0.f);
                if (LFOCUS) lf += v * v;
                if (TNADJ) v += tv;
                if (OMODE == 0)
                    ((float*)Cout)[(size_t)gr * ldc + gc] = v;
                else if (OMODE == 1)
                    ((unsigned short*)Cout)[(size_t)gr * ldc + gc] = f2b(v);
                else
                    ((unsigned char*)Cout)[(size_t)gr * ldc + gc] = f2fp8(v);
            }
        }
    }
    if (LFOCUS) {
        #pragma unroll
        for (int s = 32; s; s >>= 1) lf += __shfl_xor(lf, s);
        __syncthreads();
        float* red = (float*)lds;
        if (l == 0) red[w] = lf;
        __syncthreads();
        if (tid == 0)
            lfocus_part[bxm] = red[0] + red[1] + red[2] + red[3];   // no atomics
    }
}

// ---------------------------------------------------------------------------
// merged dispatch. Block ranges:
//   [0,391)       CSR scatter, 8 edges/thread ILP-unrolled
//   [391,1173)    h-GEMM   (782)
//   [1173,1955)   hid-GEMM (782)
//   [1955,2346)   phi-GEMM (391)
// ---------------------------------------------------------------------------
__global__ __launch_bounds__(256) void fused3_k(const unsigned short* __restrict__ e_bf,
                                                const unsigned short* __restrict__ hl_bf,
                                                const unsigned short* __restrict__ W1_bf,
                                                const unsigned short* __restrict__ Wphi_t,
                                                const unsigned short* __restrict__ W_t,
                                                const float* __restrict__ b1,
                                                unsigned short* __restrict__ hid_bf,
                                                float* __restrict__ phi,
                                                unsigned char* __restrict__ h8,
                                                const int* __restrict__ src,
                                                const int* __restrict__ dst,
                                                int* __restrict__ cursor,
                                                int* __restrict__ csr_src) {
    __shared__ __align__(16) unsigned short lds[2 * 128 * 32 + 2 * 128 * 32];
    int bx = blockIdx.x;
    if (bx < 391) {
        int base = bx * 2048 + threadIdx.x;
        int dv[8], sv[8], pos[8];
        #pragma unroll
        for (int j = 0; j < 8; ++j) {
            int e = base + j * 256;
            if (e < EE) { dv[j] = dst[e]; sv[j] = src[e]; } else dv[j] = -1;
        }
        #pragma unroll
        for (int j = 0; j < 8; ++j)
            if (dv[j] >= 0) pos[j] = atomicAdd(&cursor[dv[j]], 1);
        #pragma unroll
        for (int j = 0; j < 8; ++j)
            if (dv[j] >= 0) csr_src[pos[j]] = sv[j];
    } else if (bx < 1173) {
        int b = bx - 391;
        ggemm_body<256, 128, 128, 2, 2, false, 2, false, false>(
            lds, hl_bf, W_t, nullptr, h8, 256, nullptr, nullptr, b >> 1, b & 1);
    } else if (bx < 1955) {
        int b = bx - 1173;
        ggemm_body<128, 128, 128, 2, 2, true, 1, false, false>(
            lds, e_bf, W1_bf, b1, hid_bf, 256, nullptr, nullptr, b >> 1, b & 1);
    } else {
        ggemm_body<128, 128, 16, 4, 1, false, 0, false, false>(
            lds, e_bf, Wphi_t, nullptr, phi, 16, nullptr, nullptr, bx - 1955, 0);
    }
}

// ---------------------------------------------------------------------------
// delta' = hid @ W2^T + b2 (+tnorm); l_focus partials -> array
// ---------------------------------------------------------------------------
__global__ __launch_bounds__(256) void delta_k(const unsigned short* __restrict__ hid_bf,
                                               const unsigned short* __restrict__ W2_bf,
                                               const float* __restrict__ b2,
                                               float* __restrict__ deltap,
                                               float* __restrict__ lfocus_part,
                                               const float* __restrict__ tnorm) {
    __shared__ __align__(16) unsigned short lds[2 * 32 * 32 + 2 * 64 * 32];
    ggemm_body<256, 32, 64, 1, 4, false, 0, true, true>(
        lds, hid_bf, W2_bf, b2, deltap, 64, lfocus_part, tnorm, blockIdx.x, 0);
}

// ---------------------------------------------------------------------------
#define SCAN_NB ((NN + 255) / 256)   // 196
#define DELTA_NB 1563

__global__ __launch_bounds__(256) void scan_partial_k(const int* __restrict__ deg,
                                                      int* __restrict__ bsum) {
    __shared__ int ws_[4];
    int i = blockIdx.x * 256 + threadIdx.x;
    int v = (i < NN) ? deg[i] : 0;
    int x = v;
    #pragma unroll
    for (int s = 32; s; s >>= 1) x += __shfl_xor(x, s);
    if ((threadIdx.x & 63) == 0) ws_[threadIdx.x >> 6] = x;
    __syncthreads();
    if (threadIdx.x == 0) bsum[blockIdx.x] = ws_[0] + ws_[1] + ws_[2] + ws_[3];
}

__global__ __launch_bounds__(256) void scan_bsum_k(int* __restrict__ bsum) {
    __shared__ int sd[256];
    int t = threadIdx.x;
    int v = (t < SCAN_NB) ? bsum[t] : 0;
    sd[t] = v;
    __syncthreads();
    for (int s = 1; s < 256; s <<= 1) {
        int u = (t >= s) ? sd[t - s] : 0;
        __syncthreads();
        sd[t] += u;
        __syncthreads();
    }
    if (t < SCAN_NB) bsum[t] = sd[t] - v;   // exclusive
}

__global__ __launch_bounds__(256) void scan_scatter_k(const int* __restrict__ deg,
                                                      const int* __restrict__ bsum,
                                                      int* __restrict__ offs,
                                                      int* __restrict__ cursor,
                                                      int* __restrict__ csr_dst) {
    __shared__ int wexc[4];
    int i = blockIdx.x * 256 + threadIdx.x;
    int lane = threadIdx.x & 63, wid = threadIdx.x >> 6;
    int v = (i < NN) ? deg[i] : 0;
    int x = v;
    #pragma unroll
    for (int d = 1; d < 64; d <<= 1) { int u = __shfl_up(x, d); if (lane >= d) x += u; }
    if (lane == 63) wexc[wid] = x;
    __syncthreads();
    if (threadIdx.x == 0) {
        int a = wexc[0], b = wexc[1], c = wexc[2];
        wexc[0] = 0; wexc[1] = a; wexc[2] = a + b; wexc[3] = a + b + c;
    }
    __syncthreads();
    int excl = (x - v) + wexc[wid] + bsum[blockIdx.x];
    if (i < NN) {
        cursor[i] = excl;
        offs[i + 1] = excl + v;
        if (i == 0) offs[0] = 0;
        for (int q = excl; q < excl + v; ++q) csr_dst[q] = i;   // contiguous fill
    }
}

// ---------------------------------------------------------------------------
// edge weights (thread per CSR slot); block 3125 finalizes l_focus.
// ---------------------------------------------------------------------------
__global__ __launch_bounds__(256) void edge_w_k(const int* __restrict__ csr_src,
                                                const int* __restrict__ csr_dst,
                                                const float* __restrict__ phi,
                                                const float* __restrict__ deltap,
                                                float4* __restrict__ csr_w,
                                                const float* __restrict__ lfocus_part,
                                                float* __restrict__ lfocus_out) {
    if (blockIdx.x == 3125) {
        __shared__ float red[4];
        float s = 0.f;
        for (int i = threadIdx.x; i < DELTA_NB; i += 256) s += lfocus_part[i];
        #pragma unroll
        for (int st = 32; st; st >>= 1) s += __shfl_xor(s, st);
        if ((threadIdx.x & 63) == 0) red[threadIdx.x >> 6] = s;
        __syncthreads();
        if (threadIdx.x == 0)
            lfocus_out[0] = (red[0] + red[1] + red[2] + red[3]) * (1.f / ((float)NN * 4));
        return;
    }
    int e = blockIdx.x * 256 + threadIdx.x;
    if (e >= EE) return;
    int s = csr_src[e], d = csr_dst[e];
    const float4* ps4 = (const float4*)(phi + (size_t)s * 16);
    const float4* pd4 = (const float4*)(phi + (size_t)d * 16);
    float dv[16];
    float nrm2 = 0.f;
    #pragma unroll
    for (int q = 0; q < 4; ++q) {
        float4 a = ps4[q], b = pd4[q];
        dv[q * 4 + 0] = a.x - b.x;
        dv[q * 4 + 1] = a.y - b.y;
        dv[q * 4 + 2] = a.z - b.z;
        dv[q * 4 + 3] = a.w - b.w;
    }
    #pragma unroll
    for (int p = 0; p < 15; ++p) nrm2 += dv[p] * dv[p];
    float z = (nrm2 == 0.f) ? 1.f : 0.f;
    dv[15] = z;
    nrm2 += z;
    float inv = 1.f / fmaxf(sqrtf(nrm2), 1e-8f);
    const float* dl = deltap + (size_t)d * 64;
    float res[4];
    #pragma unroll
    for (int k = 0; k < 4; ++k) {
        const float4* dk = (const float4*)(dl + k * 16);
        float sacc = 0.f;
        #pragma unroll
        for (int q = 0; q < 4; ++q) {
            float4 tv = dk[q];
            sacc += dv[q * 4 + 0] * tv.x;
            sacc += dv[q * 4 + 1] * tv.y;
            sacc += dv[q * 4 + 2] * tv.z;
            sacc += dv[q * 4 + 3] * tv.w;
        }
        res[k] = sacc * inv;
    }
    csr_w[e] = make_float4(__expf(res[0]), __expf(res[1]),
                           __expf(res[2]), __expf(res[3]));
}

// ---------------------------------------------------------------------------
// per-dst aggregation, wave per node, lane = channel.
// ---------------------------------------------------------------------------
__global__ __launch_bounds__(256) void aggregate_k(const int* __restrict__ offs,
                                                   const int* __restrict__ csr_src,
                                                   const float* __restrict__ csr_wf,
                                                   const unsigned int* __restrict__ h8,
                                                   const float* __restrict__ bias,
                                                   float* __restrict__ out) {
    int wave = threadIdx.x >> 6;
    int lane = threadIdx.x & 63;
    int n = blockIdx.x * 4 + wave;
    if (n >= NN) return;
    int beg = offs[n], end = offs[n + 1];

    // phase 1: denominators (flat coalesced read; k-class = lane&3)
    float part = 0.f;
    for (int q = beg * 4 + lane; q < end * 4; q += 64) part += csr_wf[q];
    #pragma unroll
    for (int s = 4; s < 64; s <<= 1) part += __shfl_xor(part, s);
    float inv = (part > 0.f) ? 1.f / part : 0.f;
    float i0 = __shfl(inv, 0), i1 = __shfl(inv, 1);
    float i2 = __shfl(inv, 2), i3 = __shfl(inv, 3);

    // phase 2: weighted accumulation (packed fp8 decode)
    const float4* csr_w = (const float4*)csr_wf;
    float a0 = 0.f, a1 = 0.f, a2 = 0.f, a3 = 0.f;
    int p = beg;
    for (; p + 3 < end; p += 4) {
        float4 w0 = csr_w[p], w1 = csr_w[p + 1], w2 = csr_w[p + 2], w3 = csr_w[p + 3];
        int s0 = csr_src[p], s1 = csr_src[p + 1], s2 = csr_src[p + 2], s3 = csr_src[p + 3];
        unsigned hv0 = h8[(size_t)s0 * 64 + lane];
        unsigned hv1 = h8[(size_t)s1 * 64 + lane];
        unsigned hv2 = h8[(size_t)s2 * 64 + lane];
        unsigned hv3 = h8[(size_t)s3 * 64 + lane];
        f32x2 lo, hi;
        lo = __builtin_amdgcn_cvt_pk_f32_fp8(hv0, false);
        hi = __builtin_amdgcn_cvt_pk_f32_fp8(hv0, true);
        a0 += w0.x * lo.x; a1 += w0.y * lo.y; a2 += w0.z * hi.x; a3 += w0.w * hi.y;
        lo = __builtin_amdgcn_cvt_pk_f32_fp8(hv1, false);
        hi = __builtin_amdgcn_cvt_pk_f32_fp8(hv1, true);
        a0 += w1.x * lo.x; a1 += w1.y * lo.y; a2 += w1.z * hi.x; a3 += w1.w * hi.y;
        lo = __builtin_amdgcn_cvt_pk_f32_fp8(hv2, false);
        hi = __builtin_amdgcn_cvt_pk_f32_fp8(hv2, true);
        a0 += w2.x * lo.x; a1 += w2.y * lo.y; a2 += w2.z * hi.x; a3 += w2.w * hi.y;
        lo = __builtin_amdgcn_cvt_pk_f32_fp8(hv3, false);
        hi = __builtin_amdgcn_cvt_pk_f32_fp8(hv3, true);
        a0 += w3.x * lo.x; a1 += w3.y * lo.y; a2 += w3.z * hi.x; a3 += w3.w * hi.y;
    }
    for (; p < end; ++p) {
        float4 wA = csr_w[p];
        int sA = csr_src[p];
        unsigned hv = h8[(size_t)sA * 64 + lane];
        f32x2 lo = __builtin_amdgcn_cvt_pk_f32_fp8(hv, false);
        f32x2 hi = __builtin_amdgcn_cvt_pk_f32_fp8(hv, true);
        a0 += wA.x * lo.x; a1 += wA.y * lo.y; a2 += wA.z * hi.x; a3 += wA.w * hi.y;
    }
    float v = a0 * i0 + a1 * i1 + a2 * i2 + a3 * i3 + bias[lane];
    float nr = v * v;
    #pragma unroll
    for (int s = 32; s; s >>= 1) nr += __shfl_xor(nr, s);
    float invn = 1.f / fmaxf(sqrtf(nr), 1e-8f);
    out[(size_t)n * 64 + lane] = v * invn;
}

// ---------------------------------------------------------------------------
extern "C" void kernel_launch(void* const* d_in, const int* in_sizes, int n_in,
                              void* d_out, int out_size, void* d_ws, size_t ws_size,
                              hipStream_t stream) {
    const float* h_l       = (const float*)d_in[0];
    const float* e_l       = (const float*)d_in[1];
    const int*   src       = (const int*)d_in[2];
    const int*   dst       = (const int*)d_in[3];
    const float* W_phi     = (const float*)d_in[4];
    const float* W1        = (const float*)d_in[5];
    const float* b1        = (const float*)d_in[6];
    const float* W2        = (const float*)d_in[7];
    const float* b2        = (const float*)d_in[8];
    const float* tilde_phi = (const float*)d_in[9];
    const float* W         = (const float*)d_in[10];
    const float* bias      = (const float*)d_in[11];
    float* out = (float*)d_out;
    float* lsep_ptr   = out + (size_t)NN * 64;
    float* lfocus_ptr = out + (size_t)NN * 64 + 1;

    char* ws = (char*)d_ws;
    size_t off = 0;
    auto alloc = [&](size_t bytes) -> char* {
        char* p = ws + off;
        off += (bytes + 255) & ~(size_t)255;
        return p;
    };
    float*          phi     = (float*)alloc((size_t)NN * 16 * 4);
    float*          deltap  = (float*)alloc((size_t)NN * 64 * 4);
    unsigned char*  h8      = (unsigned char*)alloc((size_t)NN * 256);
    unsigned short* hid_bf  = (unsigned short*)alloc((size_t)NN * 256 * 2);
    unsigned short* e_bf    = (unsigned short*)alloc((size_t)NN * 128 * 2);
    unsigned short* hl_bf   = (unsigned short*)alloc((size_t)NN * 256 * 2);
    int*            csr_src = (int*)alloc((size_t)EE * 4);
    int*            csr_dst = (int*)alloc((size_t)EE * 4);
    float*          csr_w   = (float*)alloc((size_t)EE * 4 * 4);
    int*            deg     = (int*)alloc((size_t)NN * 4);
    int*            offs    = (int*)alloc((size_t)(NN + 1) * 4);
    int*            cursor  = (int*)alloc((size_t)NN * 4);
    int*            bsum    = (int*)alloc((size_t)SCAN_NB * 4);
    float*          lf_part = (float*)alloc((size_t)DELTA_NB * 4);
    unsigned short* W_t     = (unsigned short*)alloc(256 * 256 * 2);
    unsigned short* W1_bf   = (unsigned short*)alloc(256 * 128 * 2);
    unsigned short* W2_bf   = (unsigned short*)alloc(64 * 256 * 2);
    unsigned short* Wphi_t  = (unsigned short*)alloc(16 * 128 * 2);
    float*          tnorm   = (float*)alloc(64 * 4);

    hipMemsetAsync(deg, 0, (size_t)NN * 4, stream);

    // prep: tnorm/lsep + weight prep + bf16 casts + degree count
    prep_k<<<(PREP_THREADS + 255) / 256, 256, 0, stream>>>(
        W, W1, W2, W_phi, e_l, h_l, tilde_phi, dst,
        W_t, W1_bf, W2_bf, Wphi_t, e_bf, hl_bf, deg, tnorm, lsep_ptr);

    // CSR offsets (+ contiguous csr_dst fill)
    scan_partial_k<<<SCAN_NB, 256, 0, stream>>>(deg, bsum);
    scan_bsum_k<<<1, 256, 0, stream>>>(bsum);
    scan_scatter_k<<<SCAN_NB, 256, 0, stream>>>(deg, bsum, offs, cursor, csr_dst);

    // merged: ILP-8 CSR scatter + h-GEMM + hid-GEMM + phi-GEMM
    fused3_k<<<2346, 256, 0, stream>>>(e_bf, hl_bf, W1_bf, Wphi_t, W_t, b1,
                                       hid_bf, phi, h8, src, dst, cursor, csr_src);

    // delta' (depends on hid); l_focus partials
    delta_k<<<DELTA_NB, 256, 0, stream>>>(hid_bf, W2_bf, b2, deltap, lf_part, tnorm);

    // edge weights + l_focus finalize
    edge_w_k<<<3126, 256, 0, stream>>>(csr_src, csr_dst, phi, deltap, (float4*)csr_w,
                                       lf_part, lfocus_ptr);

    // per-dst softmax + aggregation + normalize
    aggregate_k<<<12500, 256, 0, stream>>>(offs, csr_src, csr_w,
                                           (const unsigned int*)h8, bias, out);
}

// Round 16
// 187.819 us; speedup vs baseline: 1.6814x; 1.1486x over previous
//
#include <hip/hip_runtime.h>
#include <math.h>

#define NN 50000
#define EE 800000

typedef __attribute__((ext_vector_type(8))) short short8;
typedef __attribute__((ext_vector_type(4))) float f32x4;
typedef __attribute__((ext_vector_type(2))) float f32x2;

__device__ inline unsigned short f2b(float f) {
    unsigned u = __float_as_uint(f);
    unsigned r = (u + 0x7FFFu + ((u >> 16) & 1u)) >> 16;   // RNE
    return (unsigned short)r;
}
__device__ inline unsigned char f2fp8(float v) {
    return (unsigned char)(__builtin_amdgcn_cvt_pk_fp8_f32(v, v, 0, false) & 0xFF);
}
__device__ inline unsigned cvt_pk_bf16(float lo, float hi) {
    unsigned r;
    asm("v_cvt_pk_bf16_f32 %0, %1, %2" : "=v"(r) : "v"(lo), "v"(hi));
    return r;
}
__device__ inline void gload16(const unsigned short* g, unsigned short* l) {
    __builtin_amdgcn_global_load_lds(
        (const __attribute__((address_space(1))) void*)g,
        (__attribute__((address_space(3))) void*)l, 16, 0, 0);
}

// ---------------------------------------------------------------------------
// fused prep: tnorm+l_sep, weight preps, e_l/h_l -> bf16 casts,
// degree count WITH rank capture (rank[e] = slot within dst's segment).
// ---------------------------------------------------------------------------
#define PREP_THREADS (65536 + 32768 + 16384 + 2048 + 800000 + 1600000 + 800000)

__global__ __launch_bounds__(256) void prep_k(const float* __restrict__ W,
                                              const float* __restrict__ W1,
                                              const float* __restrict__ W2,
                                              const float* __restrict__ W_phi,
                                              const float* __restrict__ e_l,
                                              const float* __restrict__ h_l,
                                              const float* __restrict__ tilde_phi,
                                              const int* __restrict__ dst,
                                              unsigned short* __restrict__ W_t,
                                              unsigned short* __restrict__ W1_bf,
                                              unsigned short* __restrict__ W2_bf,
                                              unsigned short* __restrict__ Wphi_t,
                                              unsigned short* __restrict__ e_bf,
                                              unsigned short* __restrict__ hl_bf,
                                              int* __restrict__ deg,
                                              int* __restrict__ rank,
                                              float* __restrict__ tnorm,
                                              float* __restrict__ lsep_out) {
    if (blockIdx.x == 0) {
        __shared__ float tn[64];
        int t = threadIdx.x;
        if (t < 64) {
            float v = tilde_phi[t];
            float sq = v * v;
            #pragma unroll
            for (int s = 8; s; s >>= 1) sq += __shfl_xor(sq, s, 16);
            float tnv = v / sqrtf(sq);
            tn[t] = tnv;
            tnorm[t] = tnv;
        }
        __syncthreads();
        if (t == 0) {
            float tot = 0.f;
            for (int a = 0; a < 4; ++a)
                for (int b = 0; b < 4; ++b) {
                    float s2 = 0.f;
                    for (int p = 0; p < 16; ++p) {
                        float df = tn[a * 16 + p] - tn[b * 16 + p];
                        s2 += df * df;
                    }
                    tot += s2;
                }
            lsep_out[0] = tot * 0.25f;
        }
    }
    int i = blockIdx.x * 256 + threadIdx.x;
    if (i < 65536) {
        int cp = i >> 8, r = i & 255;
        int ch = cp >> 2, k = cp & 3;
        W_t[i] = f2b(W[(size_t)r * 256 + (k << 6) + ch]);
    } else if (i < 98304) {
        int j = i - 65536;
        W1_bf[j] = f2b(W1[j]);
    } else if (i < 114688) {
        int j = i - 98304;
        W2_bf[j] = f2b(W2[j]);
    } else if (i < 116736) {
        int j = i - 114688;
        int cp = j >> 7, r = j & 127;
        Wphi_t[j] = (cp < 15) ? f2b(W_phi[(size_t)r * 15 + cp]) : (unsigned short)0;
    } else if (i < 916736) {
        int j = i - 116736;
        const float4* p = (const float4*)e_l + (size_t)j * 2;
        float4 f0 = p[0], f1 = p[1];
        ((uint4*)e_bf)[j] = make_uint4(cvt_pk_bf16(f0.x, f0.y), cvt_pk_bf16(f0.z, f0.w),
                                       cvt_pk_bf16(f1.x, f1.y), cvt_pk_bf16(f1.z, f1.w));
    } else if (i < 2516736) {
        int j = i - 916736;
        const float4* p = (const float4*)h_l + (size_t)j * 2;
        float4 f0 = p[0], f1 = p[1];
        ((uint4*)hl_bf)[j] = make_uint4(cvt_pk_bf16(f0.x, f0.y), cvt_pk_bf16(f0.z, f0.w),
                                        cvt_pk_bf16(f1.x, f1.y), cvt_pk_bf16(f1.z, f1.w));
    } else if (i < 3316736) {
        int j = i - 2516736;
        rank[j] = atomicAdd(&deg[dst[j]], 1);
    }
}

// ---------------------------------------------------------------------------
// GEMM body: single-buffer m97-style (stage -> sync -> MFMA -> sync).
// Coalesced global_load_lds staging, row-major [BM][32] LDS.
// lds must hold BM*32 + BN*32 ushorts.
// ---------------------------------------------------------------------------
template <int KD, int BM, int BN, int WR, int WC, bool RELU, int OMODE,
          bool LFOCUS, bool TNADJ>
__device__ __forceinline__ void ggemm_body(unsigned short* lds,
                                           const unsigned short* __restrict__ A,
                                           const unsigned short* __restrict__ Bt,
                                           const float* __restrict__ bias_vec,
                                           void* __restrict__ Cout, int ldc,
                                           float* __restrict__ lfocus_part,
                                           const float* __restrict__ tn_vec,
                                           int bxm, int bxn) {
    const int AM = BM / (WR * 16), AN = BN / (WC * 16);
    unsigned short* As = lds;              // [BM][32]
    unsigned short* Bs = lds + BM * 32;    // [BN][32]
    const int tid = threadIdx.x;
    const int l = tid & 63, l15 = l & 15, l4 = l >> 4;
    const int w = tid >> 6;
    const int wr = w / WC, wc = w % WC;
    const int row0 = bxm * BM;
    const int col0 = bxn * BN;
    const int wrow = wr * AM * 16, wcol = wc * AN * 16;

    auto stage = [&](int k0) {
        #pragma unroll
        for (int o = tid; o < BM * 4; o += 256) {
            int r = o >> 2, s = o & 3;
            int gr = row0 + r; if (gr >= NN) gr = NN - 1;
            gload16(&A[(size_t)gr * KD + k0 + s * 8], &As[(o - l) * 8]);
        }
        #pragma unroll
        for (int o = tid; o < BN * 4; o += 256) {
            int r = o >> 2, s = o & 3;
            gload16(&Bt[(size_t)(col0 + r) * KD + k0 + s * 8], &Bs[(o - l) * 8]);
        }
    };

    f32x4 acc[AM][AN];
    #pragma unroll
    for (int m = 0; m < AM; ++m)
        #pragma unroll
        for (int n = 0; n < AN; ++n)
            acc[m][n] = (f32x4){0.f, 0.f, 0.f, 0.f};

    const int NT = KD / 32;
    stage(0);
    for (int t = 0; t < NT; ++t) {
        __syncthreads();                    // staging visible (vmcnt drained)
        short8 af[AM], bfr[AN];
        #pragma unroll
        for (int m = 0; m < AM; ++m)
            af[m] = *(const short8*)&As[((wrow + m * 16 + l15) * 4 + l4) * 8];
        #pragma unroll
        for (int n = 0; n < AN; ++n)
            bfr[n] = *(const short8*)&Bs[((wcol + n * 16 + l15) * 4 + l4) * 8];
        #pragma unroll
        for (int m = 0; m < AM; ++m)
            #pragma unroll
            for (int n = 0; n < AN; ++n)
                acc[m][n] = __builtin_amdgcn_mfma_f32_16x16x32_bf16(af[m], bfr[n], acc[m][n], 0, 0, 0);
        if (t + 1 < NT) {
            __syncthreads();                // all reads done before overwrite
            stage((t + 1) * 32);
        }
    }

    float lf = 0.f;
    // C/D layout: col=lane&15, row=(lane>>4)*4+reg
    #pragma unroll
    for (int m = 0; m < AM; ++m) {
        #pragma unroll
        for (int n = 0; n < AN; ++n) {
            int gc = col0 + wcol + n * 16 + l15;
            float bv = bias_vec ? bias_vec[gc] : 0.f;
            float tv = TNADJ ? tn_vec[gc] : 0.f;
            #pragma unroll
            for (int r = 0; r < 4; ++r) {
                int gr = row0 + wrow + m * 16 + l4 * 4 + r;
                if (gr >= NN) continue;
                float v = acc[m][n][r] + bv;
                if (RELU) v = fmaxf(v, 0.f);
                if (LFOCUS) lf += v * v;
                if (TNADJ) v += tv;
                if (OMODE == 0)
                    ((float*)Cout)[(size_t)gr * ldc + gc] = v;
                else if (OMODE == 1)
                    ((unsigned short*)Cout)[(size_t)gr * ldc + gc] = f2b(v);
                else
                    ((unsigned char*)Cout)[(size_t)gr * ldc + gc] = f2fp8(v);
            }
        }
    }
    if (LFOCUS) {
        #pragma unroll
        for (int s = 32; s; s >>= 1) lf += __shfl_xor(lf, s);
        __syncthreads();
        float* red = (float*)lds;
        if (l == 0) red[w] = lf;
        __syncthreads();
        if (tid == 0)
            lfocus_part[bxm] = red[0] + red[1] + red[2] + red[3];
    }
}

// ---------------------------------------------------------------------------
// merged dispatch (16KB LDS/block). Block ranges:
//   [0,391)       CSR scatter: pos = offs[dst] + rank  (pure stores, ILP-8)
//   [391,1173)    h-GEMM   (782)
//   [1173,1955)   hid-GEMM (782)
//   [1955,2346)   phi-GEMM (391)
// ---------------------------------------------------------------------------
__global__ __launch_bounds__(256) void fused3_k(const unsigned short* __restrict__ e_bf,
                                                const unsigned short* __restrict__ hl_bf,
                                                const unsigned short* __restrict__ W1_bf,
                                                const unsigned short* __restrict__ Wphi_t,
                                                const unsigned short* __restrict__ W_t,
                                                const float* __restrict__ b1,
                                                unsigned short* __restrict__ hid_bf,
                                                float* __restrict__ phi,
                                                unsigned char* __restrict__ h8,
                                                const int* __restrict__ src,
                                                const int* __restrict__ dst,
                                                const int* __restrict__ rank,
                                                const int* __restrict__ offs,
                                                int* __restrict__ csr_src) {
    __shared__ __align__(16) unsigned short lds[128 * 32 + 128 * 32];
    int bx = blockIdx.x;
    if (bx < 391) {
        int base = bx * 2048 + threadIdx.x;
        int pos[8], sv[8];
        #pragma unroll
        for (int j = 0; j < 8; ++j) {
            int e = base + j * 256;
            if (e < EE) {
                pos[j] = offs[dst[e]] + rank[e];
                sv[j] = src[e];
            } else pos[j] = -1;
        }
        #pragma unroll
        for (int j = 0; j < 8; ++j)
            if (pos[j] >= 0) csr_src[pos[j]] = sv[j];
    } else if (bx < 1173) {
        int b = bx - 391;
        ggemm_body<256, 128, 128, 2, 2, false, 2, false, false>(
            lds, hl_bf, W_t, nullptr, h8, 256, nullptr, nullptr, b >> 1, b & 1);
    } else if (bx < 1955) {
        int b = bx - 1173;
        ggemm_body<128, 128, 128, 2, 2, true, 1, false, false>(
            lds, e_bf, W1_bf, b1, hid_bf, 256, nullptr, nullptr, b >> 1, b & 1);
    } else {
        ggemm_body<128, 128, 16, 4, 1, false, 0, false, false>(
            lds, e_bf, Wphi_t, nullptr, phi, 16, nullptr, nullptr, bx - 1955, 0);
    }
}

// ---------------------------------------------------------------------------
// delta' = hid @ W2^T + b2 (+tnorm); l_focus partials -> array. 6KB LDS.
// ---------------------------------------------------------------------------
__global__ __launch_bounds__(256) void delta_k(const unsigned short* __restrict__ hid_bf,
                                               const unsigned short* __restrict__ W2_bf,
                                               const float* __restrict__ b2,
                                               float* __restrict__ deltap,
                                               float* __restrict__ lfocus_part,
                                               const float* __restrict__ tnorm) {
    __shared__ __align__(16) unsigned short lds[32 * 32 + 64 * 32];
    ggemm_body<256, 32, 64, 1, 4, false, 0, true, true>(
        lds, hid_bf, W2_bf, b2, deltap, 64, lfocus_part, tnorm, blockIdx.x, 0);
}

// ---------------------------------------------------------------------------
#define SCAN_NB ((NN + 255) / 256)   // 196
#define DELTA_NB 1563

__global__ __launch_bounds__(256) void scan_partial_k(const int* __restrict__ deg,
                                                      int* __restrict__ bsum) {
    __shared__ int ws_[4];
    int i = blockIdx.x * 256 + threadIdx.x;
    int v = (i < NN) ? deg[i] : 0;
    int x = v;
    #pragma unroll
    for (int s = 32; s; s >>= 1) x += __shfl_xor(x, s);
    if ((threadIdx.x & 63) == 0) ws_[threadIdx.x >> 6] = x;
    __syncthreads();
    if (threadIdx.x == 0) bsum[blockIdx.x] = ws_[0] + ws_[1] + ws_[2] + ws_[3];
}

__global__ __launch_bounds__(256) void scan_bsum_k(int* __restrict__ bsum) {
    __shared__ int sd[256];
    int t = threadIdx.x;
    int v = (t < SCAN_NB) ? bsum[t] : 0;
    sd[t] = v;
    __syncthreads();
    for (int s = 1; s < 256; s <<= 1) {
        int u = (t >= s) ? sd[t - s] : 0;
        __syncthreads();
        sd[t] += u;
        __syncthreads();
    }
    if (t < SCAN_NB) bsum[t] = sd[t] - v;   // exclusive
}

__global__ __launch_bounds__(256) void scan_scatter_k(const int* __restrict__ deg,
                                                      const int* __restrict__ bsum,
                                                      int* __restrict__ offs,
                                                      int* __restrict__ csr_dst) {
    __shared__ int wexc[4];
    int i = blockIdx.x * 256 + threadIdx.x;
    int lane = threadIdx.x & 63, wid = threadIdx.x >> 6;
    int v = (i < NN) ? deg[i] : 0;
    int x = v;
    #pragma unroll
    for (int d = 1; d < 64; d <<= 1) { int u = __shfl_up(x, d); if (lane >= d) x += u; }
    if (lane == 63) wexc[wid] = x;
    __syncthreads();
    if (threadIdx.x == 0) {
        int a = wexc[0], b = wexc[1], c = wexc[2];
        wexc[0] = 0; wexc[1] = a; wexc[2] = a + b; wexc[3] = a + b + c;
    }
    __syncthreads();
    int excl = (x - v) + wexc[wid] + bsum[blockIdx.x];
    if (i < NN) {
        offs[i + 1] = excl + v;
        if (i == 0) offs[0] = 0;
        for (int q = excl; q < excl + v; ++q) csr_dst[q] = i;   // contiguous fill
    }
}

// ---------------------------------------------------------------------------
// edge weights (thread per CSR slot); block 3125 finalizes l_focus.
// ---------------------------------------------------------------------------
__global__ __launch_bounds__(256) void edge_w_k(const int* __restrict__ csr_src,
                                                const int* __restrict__ csr_dst,
                                                const float* __restrict__ phi,
                                                const float* __restrict__ deltap,
                                                float4* __restrict__ csr_w,
                                                const float* __restrict__ lfocus_part,
                                                float* __restrict__ lfocus_out) {
    if (blockIdx.x == 3125) {
        __shared__ float red[4];
        float s = 0.f;
        for (int i = threadIdx.x; i < DELTA_NB; i += 256) s += lfocus_part[i];
        #pragma unroll
        for (int st = 32; st; st >>= 1) s += __shfl_xor(s, st);
        if ((threadIdx.x & 63) == 0) red[threadIdx.x >> 6] = s;
        __syncthreads();
        if (threadIdx.x == 0)
            lfocus_out[0] = (red[0] + red[1] + red[2] + red[3]) * (1.f / ((float)NN * 4));
        return;
    }
    int e = blockIdx.x * 256 + threadIdx.x;
    if (e >= EE) return;
    int s = csr_src[e], d = csr_dst[e];
    const float4* ps4 = (const float4*)(phi + (size_t)s * 16);
    const float4* pd4 = (const float4*)(phi + (size_t)d * 16);
    float dv[16];
    float nrm2 = 0.f;
    #pragma unroll
    for (int q = 0; q < 4; ++q) {
        float4 a = ps4[q], b = pd4[q];
        dv[q * 4 + 0] = a.x - b.x;
        dv[q * 4 + 1] = a.y - b.y;
        dv[q * 4 + 2] = a.z - b.z;
        dv[q * 4 + 3] = a.w - b.w;
    }
    #pragma unroll
    for (int p = 0; p < 15; ++p) nrm2 += dv[p] * dv[p];
    float z = (nrm2 == 0.f) ? 1.f : 0.f;
    dv[15] = z;
    nrm2 += z;
    float inv = 1.f / fmaxf(sqrtf(nrm2), 1e-8f);
    const float* dl = deltap + (size_t)d * 64;
    float res[4];
    #pragma unroll
    for (int k = 0; k < 4; ++k) {
        const float4* dk = (const float4*)(dl + k * 16);
        float sacc = 0.f;
        #pragma unroll
        for (int q = 0; q < 4; ++q) {
            float4 tv = dk[q];
            sacc += dv[q * 4 + 0] * tv.x;
            sacc += dv[q * 4 + 1] * tv.y;
            sacc += dv[q * 4 + 2] * tv.z;
            sacc += dv[q * 4 + 3] * tv.w;
        }
        res[k] = sacc * inv;
    }
    csr_w[e] = make_float4(__expf(res[0]), __expf(res[1]),
                           __expf(res[2]), __expf(res[3]));
}

// ---------------------------------------------------------------------------
// per-dst aggregation, wave per node, lane = channel.
// ---------------------------------------------------------------------------
__global__ __launch_bounds__(256) void aggregate_k(const int* __restrict__ offs,
                                                   const int* __restrict__ csr_src,
                                                   const float* __restrict__ csr_wf,
                                                   const unsigned int* __restrict__ h8,
                                                   const float* __restrict__ bias,
                                                   float* __restrict__ out) {
    int wave = threadIdx.x >> 6;
    int lane = threadIdx.x & 63;
    int n = blockIdx.x * 4 + wave;
    if (n >= NN) return;
    int beg = offs[n], end = offs[n + 1];

    // phase 1: denominators (flat coalesced read; k-class = lane&3)
    float part = 0.f;
    for (int q = beg * 4 + lane; q < end * 4; q += 64) part += csr_wf[q];
    #pragma unroll
    for (int s = 4; s < 64; s <<= 1) part += __shfl_xor(part, s);
    float inv = (part > 0.f) ? 1.f / part : 0.f;
    float i0 = __shfl(inv, 0), i1 = __shfl(inv, 1);
    float i2 = __shfl(inv, 2), i3 = __shfl(inv, 3);

    // phase 2: weighted accumulation (packed fp8 decode)
    const float4* csr_w = (const float4*)csr_wf;
    float a0 = 0.f, a1 = 0.f, a2 = 0.f, a3 = 0.f;
    int p = beg;
    for (; p + 3 < end; p += 4) {
        float4 w0 = csr_w[p], w1 = csr_w[p + 1], w2 = csr_w[p + 2], w3 = csr_w[p + 3];
        int s0 = csr_src[p], s1 = csr_src[p + 1], s2 = csr_src[p + 2], s3 = csr_src[p + 3];
        unsigned hv0 = h8[(size_t)s0 * 64 + lane];
        unsigned hv1 = h8[(size_t)s1 * 64 + lane];
        unsigned hv2 = h8[(size_t)s2 * 64 + lane];
        unsigned hv3 = h8[(size_t)s3 * 64 + lane];
        f32x2 lo, hi;
        lo = __builtin_amdgcn_cvt_pk_f32_fp8(hv0, false);
        hi = __builtin_amdgcn_cvt_pk_f32_fp8(hv0, true);
        a0 += w0.x * lo.x; a1 += w0.y * lo.y; a2 += w0.z * hi.x; a3 += w0.w * hi.y;
        lo = __builtin_amdgcn_cvt_pk_f32_fp8(hv1, false);
        hi = __builtin_amdgcn_cvt_pk_f32_fp8(hv1, true);
        a0 += w1.x * lo.x; a1 += w1.y * lo.y; a2 += w1.z * hi.x; a3 += w1.w * hi.y;
        lo = __builtin_amdgcn_cvt_pk_f32_fp8(hv2, false);
        hi = __builtin_amdgcn_cvt_pk_f32_fp8(hv2, true);
        a0 += w2.x * lo.x; a1 += w2.y * lo.y; a2 += w2.z * hi.x; a3 += w2.w * hi.y;
        lo = __builtin_amdgcn_cvt_pk_f32_fp8(hv3, false);
        hi = __builtin_amdgcn_cvt_pk_f32_fp8(hv3, true);
        a0 += w3.x * lo.x; a1 += w3.y * lo.y; a2 += w3.z * hi.x; a3 += w3.w * hi.y;
    }
    for (; p < end; ++p) {
        float4 wA = csr_w[p];
        int sA = csr_src[p];
        unsigned hv = h8[(size_t)sA * 64 + lane];
        f32x2 lo = __builtin_amdgcn_cvt_pk_f32_fp8(hv, false);
        f32x2 hi = __builtin_amdgcn_cvt_pk_f32_fp8(hv, true);
        a0 += wA.x * lo.x; a1 += wA.y * lo.y; a2 += wA.z * hi.x; a3 += wA.w * hi.y;
    }
    float v = a0 * i0 + a1 * i1 + a2 * i2 + a3 * i3 + bias[lane];
    float nr = v * v;
    #pragma unroll
    for (int s = 32; s; s >>= 1) nr += __shfl_xor(nr, s);
    float invn = 1.f / fmaxf(sqrtf(nr), 1e-8f);
    out[(size_t)n * 64 + lane] = v * invn;
}

// ---------------------------------------------------------------------------
extern "C" void kernel_launch(void* const* d_in, const int* in_sizes, int n_in,
                              void* d_out, int out_size, void* d_ws, size_t ws_size,
                              hipStream_t stream) {
    const float* h_l       = (const float*)d_in[0];
    const float* e_l       = (const float*)d_in[1];
    const int*   src       = (const int*)d_in[2];
    const int*   dst       = (const int*)d_in[3];
    const float* W_phi     = (const float*)d_in[4];
    const float* W1        = (const float*)d_in[5];
    const float* b1        = (const float*)d_in[6];
    const float* W2        = (const float*)d_in[7];
    const float* b2        = (const float*)d_in[8];
    const float* tilde_phi = (const float*)d_in[9];
    const float* W         = (const float*)d_in[10];
    const float* bias      = (const float*)d_in[11];
    float* out = (float*)d_out;
    float* lsep_ptr   = out + (size_t)NN * 64;
    float* lfocus_ptr = out + (size_t)NN * 64 + 1;

    char* ws = (char*)d_ws;
    size_t off = 0;
    auto alloc = [&](size_t bytes) -> char* {
        char* p = ws + off;
        off += (bytes + 255) & ~(size_t)255;
        return p;
    };
    float*          phi     = (float*)alloc((size_t)NN * 16 * 4);
    float*          deltap  = (float*)alloc((size_t)NN * 64 * 4);
    unsigned char*  h8      = (unsigned char*)alloc((size_t)NN * 256);
    unsigned short* hid_bf  = (unsigned short*)alloc((size_t)NN * 256 * 2);
    unsigned short* e_bf    = (unsigned short*)alloc((size_t)NN * 128 * 2);
    unsigned short* hl_bf   = (unsigned short*)alloc((size_t)NN * 256 * 2);
    int*            csr_src = (int*)alloc((size_t)EE * 4);
    int*            csr_dst = (int*)alloc((size_t)EE * 4);
    int*            rank    = (int*)alloc((size_t)EE * 4);
    float*          csr_w   = (float*)alloc((size_t)EE * 4 * 4);
    int*            deg     = (int*)alloc((size_t)NN * 4);
    int*            offs    = (int*)alloc((size_t)(NN + 1) * 4);
    int*            bsum    = (int*)alloc((size_t)SCAN_NB * 4);
    float*          lf_part = (float*)alloc((size_t)DELTA_NB * 4);
    unsigned short* W_t     = (unsigned short*)alloc(256 * 256 * 2);
    unsigned short* W1_bf   = (unsigned short*)alloc(256 * 128 * 2);
    unsigned short* W2_bf   = (unsigned short*)alloc(64 * 256 * 2);
    unsigned short* Wphi_t  = (unsigned short*)alloc(16 * 128 * 2);
    float*          tnorm   = (float*)alloc(64 * 4);

    hipMemsetAsync(deg, 0, (size_t)NN * 4, stream);

    // prep: tnorm/lsep + weight prep + bf16 casts + degree/rank
    prep_k<<<(PREP_THREADS + 255) / 256, 256, 0, stream>>>(
        W, W1, W2, W_phi, e_l, h_l, tilde_phi, dst,
        W_t, W1_bf, W2_bf, Wphi_t, e_bf, hl_bf, deg, rank, tnorm, lsep_ptr);

    // CSR offsets (+ contiguous csr_dst fill)
    scan_partial_k<<<SCAN_NB, 256, 0, stream>>>(deg, bsum);
    scan_bsum_k<<<1, 256, 0, stream>>>(bsum);
    scan_scatter_k<<<SCAN_NB, 256, 0, stream>>>(deg, bsum, offs, csr_dst);

    // merged: rank-based scatter (no atomics) + h-GEMM + hid-GEMM + phi-GEMM
    fused3_k<<<2346, 256, 0, stream>>>(e_bf, hl_bf, W1_bf, Wphi_t, W_t, b1,
                                       hid_bf, phi, h8, src, dst, rank, offs,
                                       csr_src);

    // delta' (depends on hid); l_focus partials
    delta_k<<<DELTA_NB, 256, 0, stream>>>(hid_bf, W2_bf, b2, deltap, lf_part, tnorm);

    // edge weights + l_focus finalize
    edge_w_k<<<3126, 256, 0, stream>>>(csr_src, csr_dst, phi, deltap, (float4*)csr_w,
                                       lf_part, lfocus_ptr);

    // per-dst softmax + aggregation + normalize
    aggregate_k<<<12500, 256, 0, stream>>>(offs, csr_src, csr_w,
                                           (const unsigned int*)h8, bias, out);
}

// Round 17
// 178.877 us; speedup vs baseline: 1.7654x; 1.0500x over previous
//
#include <hip/hip_runtime.h>
#include <math.h>

#define NN 50000
#define EE 800000

typedef __attribute__((ext_vector_type(8))) short short8;
typedef __attribute__((ext_vector_type(4))) float f32x4;
typedef __attribute__((ext_vector_type(2))) float f32x2;

__device__ inline unsigned short f2b(float f) {
    unsigned u = __float_as_uint(f);
    unsigned r = (u + 0x7FFFu + ((u >> 16) & 1u)) >> 16;   // RNE
    return (unsigned short)r;
}
__device__ inline unsigned char f2fp8(float v) {
    return (unsigned char)(__builtin_amdgcn_cvt_pk_fp8_f32(v, v, 0, false) & 0xFF);
}
__device__ inline unsigned cvt_pk_bf16(float lo, float hi) {
    unsigned r;
    asm("v_cvt_pk_bf16_f32 %0, %1, %2" : "=v"(r) : "v"(lo), "v"(hi));
    return r;
}
__device__ inline void gload16(const unsigned short* g, unsigned short* l) {
    __builtin_amdgcn_global_load_lds(
        (const __attribute__((address_space(1))) void*)g,
        (__attribute__((address_space(3))) void*)l, 16, 0, 0);
}

// ---------------------------------------------------------------------------
// prep: rank/degree atomics FIRST (longest pole), then weight preps.
// e_l/h_l casts are GONE (GEMMs now read f32 directly, cvt in-register).
// ---------------------------------------------------------------------------
#define PREP_THREADS (800000 + 65536 + 32768 + 16384 + 2048)

__global__ __launch_bounds__(256) void prep_k(const float* __restrict__ W,
                                              const float* __restrict__ W1,
                                              const float* __restrict__ W2,
                                              const float* __restrict__ W_phi,
                                              const float* __restrict__ tilde_phi,
                                              const int* __restrict__ dst,
                                              unsigned short* __restrict__ W_t,
                                              unsigned short* __restrict__ W1_bf,
                                              unsigned short* __restrict__ W2_bf,
                                              unsigned short* __restrict__ Wphi_t,
                                              int* __restrict__ deg,
                                              int* __restrict__ rank,
                                              float* __restrict__ tnorm,
                                              float* __restrict__ lsep_out) {
    if (blockIdx.x == 0) {
        __shared__ float tn[64];
        int t = threadIdx.x;
        if (t < 64) {
            float v = tilde_phi[t];
            float sq = v * v;
            #pragma unroll
            for (int s = 8; s; s >>= 1) sq += __shfl_xor(sq, s, 16);
            float tnv = v / sqrtf(sq);
            tn[t] = tnv;
            tnorm[t] = tnv;
        }
        __syncthreads();
        if (t == 0) {
            float tot = 0.f;
            for (int a = 0; a < 4; ++a)
                for (int b = 0; b < 4; ++b) {
                    float s2 = 0.f;
                    for (int p = 0; p < 16; ++p) {
                        float df = tn[a * 16 + p] - tn[b * 16 + p];
                        s2 += df * df;
                    }
                    tot += s2;
                }
            lsep_out[0] = tot * 0.25f;
        }
    }
    int i = blockIdx.x * 256 + threadIdx.x;
    if (i < 800000) {
        rank[i] = atomicAdd(&deg[dst[i]], 1);
    } else if (i < 865536) {
        int j = i - 800000;
        int cp = j >> 8, r = j & 255;
        int ch = cp >> 2, k = cp & 3;
        W_t[j] = f2b(W[(size_t)r * 256 + (k << 6) + ch]);
    } else if (i < 898304) {
        int j = i - 865536;
        W1_bf[j] = f2b(W1[j]);
    } else if (i < 914688) {
        int j = i - 898304;
        W2_bf[j] = f2b(W2[j]);
    } else if (i < 916736) {
        int j = i - 914688;
        int cp = j >> 7, r = j & 127;
        Wphi_t[j] = (cp < 15) ? f2b(W_phi[(size_t)r * 15 + cp]) : (unsigned short)0;
    }
}

// ---------------------------------------------------------------------------
// GEMM body: single-buffer (stage -> sync -> MFMA -> sync), row-major [BM][32]
// LDS. A: f32 (AF32: load f32, cvt_pk_bf16 in-reg, ds_write_b128) or bf16
// (global_load_lds). B: bf16 via global_load_lds.
// lds must hold BM*32 + BN*32 ushorts.
// ---------------------------------------------------------------------------
template <int KD, int BM, int BN, int WR, int WC, bool RELU, int OMODE,
          bool AF32, bool LFOCUS, bool TNADJ>
__device__ __forceinline__ void ggemm_body(unsigned short* lds,
                                           const void* __restrict__ A,
                                           const unsigned short* __restrict__ Bt,
                                           const float* __restrict__ bias_vec,
                                           void* __restrict__ Cout, int ldc,
                                           float* __restrict__ lfocus_part,
                                           const float* __restrict__ tn_vec,
                                           int bxm, int bxn) {
    const int AM = BM / (WR * 16), AN = BN / (WC * 16);
    unsigned short* As = lds;              // [BM][32]
    unsigned short* Bs = lds + BM * 32;    // [BN][32]
    const int tid = threadIdx.x;
    const int l = tid & 63, l15 = l & 15, l4 = l >> 4;
    const int w = tid >> 6;
    const int wr = w / WC, wc = w % WC;
    const int row0 = bxm * BM;
    const int col0 = bxn * BN;
    const int wrow = wr * AM * 16, wcol = wc * AN * 16;

    auto stage = [&](int k0) {
        #pragma unroll
        for (int o = tid; o < BM * 4; o += 256) {
            int r = o >> 2, s = o & 3;
            int gr = row0 + r; if (gr >= NN) gr = NN - 1;
            if (AF32) {
                const float* Af = (const float*)A + (size_t)gr * KD + k0 + s * 8;
                float4 f0 = *(const float4*)Af;
                float4 f1 = *(const float4*)(Af + 4);
                *(uint4*)&As[o * 8] = make_uint4(cvt_pk_bf16(f0.x, f0.y),
                                                 cvt_pk_bf16(f0.z, f0.w),
                                                 cvt_pk_bf16(f1.x, f1.y),
                                                 cvt_pk_bf16(f1.z, f1.w));
            } else {
                gload16(&((const unsigned short*)A)[(size_t)gr * KD + k0 + s * 8],
                        &As[(o - l) * 8]);
            }
        }
        #pragma unroll
        for (int o = tid; o < BN * 4; o += 256) {
            int r = o >> 2, s = o & 3;
            gload16(&Bt[(size_t)(col0 + r) * KD + k0 + s * 8], &Bs[(o - l) * 8]);
        }
    };

    f32x4 acc[AM][AN];
    #pragma unroll
    for (int m = 0; m < AM; ++m)
        #pragma unroll
        for (int n = 0; n < AN; ++n)
            acc[m][n] = (f32x4){0.f, 0.f, 0.f, 0.f};

    const int NT = KD / 32;
    stage(0);
    for (int t = 0; t < NT; ++t) {
        __syncthreads();                    // staging visible
        short8 af[AM], bfr[AN];
        #pragma unroll
        for (int m = 0; m < AM; ++m)
            af[m] = *(const short8*)&As[((wrow + m * 16 + l15) * 4 + l4) * 8];
        #pragma unroll
        for (int n = 0; n < AN; ++n)
            bfr[n] = *(const short8*)&Bs[((wcol + n * 16 + l15) * 4 + l4) * 8];
        #pragma unroll
        for (int m = 0; m < AM; ++m)
            #pragma unroll
            for (int n = 0; n < AN; ++n)
                acc[m][n] = __builtin_amdgcn_mfma_f32_16x16x32_bf16(af[m], bfr[n], acc[m][n], 0, 0, 0);
        if (t + 1 < NT) {
            __syncthreads();                // reads done before overwrite
            stage((t + 1) * 32);
        }
    }

    float lf = 0.f;
    // C/D layout: col=lane&15, row=(lane>>4)*4+reg
    #pragma unroll
    for (int m = 0; m < AM; ++m) {
        #pragma unroll
        for (int n = 0; n < AN; ++n) {
            int gc = col0 + wcol + n * 16 + l15;
            float bv = bias_vec ? bias_vec[gc] : 0.f;
            float tv = TNADJ ? tn_vec[gc] : 0.f;
            #pragma unroll
            for (int r = 0; r < 4; ++r) {
                int gr = row0 + wrow + m * 16 + l4 * 4 + r;
                if (gr >= NN) continue;
                float v = acc[m][n][r] + bv;
                if (RELU) v = fmaxf(v, 0.f);
                if (LFOCUS) lf += v * v;
                if (TNADJ) v += tv;
                if (OMODE == 0)
                    ((float*)Cout)[(size_t)gr * ldc + gc] = v;
                else if (OMODE == 1)
                    ((unsigned short*)Cout)[(size_t)gr * ldc + gc] = f2b(v);
                else
                    ((unsigned char*)Cout)[(size_t)gr * ldc + gc] = f2fp8(v);
            }
        }
    }
    if (LFOCUS) {
        #pragma unroll
        for (int s = 32; s; s >>= 1) lf += __shfl_xor(lf, s);
        __syncthreads();
        float* red = (float*)lds;
        if (l == 0) red[w] = lf;
        __syncthreads();
        if (tid == 0)
            lfocus_part[bxm] = red[0] + red[1] + red[2] + red[3];
    }
}

// ---------------------------------------------------------------------------
// merged dispatch (16KB LDS/block). Block ranges:
//   [0,391)       CSR scatter: pos = offs[dst] + rank (pure stores, ILP-8)
//   [391,1173)    h-GEMM   (A = h_l f32)
//   [1173,1955)   hid-GEMM (A = e_l f32)
//   [1955,2346)   phi-GEMM (A = e_l f32)
// ---------------------------------------------------------------------------
__global__ __launch_bounds__(256) void fused3_k(const float* __restrict__ e_l,
                                                const float* __restrict__ h_l,
                                                const unsigned short* __restrict__ W1_bf,
                                                const unsigned short* __restrict__ Wphi_t,
                                                const unsigned short* __restrict__ W_t,
                                                const float* __restrict__ b1,
                                                unsigned short* __restrict__ hid_bf,
                                                float* __restrict__ phi,
                                                unsigned char* __restrict__ h8,
                                                const int* __restrict__ src,
                                                const int* __restrict__ dst,
                                                const int* __restrict__ rank,
                                                const int* __restrict__ offs,
                                                int* __restrict__ csr_src) {
    __shared__ __align__(16) unsigned short lds[128 * 32 + 128 * 32];
    int bx = blockIdx.x;
    if (bx < 391) {
        int base = bx * 2048 + threadIdx.x;
        int pos[8], sv[8];
        #pragma unroll
        for (int j = 0; j < 8; ++j) {
            int e = base + j * 256;
            if (e < EE) {
                pos[j] = offs[dst[e]] + rank[e];
                sv[j] = src[e];
            } else pos[j] = -1;
        }
        #pragma unroll
        for (int j = 0; j < 8; ++j)
            if (pos[j] >= 0) csr_src[pos[j]] = sv[j];
    } else if (bx < 1173) {
        int b = bx - 391;
        ggemm_body<256, 128, 128, 2, 2, false, 2, true, false, false>(
            lds, h_l, W_t, nullptr, h8, 256, nullptr, nullptr, b >> 1, b & 1);
    } else if (bx < 1955) {
        int b = bx - 1173;
        ggemm_body<128, 128, 128, 2, 2, true, 1, true, false, false>(
            lds, e_l, W1_bf, b1, hid_bf, 256, nullptr, nullptr, b >> 1, b & 1);
    } else {
        ggemm_body<128, 128, 16, 4, 1, false, 0, true, false, false>(
            lds, e_l, Wphi_t, nullptr, phi, 16, nullptr, nullptr, bx - 1955, 0);
    }
}

// ---------------------------------------------------------------------------
// delta' = hid @ W2^T + b2 (+tnorm); l_focus partials -> array. 6KB LDS.
// ---------------------------------------------------------------------------
__global__ __launch_bounds__(256) void delta_k(const unsigned short* __restrict__ hid_bf,
                                               const unsigned short* __restrict__ W2_bf,
                                               const float* __restrict__ b2,
                                               float* __restrict__ deltap,
                                               float* __restrict__ lfocus_part,
                                               const float* __restrict__ tnorm) {
    __shared__ __align__(16) unsigned short lds[32 * 32 + 64 * 32];
    ggemm_body<256, 32, 64, 1, 4, false, 0, false, true, true>(
        lds, hid_bf, W2_bf, b2, deltap, 64, lfocus_part, tnorm, blockIdx.x, 0);
}

// ---------------------------------------------------------------------------
#define SCAN_NB ((NN + 255) / 256)   // 196
#define DELTA_NB 1563

__global__ __launch_bounds__(256) void scan_partial_k(const int* __restrict__ deg,
                                                      int* __restrict__ bsum) {
    __shared__ int ws_[4];
    int i = blockIdx.x * 256 + threadIdx.x;
    int v = (i < NN) ? deg[i] : 0;
    int x = v;
    #pragma unroll
    for (int s = 32; s; s >>= 1) x += __shfl_xor(x, s);
    if ((threadIdx.x & 63) == 0) ws_[threadIdx.x >> 6] = x;
    __syncthreads();
    if (threadIdx.x == 0) bsum[blockIdx.x] = ws_[0] + ws_[1] + ws_[2] + ws_[3];
}

__global__ __launch_bounds__(256) void scan_bsum_k(int* __restrict__ bsum) {
    __shared__ int sd[256];
    int t = threadIdx.x;
    int v = (t < SCAN_NB) ? bsum[t] : 0;
    sd[t] = v;
    __syncthreads();
    for (int s = 1; s < 256; s <<= 1) {
        int u = (t >= s) ? sd[t - s] : 0;
        __syncthreads();
        sd[t] += u;
        __syncthreads();
    }
    if (t < SCAN_NB) bsum[t] = sd[t] - v;   // exclusive
}

__global__ __launch_bounds__(256) void scan_scatter_k(const int* __restrict__ deg,
                                                      const int* __restrict__ bsum,
                                                      int* __restrict__ offs,
                                                      int* __restrict__ csr_dst) {
    __shared__ int wexc[4];
    int i = blockIdx.x * 256 + threadIdx.x;
    int lane = threadIdx.x & 63, wid = threadIdx.x >> 6;
    int v = (i < NN) ? deg[i] : 0;
    int x = v;
    #pragma unroll
    for (int d = 1; d < 64; d <<= 1) { int u = __shfl_up(x, d); if (lane >= d) x += u; }
    if (lane == 63) wexc[wid] = x;
    __syncthreads();
    if (threadIdx.x == 0) {
        int a = wexc[0], b = wexc[1], c = wexc[2];
        wexc[0] = 0; wexc[1] = a; wexc[2] = a + b; wexc[3] = a + b + c;
    }
    __syncthreads();
    int excl = (x - v) + wexc[wid] + bsum[blockIdx.x];
    if (i < NN) {
        offs[i + 1] = excl + v;
        if (i == 0) offs[0] = 0;
        for (int q = excl; q < excl + v; ++q) csr_dst[q] = i;   // contiguous fill
    }
}

// ---------------------------------------------------------------------------
// edge weights (thread per CSR slot); block 3125 finalizes l_focus.
// ---------------------------------------------------------------------------
__global__ __launch_bounds__(256) void edge_w_k(const int* __restrict__ csr_src,
                                                const int* __restrict__ csr_dst,
                                                const float* __restrict__ phi,
                                                const float* __restrict__ deltap,
                                                float4* __restrict__ csr_w,
                                                const float* __restrict__ lfocus_part,
                                                float* __restrict__ lfocus_out) {
    if (blockIdx.x == 3125) {
        __shared__ float red[4];
        float s = 0.f;
        for (int i = threadIdx.x; i < DELTA_NB; i += 256) s += lfocus_part[i];
        #pragma unroll
        for (int st = 32; st; st >>= 1) s += __shfl_xor(s, st);
        if ((threadIdx.x & 63) == 0) red[threadIdx.x >> 6] = s;
        __syncthreads();
        if (threadIdx.x == 0)
            lfocus_out[0] = (red[0] + red[1] + red[2] + red[3]) * (1.f / ((float)NN * 4));
        return;
    }
    int e = blockIdx.x * 256 + threadIdx.x;
    if (e >= EE) return;
    int s = csr_src[e], d = csr_dst[e];
    const float4* ps4 = (const float4*)(phi + (size_t)s * 16);
    const float4* pd4 = (const float4*)(phi + (size_t)d * 16);
    float dv[16];
    float nrm2 = 0.f;
    #pragma unroll
    for (int q = 0; q < 4; ++q) {
        float4 a = ps4[q], b = pd4[q];
        dv[q * 4 + 0] = a.x - b.x;
        dv[q * 4 + 1] = a.y - b.y;
        dv[q * 4 + 2] = a.z - b.z;
        dv[q * 4 + 3] = a.w - b.w;
    }
    #pragma unroll
    for (int p = 0; p < 15; ++p) nrm2 += dv[p] * dv[p];
    float z = (nrm2 == 0.f) ? 1.f : 0.f;
    dv[15] = z;
    nrm2 += z;
    float inv = 1.f / fmaxf(sqrtf(nrm2), 1e-8f);
    const float* dl = deltap + (size_t)d * 64;
    float res[4];
    #pragma unroll
    for (int k = 0; k < 4; ++k) {
        const float4* dk = (const float4*)(dl + k * 16);
        float sacc = 0.f;
        #pragma unroll
        for (int q = 0; q < 4; ++q) {
            float4 tv = dk[q];
            sacc += dv[q * 4 + 0] * tv.x;
            sacc += dv[q * 4 + 1] * tv.y;
            sacc += dv[q * 4 + 2] * tv.z;
            sacc += dv[q * 4 + 3] * tv.w;
        }
        res[k] = sacc * inv;
    }
    csr_w[e] = make_float4(__expf(res[0]), __expf(res[1]),
                           __expf(res[2]), __expf(res[3]));
}

// ---------------------------------------------------------------------------
// per-dst aggregation, wave per node, lane = channel.
// ---------------------------------------------------------------------------
__global__ __launch_bounds__(256) void aggregate_k(const int* __restrict__ offs,
                                                   const int* __restrict__ csr_src,
                                                   const float* __restrict__ csr_wf,
                                                   const unsigned int* __restrict__ h8,
                                                   const float* __restrict__ bias,
                                                   float* __restrict__ out) {
    int wave = threadIdx.x >> 6;
    int lane = threadIdx.x & 63;
    int n = blockIdx.x * 4 + wave;
    if (n >= NN) return;
    int beg = offs[n], end = offs[n + 1];

    // phase 1: denominators (flat coalesced read; k-class = lane&3)
    float part = 0.f;
    for (int q = beg * 4 + lane; q < end * 4; q += 64) part += csr_wf[q];
    #pragma unroll
    for (int s = 4; s < 64; s <<= 1) part += __shfl_xor(part, s);
    float inv = (part > 0.f) ? 1.f / part : 0.f;
    float i0 = __shfl(inv, 0), i1 = __shfl(inv, 1);
    float i2 = __shfl(inv, 2), i3 = __shfl(inv, 3);

    // phase 2: weighted accumulation (packed fp8 decode)
    const float4* csr_w = (const float4*)csr_wf;
    float a0 = 0.f, a1 = 0.f, a2 = 0.f, a3 = 0.f;
    int p = beg;
    for (; p + 3 < end; p += 4) {
        float4 w0 = csr_w[p], w1 = csr_w[p + 1], w2 = csr_w[p + 2], w3 = csr_w[p + 3];
        int s0 = csr_src[p], s1 = csr_src[p + 1], s2 = csr_src[p + 2], s3 = csr_src[p + 3];
        unsigned hv0 = h8[(size_t)s0 * 64 + lane];
        unsigned hv1 = h8[(size_t)s1 * 64 + lane];
        unsigned hv2 = h8[(size_t)s2 * 64 + lane];
        unsigned hv3 = h8[(size_t)s3 * 64 + lane];
        f32x2 lo, hi;
        lo = __builtin_amdgcn_cvt_pk_f32_fp8(hv0, false);
        hi = __builtin_amdgcn_cvt_pk_f32_fp8(hv0, true);
        a0 += w0.x * lo.x; a1 += w0.y * lo.y; a2 += w0.z * hi.x; a3 += w0.w * hi.y;
        lo = __builtin_amdgcn_cvt_pk_f32_fp8(hv1, false);
        hi = __builtin_amdgcn_cvt_pk_f32_fp8(hv1, true);
        a0 += w1.x * lo.x; a1 += w1.y * lo.y; a2 += w1.z * hi.x; a3 += w1.w * hi.y;
        lo = __builtin_amdgcn_cvt_pk_f32_fp8(hv2, false);
        hi = __builtin_amdgcn_cvt_pk_f32_fp8(hv2, true);
        a0 += w2.x * lo.x; a1 += w2.y * lo.y; a2 += w2.z * hi.x; a3 += w2.w * hi.y;
        lo = __builtin_amdgcn_cvt_pk_f32_fp8(hv3, false);
        hi = __builtin_amdgcn_cvt_pk_f32_fp8(hv3, true);
        a0 += w3.x * lo.x; a1 += w3.y * lo.y; a2 += w3.z * hi.x; a3 += w3.w * hi.y;
    }
    for (; p < end; ++p) {
        float4 wA = csr_w[p];
        int sA = csr_src[p];
        unsigned hv = h8[(size_t)sA * 64 + lane];
        f32x2 lo = __builtin_amdgcn_cvt_pk_f32_fp8(hv, false);
        f32x2 hi = __builtin_amdgcn_cvt_pk_f32_fp8(hv, true);
        a0 += wA.x * lo.x; a1 += wA.y * lo.y; a2 += wA.z * hi.x; a3 += wA.w * hi.y;
    }
    float v = a0 * i0 + a1 * i1 + a2 * i2 + a3 * i3 + bias[lane];
    float nr = v * v;
    #pragma unroll
    for (int s = 32; s; s >>= 1) nr += __shfl_xor(nr, s);
    float invn = 1.f / fmaxf(sqrtf(nr), 1e-8f);
    out[(size_t)n * 64 + lane] = v * invn;
}

// ---------------------------------------------------------------------------
extern "C" void kernel_launch(void* const* d_in, const int* in_sizes, int n_in,
                              void* d_out, int out_size, void* d_ws, size_t ws_size,
                              hipStream_t stream) {
    const float* h_l       = (const float*)d_in[0];
    const float* e_l       = (const float*)d_in[1];
    const int*   src       = (const int*)d_in[2];
    const int*   dst       = (const int*)d_in[3];
    const float* W_phi     = (const float*)d_in[4];
    const float* W1        = (const float*)d_in[5];
    const float* b1        = (const float*)d_in[6];
    const float* W2        = (const float*)d_in[7];
    const float* b2        = (const float*)d_in[8];
    const float* tilde_phi = (const float*)d_in[9];
    const float* W         = (const float*)d_in[10];
    const float* bias      = (const float*)d_in[11];
    float* out = (float*)d_out;
    float* lsep_ptr   = out + (size_t)NN * 64;
    float* lfocus_ptr = out + (size_t)NN * 64 + 1;

    char* ws = (char*)d_ws;
    size_t off = 0;
    auto alloc = [&](size_t bytes) -> char* {
        char* p = ws + off;
        off += (bytes + 255) & ~(size_t)255;
        return p;
    };
    float*          phi     = (float*)alloc((size_t)NN * 16 * 4);
    float*          deltap  = (float*)alloc((size_t)NN * 64 * 4);
    unsigned char*  h8      = (unsigned char*)alloc((size_t)NN * 256);
    unsigned short* hid_bf  = (unsigned short*)alloc((size_t)NN * 256 * 2);
    int*            csr_src = (int*)alloc((size_t)EE * 4);
    int*            csr_dst = (int*)alloc((size_t)EE * 4);
    int*            rank    = (int*)alloc((size_t)EE * 4);
    float*          csr_w   = (float*)alloc((size_t)EE * 4 * 4);
    int*            deg     = (int*)alloc((size_t)NN * 4);
    int*            offs    = (int*)alloc((size_t)(NN + 1) * 4);
    int*            bsum    = (int*)alloc((size_t)SCAN_NB * 4);
    float*          lf_part = (float*)alloc((size_t)DELTA_NB * 4);
    unsigned short* W_t     = (unsigned short*)alloc(256 * 256 * 2);
    unsigned short* W1_bf   = (unsigned short*)alloc(256 * 128 * 2);
    unsigned short* W2_bf   = (unsigned short*)alloc(64 * 256 * 2);
    unsigned short* Wphi_t  = (unsigned short*)alloc(16 * 128 * 2);
    float*          tnorm   = (float*)alloc(64 * 4);

    hipMemsetAsync(deg, 0, (size_t)NN * 4, stream);

    // prep: rank/degree atomics + weight prep + tnorm/lsep
    prep_k<<<(PREP_THREADS + 255) / 256, 256, 0, stream>>>(
        W, W1, W2, W_phi, tilde_phi, dst,
        W_t, W1_bf, W2_bf, Wphi_t, deg, rank, tnorm, lsep_ptr);

    // CSR offsets (+ contiguous csr_dst fill)
    scan_partial_k<<<SCAN_NB, 256, 0, stream>>>(deg, bsum);
    scan_bsum_k<<<1, 256, 0, stream>>>(bsum);
    scan_scatter_k<<<SCAN_NB, 256, 0, stream>>>(deg, bsum, offs, csr_dst);

    // merged: rank-based scatter + h-GEMM + hid-GEMM + phi-GEMM (A read f32)
    fused3_k<<<2346, 256, 0, stream>>>(e_l, h_l, W1_bf, Wphi_t, W_t, b1,
                                       hid_bf, phi, h8, src, dst, rank, offs,
                                       csr_src);

    // delta' (depends on hid); l_focus partials
    delta_k<<<DELTA_NB, 256, 0, stream>>>(hid_bf, W2_bf, b2, deltap, lf_part, tnorm);

    // edge weights + l_focus finalize
    edge_w_k<<<3126, 256, 0, stream>>>(csr_src, csr_dst, phi, deltap, (float4*)csr_w,
                                       lf_part, lfocus_ptr);

    // per-dst softmax + aggregation + normalize
    aggregate_k<<<12500, 256, 0, stream>>>(offs, csr_src, csr_w,
                                           (const unsigned int*)h8, bias, out);
}

// Round 18
// 173.794 us; speedup vs baseline: 1.8170x; 1.0292x over previous
//
#include <hip/hip_runtime.h>
#include <math.h>

#define NN 50000
#define EE 800000

typedef __attribute__((ext_vector_type(8))) short short8;
typedef __attribute__((ext_vector_type(4))) float f32x4;
typedef __attribute__((ext_vector_type(2))) float f32x2;

__device__ inline unsigned short f2b(float f) {
    unsigned u = __float_as_uint(f);
    unsigned r = (u + 0x7FFFu + ((u >> 16) & 1u)) >> 16;   // RNE
    return (unsigned short)r;
}
__device__ inline unsigned char f2fp8(float v) {
    return (unsigned char)(__builtin_amdgcn_cvt_pk_fp8_f32(v, v, 0, false) & 0xFF);
}
__device__ inline unsigned cvt_pk_bf16(float lo, float hi) {
    unsigned r;
    asm("v_cvt_pk_bf16_f32 %0, %1, %2" : "=v"(r) : "v"(lo), "v"(hi));
    return r;
}
__device__ inline void gload16(const unsigned short* g, unsigned short* l) {
    __builtin_amdgcn_global_load_lds(
        (const __attribute__((address_space(1))) void*)g,
        (__attribute__((address_space(3))) void*)l, 16, 0, 0);
}

// ---------------------------------------------------------------------------
// prep: rank/degree atomics FIRST, then weight preps + tnorm/lsep.
// ---------------------------------------------------------------------------
#define PREP_THREADS (800000 + 65536 + 32768 + 16384 + 2048)

__global__ __launch_bounds__(256) void prep_k(const float* __restrict__ W,
                                              const float* __restrict__ W1,
                                              const float* __restrict__ W2,
                                              const float* __restrict__ W_phi,
                                              const float* __restrict__ tilde_phi,
                                              const int* __restrict__ dst,
                                              unsigned short* __restrict__ W_t,
                                              unsigned short* __restrict__ W1_bf,
                                              unsigned short* __restrict__ W2_bf,
                                              unsigned short* __restrict__ Wphi_t,
                                              int* __restrict__ deg,
                                              int* __restrict__ rank,
                                              float* __restrict__ tnorm,
                                              float* __restrict__ lsep_out) {
    if (blockIdx.x == 0) {
        __shared__ float tn[64];
        int t = threadIdx.x;
        if (t < 64) {
            float v = tilde_phi[t];
            float sq = v * v;
            #pragma unroll
            for (int s = 8; s; s >>= 1) sq += __shfl_xor(sq, s, 16);
            float tnv = v / sqrtf(sq);
            tn[t] = tnv;
            tnorm[t] = tnv;
        }
        __syncthreads();
        if (t == 0) {
            float tot = 0.f;
            for (int a = 0; a < 4; ++a)
                for (int b = 0; b < 4; ++b) {
                    float s2 = 0.f;
                    for (int p = 0; p < 16; ++p) {
                        float df = tn[a * 16 + p] - tn[b * 16 + p];
                        s2 += df * df;
                    }
                    tot += s2;
                }
            lsep_out[0] = tot * 0.25f;
        }
    }
    int i = blockIdx.x * 256 + threadIdx.x;
    if (i < 800000) {
        rank[i] = atomicAdd(&deg[dst[i]], 1);
    } else if (i < 865536) {
        int j = i - 800000;
        int cp = j >> 8, r = j & 255;
        int ch = cp >> 2, k = cp & 3;
        W_t[j] = f2b(W[(size_t)r * 256 + (k << 6) + ch]);
    } else if (i < 898304) {
        int j = i - 865536;
        W1_bf[j] = f2b(W1[j]);
    } else if (i < 914688) {
        int j = i - 898304;
        W2_bf[j] = f2b(W2[j]);
    } else if (i < 916736) {
        int j = i - 914688;
        int cp = j >> 7, r = j & 127;
        Wphi_t[j] = (cp < 15) ? f2b(W_phi[(size_t)r * 15 + cp]) : (unsigned short)0;
    }
}

// ---------------------------------------------------------------------------
// h-GEMM branch: BM=128, BN=128, KD=256, 512 thr (8 waves, 4x2), AM=2, AN=4.
// Single-buffer. A = h_l f32 (cvt in-reg). Out fp8 [ch][k]-interleaved.
// ---------------------------------------------------------------------------
__device__ __forceinline__ void hgemm8_body(unsigned short* lds,
                                            const float* __restrict__ A,
                                            const unsigned short* __restrict__ Bt,
                                            unsigned char* __restrict__ h8,
                                            int bxm, int bxn) {
    unsigned short* As = lds;          // [128][32]
    unsigned short* Bs = lds + 4096;   // [128][32]
    const int tid = threadIdx.x;
    const int l = tid & 63, l15 = l & 15, l4 = l >> 4;
    const int w = tid >> 6;
    const int wr = w >> 1, wc = w & 1;
    const int row0 = bxm * 128, col0 = bxn * 128;
    const int wrow = wr * 32, wcol = wc * 64;

    auto stage = [&](int k0) {
        {   // A: 512 16B-units (f32->bf16 in-reg)
            int o = tid, r = o >> 2, s = o & 3;
            int gr = row0 + r; if (gr >= NN) gr = NN - 1;
            const float* Af = A + (size_t)gr * 256 + k0 + s * 8;
            float4 f0 = *(const float4*)Af, f1 = *(const float4*)(Af + 4);
            *(uint4*)&As[o * 8] = make_uint4(cvt_pk_bf16(f0.x, f0.y), cvt_pk_bf16(f0.z, f0.w),
                                             cvt_pk_bf16(f1.x, f1.y), cvt_pk_bf16(f1.z, f1.w));
        }
        {   // B: 512 units via global_load_lds
            int o = tid, r = o >> 2, s = o & 3;
            gload16(&Bt[(size_t)(col0 + r) * 256 + k0 + s * 8], &Bs[(o - l) * 8]);
        }
    };

    f32x4 acc[2][4];
    #pragma unroll
    for (int m = 0; m < 2; ++m)
        #pragma unroll
        for (int n = 0; n < 4; ++n) acc[m][n] = (f32x4){0.f, 0.f, 0.f, 0.f};

    stage(0);
    for (int t = 0; t < 8; ++t) {
        __syncthreads();
        short8 af[2], bfr[4];
        #pragma unroll
        for (int m = 0; m < 2; ++m)
            af[m] = *(const short8*)&As[((wrow + m * 16 + l15) * 4 + l4) * 8];
        #pragma unroll
        for (int n = 0; n < 4; ++n)
            bfr[n] = *(const short8*)&Bs[((wcol + n * 16 + l15) * 4 + l4) * 8];
        #pragma unroll
        for (int m = 0; m < 2; ++m)
            #pragma unroll
            for (int n = 0; n < 4; ++n)
                acc[m][n] = __builtin_amdgcn_mfma_f32_16x16x32_bf16(af[m], bfr[n], acc[m][n], 0, 0, 0);
        if (t + 1 < 8) { __syncthreads(); stage((t + 1) * 32); }
    }
    #pragma unroll
    for (int m = 0; m < 2; ++m)
        #pragma unroll
        for (int n = 0; n < 4; ++n) {
            int gc = col0 + wcol + n * 16 + l15;
            #pragma unroll
            for (int r = 0; r < 4; ++r) {
                int gr = row0 + wrow + m * 16 + l4 * 4 + r;
                if (gr < NN) h8[(size_t)gr * 256 + gc] = f2fp8(acc[m][n][r]);
            }
        }
}

// ---------------------------------------------------------------------------
// hid+phi+delta branch: BM=64 rows of e_l.
// Stage 1: hid = relu(e_l@W1^T+b1) kept in regs (wave = 16 rows x 128 cols,
//          AN=8) + phi frag on wc==1 waves. hid -> LDS [64][264] bf16.
// Stage 2: delta' = hid@W2^T + b2 (+tnorm), lfocus; W2 read from global (L2).
// ---------------------------------------------------------------------------
#define LDPAD 264

__device__ __forceinline__ void hiddelta_body(unsigned short* lds,
                                              const float* __restrict__ e_l,
                                              const unsigned short* __restrict__ W1_bf,
                                              const unsigned short* __restrict__ Wphi_t,
                                              const unsigned short* __restrict__ W2_bf,
                                              const float* __restrict__ b1,
                                              const float* __restrict__ b2,
                                              const float* __restrict__ tnorm,
                                              float* __restrict__ phi,
                                              float* __restrict__ deltap,
                                              float* __restrict__ lf_part, int bxm) {
    unsigned short* As = lds;            // [64][32]   (stage 1)
    unsigned short* Bs = lds + 2048;     // [256][32]  (stage 1)
    unsigned short* Wp = lds + 10240;    // [16][128]  (stage 1)
    unsigned short* hidL = lds;          // [64][264]  (stage 2, aliases above)
    const int tid = threadIdx.x;
    const int l = tid & 63, l15 = l & 15, l4 = l >> 4;
    const int w = tid >> 6;              // 0..7
    const int wr = w >> 1, wc = w & 1;
    const int row0 = bxm * 64;

    // stage Wphi once (256 units, waves 0-3)
    if (tid < 256) gload16(&Wphi_t[tid * 8], &Wp[(tid - l) * 8]);

    auto stage = [&](int k0) {
        if (tid < 256) {   // A: 256 units (f32 cvt)
            int o = tid, r = o >> 2, s = o & 3;
            int gr = row0 + r; if (gr >= NN) gr = NN - 1;
            const float* Af = e_l + (size_t)gr * 128 + k0 + s * 8;
            float4 f0 = *(const float4*)Af, f1 = *(const float4*)(Af + 4);
            *(uint4*)&As[o * 8] = make_uint4(cvt_pk_bf16(f0.x, f0.y), cvt_pk_bf16(f0.z, f0.w),
                                             cvt_pk_bf16(f1.x, f1.y), cvt_pk_bf16(f1.z, f1.w));
        }
        #pragma unroll
        for (int o = tid; o < 1024; o += 512) {   // B: 1024 units
            int r = o >> 2, s = o & 3;
            gload16(&W1_bf[(size_t)r * 128 + k0 + s * 8], &Bs[(o - l) * 8]);
        }
    };

    f32x4 acc[8], pacc;
    #pragma unroll
    for (int n = 0; n < 8; ++n) acc[n] = (f32x4){0.f, 0.f, 0.f, 0.f};
    pacc = (f32x4){0.f, 0.f, 0.f, 0.f};

    stage(0);
    for (int t = 0; t < 4; ++t) {
        int k0 = t * 32;
        __syncthreads();
        short8 af = *(const short8*)&As[((wr * 16 + l15) * 4 + l4) * 8];
        short8 bfr[8];
        #pragma unroll
        for (int n = 0; n < 8; ++n)
            bfr[n] = *(const short8*)&Bs[((wc * 128 + n * 16 + l15) * 4 + l4) * 8];
        #pragma unroll
        for (int n = 0; n < 8; ++n)
            acc[n] = __builtin_amdgcn_mfma_f32_16x16x32_bf16(af, bfr[n], acc[n], 0, 0, 0);
        if (wc == 1) {
            short8 pf = *(const short8*)&Wp[l15 * 128 + k0 + l4 * 8];
            pacc = __builtin_amdgcn_mfma_f32_16x16x32_bf16(af, pf, pacc, 0, 0, 0);
        }
        if (t + 1 < 4) { __syncthreads(); stage((t + 1) * 32); }
    }

    __syncthreads();                      // all stage-1 LDS reads done
    // hid epilogue -> LDS bf16 [64][264]
    #pragma unroll
    for (int n = 0; n < 8; ++n) {
        int col = wc * 128 + n * 16 + l15;
        float bv = b1[col];
        #pragma unroll
        for (int r = 0; r < 4; ++r) {
            int row = wr * 16 + l4 * 4 + r;
            hidL[row * LDPAD + col] = f2b(fmaxf(acc[n][r] + bv, 0.f));
        }
    }
    // phi epilogue (wc==1 waves)
    if (wc == 1) {
        #pragma unroll
        for (int r = 0; r < 4; ++r) {
            int gr = row0 + wr * 16 + l4 * 4 + r;
            if (gr < NN) phi[(size_t)gr * 16 + l15] = pacc[r];
        }
    }
    __syncthreads();                      // hidL visible

    // stage 2: delta[64][64], wave = 16 rows x 32 cols, K=256
    f32x4 acc2[2];
    acc2[0] = (f32x4){0.f, 0.f, 0.f, 0.f};
    acc2[1] = (f32x4){0.f, 0.f, 0.f, 0.f};
    for (int kk = 0; kk < 8; ++kk) {
        int k0 = kk * 32;
        short8 a2 = *(const short8*)&hidL[(wr * 16 + l15) * LDPAD + k0 + l4 * 8];
        #pragma unroll
        for (int n = 0; n < 2; ++n) {
            int col = wc * 32 + n * 16 + l15;
            short8 b2f_ = *(const short8*)&W2_bf[(size_t)col * 256 + k0 + l4 * 8];
            acc2[n] = __builtin_amdgcn_mfma_f32_16x16x32_bf16(a2, b2f_, acc2[n], 0, 0, 0);
        }
    }
    float lf = 0.f;
    #pragma unroll
    for (int n = 0; n < 2; ++n) {
        int gc = wc * 32 + n * 16 + l15;
        float bv = b2[gc], tv = tnorm[gc];
        #pragma unroll
        for (int r = 0; r < 4; ++r) {
            int gr = row0 + wr * 16 + l4 * 4 + r;
            if (gr < NN) {
                float v = acc2[n][r] + bv;
                lf += v * v;
                deltap[(size_t)gr * 64 + gc] = v + tv;
            }
        }
    }
    #pragma unroll
    for (int s = 32; s; s >>= 1) lf += __shfl_xor(lf, s);
    __syncthreads();
    float* red = (float*)&lds[16896];
    if (l == 0) red[w] = lf;
    __syncthreads();
    if (tid == 0) {
        float t_ = 0.f;
        #pragma unroll
        for (int j = 0; j < 8; ++j) t_ += red[j];
        lf_part[bxm] = t_;
    }
}

// ---------------------------------------------------------------------------
// merged dispatch, 512 threads. Block ranges:
//   [0,391)      CSR scatter: pos = offs[dst]+rank (pure stores, ILP-4)
//   [391,1173)   h-GEMM (782)
//   [1173,1955)  hid+phi+delta (782)
// ---------------------------------------------------------------------------
__global__ __launch_bounds__(512) void fused3_k(const float* __restrict__ e_l,
                                                const float* __restrict__ h_l,
                                                const unsigned short* __restrict__ W1_bf,
                                                const unsigned short* __restrict__ Wphi_t,
                                                const unsigned short* __restrict__ W_t,
                                                const unsigned short* __restrict__ W2_bf,
                                                const float* __restrict__ b1,
                                                const float* __restrict__ b2,
                                                const float* __restrict__ tnorm,
                                                float* __restrict__ phi,
                                                unsigned char* __restrict__ h8,
                                                float* __restrict__ deltap,
                                                float* __restrict__ lf_part,
                                                const int* __restrict__ src,
                                                const int* __restrict__ dst,
                                                const int* __restrict__ rank,
                                                const int* __restrict__ offs,
                                                int* __restrict__ csr_src) {
    __shared__ __align__(16) unsigned short lds[17408];   // 34.8 KB
    int bx = blockIdx.x;
    if (bx < 391) {
        int base = bx * 2048 + threadIdx.x;
        int pos[4], sv[4];
        #pragma unroll
        for (int j = 0; j < 4; ++j) {
            int e = base + j * 512;
            if (e < EE) { pos[j] = offs[dst[e]] + rank[e]; sv[j] = src[e]; }
            else pos[j] = -1;
        }
        #pragma unroll
        for (int j = 0; j < 4; ++j)
            if (pos[j] >= 0) csr_src[pos[j]] = sv[j];
    } else if (bx < 1173) {
        int b = bx - 391;
        hgemm8_body(lds, h_l, W_t, h8, b >> 1, b & 1);
    } else {
        hiddelta_body(lds, e_l, W1_bf, Wphi_t, W2_bf, b1, b2, tnorm,
                      phi, deltap, lf_part, bx - 1173);
    }
}

// ---------------------------------------------------------------------------
#define SCAN_NB ((NN + 255) / 256)   // 196
#define LF_NB 782

__global__ __launch_bounds__(256) void scan_partial_k(const int* __restrict__ deg,
                                                      int* __restrict__ bsum) {
    __shared__ int ws_[4];
    int i = blockIdx.x * 256 + threadIdx.x;
    int v = (i < NN) ? deg[i] : 0;
    int x = v;
    #pragma unroll
    for (int s = 32; s; s >>= 1) x += __shfl_xor(x, s);
    if ((threadIdx.x & 63) == 0) ws_[threadIdx.x >> 6] = x;
    __syncthreads();
    if (threadIdx.x == 0) bsum[blockIdx.x] = ws_[0] + ws_[1] + ws_[2] + ws_[3];
}

__global__ __launch_bounds__(256) void scan_bsum_k(int* __restrict__ bsum) {
    __shared__ int sd[256];
    int t = threadIdx.x;
    int v = (t < SCAN_NB) ? bsum[t] : 0;
    sd[t] = v;
    __syncthreads();
    for (int s = 1; s < 256; s <<= 1) {
        int u = (t >= s) ? sd[t - s] : 0;
        __syncthreads();
        sd[t] += u;
        __syncthreads();
    }
    if (t < SCAN_NB) bsum[t] = sd[t] - v;   // exclusive
}

__global__ __launch_bounds__(256) void scan_scatter_k(const int* __restrict__ deg,
                                                      const int* __restrict__ bsum,
                                                      int* __restrict__ offs,
                                                      int* __restrict__ csr_dst) {
    __shared__ int wexc[4];
    int i = blockIdx.x * 256 + threadIdx.x;
    int lane = threadIdx.x & 63, wid = threadIdx.x >> 6;
    int v = (i < NN) ? deg[i] : 0;
    int x = v;
    #pragma unroll
    for (int d = 1; d < 64; d <<= 1) { int u = __shfl_up(x, d); if (lane >= d) x += u; }
    if (lane == 63) wexc[wid] = x;
    __syncthreads();
    if (threadIdx.x == 0) {
        int a = wexc[0], b = wexc[1], c = wexc[2];
        wexc[0] = 0; wexc[1] = a; wexc[2] = a + b; wexc[3] = a + b + c;
    }
    __syncthreads();
    int excl = (x - v) + wexc[wid] + bsum[blockIdx.x];
    if (i < NN) {
        offs[i + 1] = excl + v;
        if (i == 0) offs[0] = 0;
        for (int q = excl; q < excl + v; ++q) csr_dst[q] = i;
    }
}

// ---------------------------------------------------------------------------
// edge weights (thread per CSR slot); block 3125 finalizes l_focus.
// ---------------------------------------------------------------------------
__global__ __launch_bounds__(256) void edge_w_k(const int* __restrict__ csr_src,
                                                const int* __restrict__ csr_dst,
                                                const float* __restrict__ phi,
                                                const float* __restrict__ deltap,
                                                float4* __restrict__ csr_w,
                                                const float* __restrict__ lfocus_part,
                                                float* __restrict__ lfocus_out) {
    if (blockIdx.x == 3125) {
        __shared__ float red[4];
        float s = 0.f;
        for (int i = threadIdx.x; i < LF_NB; i += 256) s += lfocus_part[i];
        #pragma unroll
        for (int st = 32; st; st >>= 1) s += __shfl_xor(s, st);
        if ((threadIdx.x & 63) == 0) red[threadIdx.x >> 6] = s;
        __syncthreads();
        if (threadIdx.x == 0)
            lfocus_out[0] = (red[0] + red[1] + red[2] + red[3]) * (1.f / ((float)NN * 4));
        return;
    }
    int e = blockIdx.x * 256 + threadIdx.x;
    if (e >= EE) return;
    int s = csr_src[e], d = csr_dst[e];
    const float4* ps4 = (const float4*)(phi + (size_t)s * 16);
    const float4* pd4 = (const float4*)(phi + (size_t)d * 16);
    float dv[16];
    float nrm2 = 0.f;
    #pragma unroll
    for (int q = 0; q < 4; ++q) {
        float4 a = ps4[q], b = pd4[q];
        dv[q * 4 + 0] = a.x - b.x;
        dv[q * 4 + 1] = a.y - b.y;
        dv[q * 4 + 2] = a.z - b.z;
        dv[q * 4 + 3] = a.w - b.w;
    }
    #pragma unroll
    for (int p = 0; p < 15; ++p) nrm2 += dv[p] * dv[p];
    float z = (nrm2 == 0.f) ? 1.f : 0.f;
    dv[15] = z;
    nrm2 += z;
    float inv = 1.f / fmaxf(sqrtf(nrm2), 1e-8f);
    const float* dl = deltap + (size_t)d * 64;
    float res[4];
    #pragma unroll
    for (int k = 0; k < 4; ++k) {
        const float4* dk = (const float4*)(dl + k * 16);
        float sacc = 0.f;
        #pragma unroll
        for (int q = 0; q < 4; ++q) {
            float4 tv = dk[q];
            sacc += dv[q * 4 + 0] * tv.x;
            sacc += dv[q * 4 + 1] * tv.y;
            sacc += dv[q * 4 + 2] * tv.z;
            sacc += dv[q * 4 + 3] * tv.w;
        }
        res[k] = sacc * inv;
    }
    csr_w[e] = make_float4(__expf(res[0]), __expf(res[1]),
                           __expf(res[2]), __expf(res[3]));
}

// ---------------------------------------------------------------------------
// per-dst aggregation, wave per node, lane = channel.
// ---------------------------------------------------------------------------
__global__ __launch_bounds__(256) void aggregate_k(const int* __restrict__ offs,
                                                   const int* __restrict__ csr_src,
                                                   const float* __restrict__ csr_wf,
                                                   const unsigned int* __restrict__ h8,
                                                   const float* __restrict__ bias,
                                                   float* __restrict__ out) {
    int wave = threadIdx.x >> 6;
    int lane = threadIdx.x & 63;
    int n = blockIdx.x * 4 + wave;
    if (n >= NN) return;
    int beg = offs[n], end = offs[n + 1];

    float part = 0.f;
    for (int q = beg * 4 + lane; q < end * 4; q += 64) part += csr_wf[q];
    #pragma unroll
    for (int s = 4; s < 64; s <<= 1) part += __shfl_xor(part, s);
    float inv = (part > 0.f) ? 1.f / part : 0.f;
    float i0 = __shfl(inv, 0), i1 = __shfl(inv, 1);
    float i2 = __shfl(inv, 2), i3 = __shfl(inv, 3);

    const float4* csr_w = (const float4*)csr_wf;
    float a0 = 0.f, a1 = 0.f, a2 = 0.f, a3 = 0.f;
    int p = beg;
    for (; p + 3 < end; p += 4) {
        float4 w0 = csr_w[p], w1 = csr_w[p + 1], w2 = csr_w[p + 2], w3 = csr_w[p + 3];
        int s0 = csr_src[p], s1 = csr_src[p + 1], s2 = csr_src[p + 2], s3 = csr_src[p + 3];
        unsigned hv0 = h8[(size_t)s0 * 64 + lane];
        unsigned hv1 = h8[(size_t)s1 * 64 + lane];
        unsigned hv2 = h8[(size_t)s2 * 64 + lane];
        unsigned hv3 = h8[(size_t)s3 * 64 + lane];
        f32x2 lo, hi;
        lo = __builtin_amdgcn_cvt_pk_f32_fp8(hv0, false);
        hi = __builtin_amdgcn_cvt_pk_f32_fp8(hv0, true);
        a0 += w0.x * lo.x; a1 += w0.y * lo.y; a2 += w0.z * hi.x; a3 += w0.w * hi.y;
        lo = __builtin_amdgcn_cvt_pk_f32_fp8(hv1, false);
        hi = __builtin_amdgcn_cvt_pk_f32_fp8(hv1, true);
        a0 += w1.x * lo.x; a1 += w1.y * lo.y; a2 += w1.z * hi.x; a3 += w1.w * hi.y;
        lo = __builtin_amdgcn_cvt_pk_f32_fp8(hv2, false);
        hi = __builtin_amdgcn_cvt_pk_f32_fp8(hv2, true);
        a0 += w2.x * lo.x; a1 += w2.y * lo.y; a2 += w2.z * hi.x; a3 += w2.w * hi.y;
        lo = __builtin_amdgcn_cvt_pk_f32_fp8(hv3, false);
        hi = __builtin_amdgcn_cvt_pk_f32_fp8(hv3, true);
        a0 += w3.x * lo.x; a1 += w3.y * lo.y; a2 += w3.z * hi.x; a3 += w3.w * hi.y;
    }
    for (; p < end; ++p) {
        float4 wA = csr_w[p];
        int sA = csr_src[p];
        unsigned hv = h8[(size_t)sA * 64 + lane];
        f32x2 lo = __builtin_amdgcn_cvt_pk_f32_fp8(hv, false);
        f32x2 hi = __builtin_amdgcn_cvt_pk_f32_fp8(hv, true);
        a0 += wA.x * lo.x; a1 += wA.y * lo.y; a2 += wA.z * hi.x; a3 += wA.w * hi.y;
    }
    float v = a0 * i0 + a1 * i1 + a2 * i2 + a3 * i3 + bias[lane];
    float nr = v * v;
    #pragma unroll
    for (int s = 32; s; s >>= 1) nr += __shfl_xor(nr, s);
    float invn = 1.f / fmaxf(sqrtf(nr), 1e-8f);
    out[(size_t)n * 64 + lane] = v * invn;
}

// ---------------------------------------------------------------------------
extern "C" void kernel_launch(void* const* d_in, const int* in_sizes, int n_in,
                              void* d_out, int out_size, void* d_ws, size_t ws_size,
                              hipStream_t stream) {
    const float* h_l       = (const float*)d_in[0];
    const float* e_l       = (const float*)d_in[1];
    const int*   src       = (const int*)d_in[2];
    const int*   dst       = (const int*)d_in[3];
    const float* W_phi     = (const float*)d_in[4];
    const float* W1        = (const float*)d_in[5];
    const float* b1        = (const float*)d_in[6];
    const float* W2        = (const float*)d_in[7];
    const float* b2        = (const float*)d_in[8];
    const float* tilde_phi = (const float*)d_in[9];
    const float* W         = (const float*)d_in[10];
    const float* bias      = (const float*)d_in[11];
    float* out = (float*)d_out;
    float* lsep_ptr   = out + (size_t)NN * 64;
    float* lfocus_ptr = out + (size_t)NN * 64 + 1;

    char* ws = (char*)d_ws;
    size_t off = 0;
    auto alloc = [&](size_t bytes) -> char* {
        char* p = ws + off;
        off += (bytes + 255) & ~(size_t)255;
        return p;
    };
    float*          phi     = (float*)alloc((size_t)NN * 16 * 4);
    float*          deltap  = (float*)alloc((size_t)NN * 64 * 4);
    unsigned char*  h8      = (unsigned char*)alloc((size_t)NN * 256);
    int*            csr_src = (int*)alloc((size_t)EE * 4);
    int*            csr_dst = (int*)alloc((size_t)EE * 4);
    int*            rank    = (int*)alloc((size_t)EE * 4);
    float*          csr_w   = (float*)alloc((size_t)EE * 4 * 4);
    int*            deg     = (int*)alloc((size_t)NN * 4);
    int*            offs    = (int*)alloc((size_t)(NN + 1) * 4);
    int*            bsum    = (int*)alloc((size_t)SCAN_NB * 4);
    float*          lf_part = (float*)alloc((size_t)LF_NB * 4);
    unsigned short* W_t     = (unsigned short*)alloc(256 * 256 * 2);
    unsigned short* W1_bf   = (unsigned short*)alloc(256 * 128 * 2);
    unsigned short* W2_bf   = (unsigned short*)alloc(64 * 256 * 2);
    unsigned short* Wphi_t  = (unsigned short*)alloc(16 * 128 * 2);
    float*          tnorm   = (float*)alloc(64 * 4);

    hipMemsetAsync(deg, 0, (size_t)NN * 4, stream);

    // prep: rank/degree atomics + weight prep + tnorm/lsep
    prep_k<<<(PREP_THREADS + 255) / 256, 256, 0, stream>>>(
        W, W1, W2, W_phi, tilde_phi, dst,
        W_t, W1_bf, W2_bf, Wphi_t, deg, rank, tnorm, lsep_ptr);

    // CSR offsets (+ contiguous csr_dst fill)
    scan_partial_k<<<SCAN_NB, 256, 0, stream>>>(deg, bsum);
    scan_bsum_k<<<1, 256, 0, stream>>>(bsum);
    scan_scatter_k<<<SCAN_NB, 256, 0, stream>>>(deg, bsum, offs, csr_dst);

    // merged: scatter + h-GEMM + hid+phi+delta (hid never touches HBM)
    fused3_k<<<1955, 512, 0, stream>>>(e_l, h_l, W1_bf, Wphi_t, W_t, W2_bf,
                                       b1, b2, tnorm, phi, h8, deltap, lf_part,
                                       src, dst, rank, offs, csr_src);

    // edge weights + l_focus finalize
    edge_w_k<<<3126, 256, 0, stream>>>(csr_src, csr_dst, phi, deltap, (float4*)csr_w,
                                       lf_part, lfocus_ptr);

    // per-dst softmax + aggregation + normalize
    aggregate_k<<<12500, 256, 0, stream>>>(offs, csr_src, csr_w,
                                           (const unsigned int*)h8, bias, out);
}